// Round 16
// baseline (214.786 us; speedup 1.0000x reference)
//
#include <hip/hip_runtime.h>
#include <math.h>

#define HID 128
#define INDIM 6

typedef float4 f4;
typedef __attribute__((ext_vector_type(8))) short short8;
typedef __attribute__((ext_vector_type(4))) float f32x4;

static __device__ inline unsigned short f2bf(float f) {
    union { float f; unsigned int u; } v; v.f = f;
    unsigned int r = v.u + 0x7fffu + ((v.u >> 16) & 1u);   // RNE
    return (unsigned short)(r >> 16);
}
static __device__ inline float bf2f_lo(unsigned int u) {
    union { unsigned int u; float f; } v; v.u = u << 16; return v.f;
}
static __device__ inline float bf2f_hi(unsigned int u) {
    union { unsigned int u; float f; } v; v.u = u & 0xffff0000u; return v.f;
}

// ---------------- utility: zero degi[N] + bnbuf[4096] in one launch ----------------
__global__ void k_zero2(int* a, int na, int* b, int nb) {
    int i = blockIdx.x * blockDim.x + threadIdx.x;
    if (i < na) a[i] = 0;
    if (i < nb) b[i] = 0;
}

// ---------------- degree + per-edge rank ----------------
__global__ void k_deg(const int* dst, int* deg, int* rank, int E) {
    int e = blockIdx.x * blockDim.x + threadIdx.x;
    if (e < E) rank[e] = atomicAdd(&deg[dst[e]], 1);
}

// ---------------- hierarchical exclusive scan (deg -> rowptr) ----------------
__global__ void k_scan_partial(const int* __restrict__ deg, int* __restrict__ partial, int N) {
    __shared__ int lds[256];
    int t = threadIdx.x;
    int base = blockIdx.x * 1024 + t * 4;
    int s = 0;
    if (base + 4 <= N) {
        int4 v = *(const int4*)&deg[base];
        s = v.x + v.y + v.z + v.w;
    } else {
        for (int i = 0; i < 4; i++) if (base + i < N) s += deg[base + i];
    }
    lds[t] = s;
    __syncthreads();
    for (int off = 128; off > 0; off >>= 1) {
        if (t < off) lds[t] += lds[t + off];
        __syncthreads();
    }
    if (t == 0) partial[blockIdx.x] = lds[0];
}

__global__ void k_scan_tops(int* partial, int nb) {
    __shared__ int lds[1024];
    int t = threadIdx.x;
    lds[t] = (t < nb) ? partial[t] : 0;
    __syncthreads();
    for (int off = 1; off < 1024; off <<= 1) {
        int v = (t >= off) ? lds[t - off] : 0;
        __syncthreads();
        lds[t] += v;
        __syncthreads();
    }
    if (t < nb) partial[t] = (t == 0) ? 0 : lds[t - 1];
}

__global__ void k_scan_write(const int* __restrict__ deg, const int* __restrict__ partial,
                             int* __restrict__ rowptr, int N, int E) {
    __shared__ int lds[256];
    int t = threadIdx.x;
    int base = blockIdx.x * 1024 + t * 4;
    int v0 = 0, v1 = 0, v2 = 0, v3 = 0;
    if (base + 4 <= N) {
        int4 v = *(const int4*)&deg[base];
        v0 = v.x; v1 = v.y; v2 = v.z; v3 = v.w;
    } else {
        if (base + 0 < N) v0 = deg[base + 0];
        if (base + 1 < N) v1 = deg[base + 1];
        if (base + 2 < N) v2 = deg[base + 2];
        if (base + 3 < N) v3 = deg[base + 3];
    }
    lds[t] = v0 + v1 + v2 + v3;
    __syncthreads();
    for (int off = 1; off < 256; off <<= 1) {
        int v = (t >= off) ? lds[t - off] : 0;
        __syncthreads();
        lds[t] += v;
        __syncthreads();
    }
    int run = partial[blockIdx.x] + ((t == 0) ? 0 : lds[t - 1]);
    if (base + 0 < N) rowptr[base + 0] = run; run += v0;
    if (base + 1 < N) rowptr[base + 1] = run; run += v1;
    if (base + 2 < N) rowptr[base + 2] = run; run += v2;
    if (base + 3 < N) rowptr[base + 3] = run; run += v3;
    if (blockIdx.x == 0 && t == 0) rowptr[N] = E;
}

// ---------------- CSR fill, atomic-free (uses rank from k_deg) ----------------
__global__ void k_fill(const int* ei, const int* rank, const int* rowptr, int* csr, int E) {
    int e = blockIdx.x * blockDim.x + threadIdx.x;
    if (e < E) {
        int d = ei[E + e];
        csr[rowptr[d] + rank[e]] = ei[e];
    }
}

__global__ void k_invdeg(const int* deg, float* invd, int N) {
    int i = blockIdx.x * blockDim.x + threadIdx.x;
    if (i < N) invd[i] = 1.0f / (float)max(deg[i], 1);
}

// ---------------- weight prep: concat [Wl1 | Wr1] -> bf16 [128][256] ----------------
__global__ void k_prepw(const float* __restrict__ wl, const float* __restrict__ wr,
                        unsigned short* __restrict__ wcat) {
    int i = blockIdx.x * 256 + threadIdx.x;       // 32768 total
    int o = i >> 8, k = i & 255;
    float v = (k < 128) ? wl[o * 128 + k] : wr[o * 128 + k - 128];
    wcat[i] = f2bf(v);
}

// ---------------- layer 0a: gather mean6 + in-register h for BN0 stats ----------------
// 32 nodes/block, 8 threads/node (6 active in gather). Inline per-k reduction keeps
// VGPR low (R14 regression: sk[16]/qk[16] arrays blew VGPR 36->112, occupancy 51->18%).
__global__ __launch_bounds__(256) void k_l0stats(
        const float* __restrict__ x, const int* __restrict__ rowptr,
        const int* __restrict__ csr, const float* __restrict__ invd,
        const float* __restrict__ wl, const float* __restrict__ bl,
        const float* __restrict__ wr, float* __restrict__ mean6,
        float* __restrict__ sum8, float* __restrict__ sq8, int N) {
    __shared__ float wlds[1600];   // [wl | wr], addr = base + o*6+i + (o>>4)*2  (bank-spread)
    __shared__ float blds[136];    // bias, addr = o + (o>>4)
    __shared__ float mx[32][8];
    __shared__ float xr[32][8];
    __shared__ float ps[4][128];
    __shared__ float pq[4][128];
    int t = threadIdx.x;
    for (int idx = t; idx < 1536; idx += 256) {
        int half = idx >= 768 ? 1 : 0;
        int lin = idx - half * 768;
        int o = lin / 6, i = lin - o * 6;
        float v = half ? wr[lin] : wl[lin];
        wlds[half * 800 + o * 6 + i + (o >> 4) * 2] = v;
    }
    if (t < 128) blds[t + (t >> 4)] = bl[t];
    int nl = t >> 3, f = t & 7;
    int n = blockIdx.x * 32 + nl;
    bool valid = n < N;
    if (f < 6) {
        float mean = 0.f, xv = 0.f;
        if (valid) {
            int s = rowptr[n], e = rowptr[n + 1];
            float acc = 0.f;
            int i = s;
            for (; i + 4 <= e; i += 4) {           // 4-deep MLP unroll
                int i0 = csr[i], i1 = csr[i + 1], i2 = csr[i + 2], i3 = csr[i + 3];
                float a0 = x[i0 * 6 + f], a1 = x[i1 * 6 + f];
                float a2 = x[i2 * 6 + f], a3 = x[i3 * 6 + f];
                acc += (a0 + a1) + (a2 + a3);
            }
            for (; i < e; i++) acc += x[csr[i] * 6 + f];
            mean = acc * invd[n];
            xv = x[n * 6 + f];
            mean6[n * 6 + f] = mean;               // 2.4 MB total (replaces 51 MB h write)
        }
        mx[nl][f] = mean;
        xr[nl][f] = xv;
    }
    __syncthreads();
    float m0 = mx[nl][0], m1 = mx[nl][1], m2 = mx[nl][2];
    float m3 = mx[nl][3], m4 = mx[nl][4], m5 = mx[nl][5];
    float r0 = xr[nl][0], r1 = xr[nl][1], r2 = xr[nl][2];
    float r3 = xr[nl][3], r4 = xr[nl][4], r5 = xr[nl][5];
    const float* wA = wlds;
    const float* wB = wlds + 800;
    int wv = t >> 6, lane = t & 63;
#pragma unroll
    for (int k = 0; k < 16; k++) {                 // inline reduce: no sk/qk arrays
        int o = f * 16 + k;
        int wb = 98 * f + 6 * k;                   // o*6 + (o>>4)*2
        float h = blds[o + f];                     // o + (o>>4), o>>4 == f
        h += m0 * wA[wb] + m1 * wA[wb + 1] + m2 * wA[wb + 2]
           + m3 * wA[wb + 3] + m4 * wA[wb + 4] + m5 * wA[wb + 5];
        h += r0 * wB[wb] + r1 * wB[wb + 1] + r2 * wB[wb + 2]
           + r3 * wB[wb + 3] + r4 * wB[wb + 4] + r5 * wB[wb + 5];
        float s = valid ? h : 0.f;
        float q = s * s;
        s += __shfl_xor(s, 8, 64);  q += __shfl_xor(q, 8, 64);
        s += __shfl_xor(s, 16, 64); q += __shfl_xor(q, 16, 64);
        s += __shfl_xor(s, 32, 64); q += __shfl_xor(q, 32, 64);
        if (lane < 8) { ps[wv][lane * 16 + k] = s; pq[wv][lane * 16 + k] = q; }
    }
    __syncthreads();
    if (t < 128) {
        float S = ps[0][t] + ps[1][t] + ps[2][t] + ps[3][t];
        float Q = pq[0][t] + pq[1][t] + pq[2][t] + pq[3][t];
        int slot = (blockIdx.x & 7) * 128 + t;
        atomicAdd(&sum8[slot], S);
        atomicAdd(&sq8[slot], Q);
    }
}

// ---------------- layer 0b: recompute h (identical code) + BN0+ReLU -> bf16 ----------
__global__ __launch_bounds__(256) void k_l0apply(
        const float* __restrict__ x, const float* __restrict__ mean6,
        const float* __restrict__ wl, const float* __restrict__ bl,
        const float* __restrict__ wr, const float* __restrict__ scale,
        const float* __restrict__ shift, unsigned short* __restrict__ out, int N) {
    __shared__ float wlds[1600];
    __shared__ float blds[136];
    __shared__ float sclds[136];
    __shared__ float shlds[136];
    __shared__ float mx[32][8];
    __shared__ float xr[32][8];
    int t = threadIdx.x;
    for (int idx = t; idx < 1536; idx += 256) {
        int half = idx >= 768 ? 1 : 0;
        int lin = idx - half * 768;
        int o = lin / 6, i = lin - o * 6;
        float v = half ? wr[lin] : wl[lin];
        wlds[half * 800 + o * 6 + i + (o >> 4) * 2] = v;
    }
    if (t < 128) {
        blds[t + (t >> 4)]  = bl[t];
        sclds[t + (t >> 4)] = scale[t];
        shlds[t + (t >> 4)] = shift[t];
    }
    int nl = t >> 3, f = t & 7;
    int n = blockIdx.x * 32 + nl;
    bool valid = n < N;
    if (f < 6) {
        mx[nl][f] = valid ? mean6[n * 6 + f] : 0.f;
        xr[nl][f] = valid ? x[n * 6 + f] : 0.f;
    }
    __syncthreads();
    if (!valid) return;
    float m0 = mx[nl][0], m1 = mx[nl][1], m2 = mx[nl][2];
    float m3 = mx[nl][3], m4 = mx[nl][4], m5 = mx[nl][5];
    float r0 = xr[nl][0], r1 = xr[nl][1], r2 = xr[nl][2];
    float r3 = xr[nl][3], r4 = xr[nl][4], r5 = xr[nl][5];
    const float* wA = wlds;
    const float* wB = wlds + 800;
    unsigned short pk[16];
#pragma unroll
    for (int k4 = 0; k4 < 4; k4++) {
#pragma unroll
        for (int j = 0; j < 4; j++) {
            int k = k4 * 4 + j;
            int o = f * 16 + k;
            int wb = 98 * f + 6 * k;
            float h = blds[o + f];              // identical expression tree to k_l0stats
            h += m0 * wA[wb] + m1 * wA[wb + 1] + m2 * wA[wb + 2]
               + m3 * wA[wb + 3] + m4 * wA[wb + 4] + m5 * wA[wb + 5];
            h += r0 * wB[wb] + r1 * wB[wb + 1] + r2 * wB[wb + 2]
               + r3 * wB[wb + 3] + r4 * wB[wb + 4] + r5 * wB[wb + 5];
            pk[k] = f2bf(fmaxf(0.f, fmaf(h, sclds[o + f], shlds[o + f])));
        }
    }
    unsigned short* dst = out + (size_t)n * HID + f * 16;
    *(uint4*)(dst)     = *(const uint4*)&pk[0];
    *(uint4*)(dst + 8) = *(const uint4*)&pk[8];
}

// ---------------- BN finalize from 8-copy accumulators ----------------
__global__ void k_bnfin8(const float* sum8, const float* sq8, const float* g, const float* b,
                         float* scale, float* shift, float invN) {
    int t = threadIdx.x;
    float s = 0.f, q = 0.f;
    for (int c = 0; c < 8; c++) { s += sum8[c * 128 + t]; q += sq8[c * 128 + t]; }
    float mu  = s * invN;
    float var = q * invN - mu * mu;
    float sc  = g[t] * rsqrtf(var + 1e-5f);
    scale[t] = sc;
    shift[t] = b[t] - mu * sc;
}

// ---------------- bf16 mean aggregation: half-wave per node, uint2 lanes, 4-deep MLP ----
__global__ void k_agg_bf(const unsigned short* __restrict__ hb, const int* __restrict__ rowptr,
                         const int* __restrict__ csr, const float* __restrict__ invd,
                         unsigned short* __restrict__ out, int N) {
    int t = threadIdx.x;
    int w = t >> 6, lid = t & 63;
    int half = lid >> 5, l32 = lid & 31;
    int n = blockIdx.x * 8 + w * 2 + half;
    if (n >= N) return;
    int s = rowptr[n], e = rowptr[n + 1];
    const uint2* hb64 = (const uint2*)hb;          // row stride = 32 uint2 (256 B)
    float ax0 = 0.f, ay0 = 0.f, ax1 = 0.f, ay1 = 0.f;
    int i = s;
    for (; i + 4 <= e; i += 4) {                   // 4 rows x 2 nodes/wave in flight
        int i0 = csr[i], i1 = csr[i + 1], i2 = csr[i + 2], i3 = csr[i + 3];
        uint2 u0 = hb64[(size_t)i0 * 32 + l32];
        uint2 u1 = hb64[(size_t)i1 * 32 + l32];
        uint2 u2 = hb64[(size_t)i2 * 32 + l32];
        uint2 u3 = hb64[(size_t)i3 * 32 + l32];
        ax0 += (bf2f_lo(u0.x) + bf2f_lo(u1.x)) + (bf2f_lo(u2.x) + bf2f_lo(u3.x));
        ay0 += (bf2f_hi(u0.x) + bf2f_hi(u1.x)) + (bf2f_hi(u2.x) + bf2f_hi(u3.x));
        ax1 += (bf2f_lo(u0.y) + bf2f_lo(u1.y)) + (bf2f_lo(u2.y) + bf2f_lo(u3.y));
        ay1 += (bf2f_hi(u0.y) + bf2f_hi(u1.y)) + (bf2f_hi(u2.y) + bf2f_hi(u3.y));
    }
    for (; i < e; i++) {
        uint2 u = hb64[(size_t)csr[i] * 32 + l32];
        ax0 += bf2f_lo(u.x); ay0 += bf2f_hi(u.x);
        ax1 += bf2f_lo(u.y); ay1 += bf2f_hi(u.y);
    }
    float id = invd[n];
    uint2 r;
    r.x = (unsigned int)f2bf(ax0 * id) | ((unsigned int)f2bf(ay0 * id) << 16);
    r.y = (unsigned int)f2bf(ax1 * id) | ((unsigned int)f2bf(ay1 * id) << 16);
    ((uint2*)out)[(size_t)n * 32 + l32] = r;
}

// ---------------- MFMA double GEMM + fused BN1 stats (BK=64, W from L2, bf16 C) -------
// block: 128 rows x 128 cols, 4 waves (2x2 of 64x64), K = 256 in 4 chunks of 64
__global__ __launch_bounds__(256) void k_gemm(
        const unsigned short* __restrict__ Bm, const unsigned short* __restrict__ Ar,
        const unsigned short* __restrict__ wcat, const float* __restrict__ bias,
        float* __restrict__ sum8, float* __restrict__ sq8,
        unsigned short* __restrict__ C, int N) {
    __shared__ __align__(16) unsigned short As[128][72];   // 64 k + 8 pad (row = 36 banks)
    __shared__ float lds_s[2][128];
    __shared__ float lds_q[2][128];
    int t = threadIdx.x;
    int wave = t >> 6, lane = t & 63;
    int wr = wave >> 1, wc = wave & 1;
    int row0 = blockIdx.x * 128;
    int r = t >> 1, half = t & 1;          // staging: row r, 32-col half
    int lrow = lane & 15, koff = (lane >> 4) * 8;

    f32x4 acc[4][4];
#pragma unroll
    for (int m = 0; m < 4; m++)
#pragma unroll
        for (int n = 0; n < 4; n++) acc[m][n] = (f32x4)(0.f);

    for (int chunk = 0; chunk < 4; chunk++) {
        int kb = chunk * 64;
        // ---- stage A (bf16 copy, 64 B per thread) ----
        int srow = row0 + r;
        int c0 = (kb & 127) + half * 32;
        const unsigned short* src = (kb < 128) ? Bm : Ar;
        uint4 v0, v1, v2, v3;
        if (srow < N) {
            const unsigned short* p = src + (size_t)srow * HID + c0;
            v0 = *(const uint4*)(p);      v1 = *(const uint4*)(p + 8);
            v2 = *(const uint4*)(p + 16); v3 = *(const uint4*)(p + 24);
        } else {
            v0 = v1 = v2 = v3 = make_uint4(0, 0, 0, 0);
        }
        *(uint4*)&As[r][half * 32]      = v0;
        *(uint4*)&As[r][half * 32 + 8]  = v1;
        *(uint4*)&As[r][half * 32 + 16] = v2;
        *(uint4*)&As[r][half * 32 + 24] = v3;
        __syncthreads();

        // ---- MFMA: two k-steps of 32; W frags straight from L2-resident wcat ----
#pragma unroll
        for (int ks = 0; ks < 64; ks += 32) {
            short8 af[4], bfr[4];
#pragma unroll
            for (int m = 0; m < 4; m++)
                af[m] = *(const short8*)&As[wr * 64 + m * 16 + lrow][ks + koff];
#pragma unroll
            for (int n = 0; n < 4; n++)
                bfr[n] = *(const short8*)&wcat[(size_t)(wc * 64 + n * 16 + lrow) * 256 + kb + ks + koff];
#pragma unroll
            for (int m = 0; m < 4; m++)
#pragma unroll
                for (int n = 0; n < 4; n++)
                    acc[m][n] = __builtin_amdgcn_mfma_f32_16x16x32_bf16(af[m], bfr[n], acc[m][n], 0, 0, 0);
        }
        __syncthreads();
    }

    // ---- epilogue: bf16 store + per-col fp32 stats. D: col = lane&15, row = (lane>>4)*4+reg
    int cl = lane & 15, rq = (lane >> 4) * 4;
    float cs[4], cq[4];
#pragma unroll
    for (int n = 0; n < 4; n++) {
        int col = wc * 64 + n * 16 + cl;
        float bn = bias[col];
        float s = 0.f, q = 0.f;
#pragma unroll
        for (int m = 0; m < 4; m++) {
#pragma unroll
            for (int reg = 0; reg < 4; reg++) {
                int row = row0 + wr * 64 + m * 16 + rq + reg;
                float v = acc[m][n][reg] + bn;
                if (row < N) {
                    C[(size_t)row * HID + col] = f2bf(v);
                    s += v;
                    q += v * v;
                }
            }
        }
        cs[n] = s; cq[n] = q;
    }
#pragma unroll
    for (int n = 0; n < 4; n++) {
        float s = cs[n], q = cq[n];
        s += __shfl_xor(s, 16, 64); q += __shfl_xor(q, 16, 64);
        s += __shfl_xor(s, 32, 64); q += __shfl_xor(q, 32, 64);
        if (lane < 16) {
            int col = wc * 64 + n * 16 + cl;   // cl == lane
            lds_s[wr][col] = s;
            lds_q[wr][col] = q;
        }
    }
    __syncthreads();
    if (t < 128) {
        float S = lds_s[0][t] + lds_s[1][t];
        float Q = lds_q[0][t] + lds_q[1][t];
        int slot = (blockIdx.x & 7) * 128 + t;
        atomicAdd(&sum8[slot], S);
        atomicAdd(&sq8[slot], Q);
    }
}

// ---------------- layer 2 dots (bf16 h1): s = relu(bn1(h))·wl2, r = relu(bn1(h))·wr2 ----
__global__ void k_dots(const unsigned short* __restrict__ h, const float* __restrict__ scale,
                       const float* __restrict__ shift, const float* __restrict__ wl2,
                       const float* __restrict__ wr2, float* __restrict__ s_arr,
                       float* __restrict__ r_arr, int N) {
    int w = threadIdx.x >> 6, lid = threadIdx.x & 63;
    int n = blockIdx.x * 4 + w;
    if (n >= N) return;
    unsigned int u = ((const unsigned int*)h)[(size_t)n * 64 + lid];
    float hx = bf2f_lo(u), hy = bf2f_hi(u);
    float2 sc = *(const float2*)&scale[lid * 2];
    float2 sh = *(const float2*)&shift[lid * 2];
    float y0 = fmaxf(0.f, fmaf(hx, sc.x, sh.x));
    float y1 = fmaxf(0.f, fmaf(hy, sc.y, sh.y));
    float2 wl = *(const float2*)&wl2[lid * 2];
    float2 wrv = *(const float2*)&wr2[lid * 2];
    float ps = y0 * wl.x + y1 * wl.y;
    float pr = y0 * wrv.x + y1 * wrv.y;
#pragma unroll
    for (int off = 32; off > 0; off >>= 1) {
        ps += __shfl_down(ps, off, 64);
        pr += __shfl_down(pr, off, 64);
    }
    if (lid == 0) { s_arr[n] = ps; r_arr[n] = pr; }
}

// ---------------- final: scalar mean over edges + sigmoid (4-deep MLP) ----------------
__global__ void k_final2(const float* __restrict__ s_arr, const float* __restrict__ r_arr,
                         const int* __restrict__ rowptr, const int* __restrict__ csr,
                         const float* __restrict__ invd, const float* __restrict__ bl2,
                         float* __restrict__ out, int N) {
    int n = blockIdx.x * blockDim.x + threadIdx.x;
    if (n >= N) return;
    int s = rowptr[n], e = rowptr[n + 1];
    float a = 0.f;
    int i = s;
    for (; i + 4 <= e; i += 4) {
        float a0 = s_arr[csr[i]],     a1 = s_arr[csr[i + 1]];
        float a2 = s_arr[csr[i + 2]], a3 = s_arr[csr[i + 3]];
        a += (a0 + a1) + (a2 + a3);
    }
    for (; i < e; i++) a += s_arr[csr[i]];
    float p = a * invd[n] + r_arr[n] + bl2[0];
    out[n] = 1.f / (1.f + expf(-p));
}

// ---------------- host ----------------
extern "C" void kernel_launch(void* const* d_in, const int* in_sizes, int n_in,
                              void* d_out, int out_size, void* d_ws, size_t ws_size,
                              hipStream_t stream) {
    const float* x   = (const float*)d_in[0];
    const int*   ei  = (const int*)d_in[1];
    const float* wl0 = (const float*)d_in[2];
    const float* bl0 = (const float*)d_in[3];
    const float* wr0 = (const float*)d_in[4];
    const float* g0  = (const float*)d_in[5];
    const float* be0 = (const float*)d_in[6];
    const float* wl1 = (const float*)d_in[7];
    const float* bl1 = (const float*)d_in[8];
    const float* wr1 = (const float*)d_in[9];
    const float* g1  = (const float*)d_in[10];
    const float* be1 = (const float*)d_in[11];
    const float* wl2 = (const float*)d_in[12];
    const float* bl2 = (const float*)d_in[13];
    const float* wr2 = (const float*)d_in[14];
    float* outp = (float*)d_out;

    int N = in_sizes[0] / INDIM;     // 100000
    int E = in_sizes[1] / 2;         // 600000

    char* ws = (char*)d_ws;
    size_t off = 0;
    auto alloc = [&](size_t bytes) { size_t o = off; off = (off + bytes + 255) & ~(size_t)255; return o; };
    int*   degi   = (int*)(ws + alloc((size_t)N * 4));
    int*   rank   = (int*)(ws + alloc((size_t)E * 4));
    int*   rowptr = (int*)(ws + alloc((size_t)(N + 1) * 4));
    int*   csr    = (int*)(ws + alloc((size_t)E * 4));
    float* invd   = (float*)(ws + alloc((size_t)N * 4));
    int*   partial= (int*)(ws + alloc(1024 * 4));
    float* bnbuf  = (float*)(ws + alloc(5120 * 4));
    unsigned short* wcat = (unsigned short*)(ws + alloc(128 * 256 * 2));
    float* sarr   = (float*)(ws + alloc((size_t)N * 4));
    float* rarr   = (float*)(ws + alloc((size_t)N * 4));
    float* mean6  = (float*)(ws + alloc((size_t)N * 6 * 4));
    // bnbuf layout: sum0_8[1024] sq0_8[1024] sum1_8[1024] sq1_8[1024] sc0 sh0 sc1 sh1 [128 each]
    float* sum0_8 = bnbuf;
    float* sq0_8  = bnbuf + 1024;
    float* sum1_8 = bnbuf + 2048;
    float* sq1_8  = bnbuf + 3072;
    float* sc0 = bnbuf + 4096, *sh0 = bnbuf + 4224;
    float* sc1 = bnbuf + 4352, *sh1 = bnbuf + 4480;
    unsigned short* bufB = (unsigned short*)(ws + alloc((size_t)N * HID * 2)); // bf16 gemm out
    unsigned short* bufC = (unsigned short*)(ws + alloc((size_t)N * HID * 2)); // bf16 relu(bn0)
    unsigned short* bufD = (unsigned short*)(ws + alloc((size_t)N * HID * 2)); // bf16 agg mean

    float invN = 1.0f / (float)N;
    int gE = (E + 255) / 256;
    int gN = (N + 255) / 256;
    int gW = (N + 3) / 4;            // wave-per-node kernels
    int gA = (N + 7) / 8;            // agg blocks (8 nodes each, half-wave per node)
    int gL = (N + 31) / 32;          // layer0 blocks (32 nodes each)
    int gS = (N + 127) / 128;        // gemm blocks
    int nbScan = (N + 1023) / 1024;

    // zero degree + BN accumulators in one launch
    k_zero2<<<gN, 256, 0, stream>>>(degi, N, (int*)bnbuf, 4096);

    // weight prep (independent)
    k_prepw<<<128, 256, 0, stream>>>(wl1, wr1, wcat);

    // CSR build (rank-based, atomic-free fill)
    k_deg<<<gE, 256, 0, stream>>>(ei + E, degi, rank, E);
    k_scan_partial<<<nbScan, 256, 0, stream>>>(degi, partial, N);
    k_scan_tops<<<1, 1024, 0, stream>>>(partial, nbScan);
    k_scan_write<<<nbScan, 256, 0, stream>>>(degi, partial, rowptr, N, E);
    k_fill<<<gE, 256, 0, stream>>>(ei, rank, rowptr, csr, E);
    k_invdeg<<<gN, 256, 0, stream>>>(degi, invd, N);

    // layer 0a: gather mean6 + fused BN0 stats (h in-register, discarded)
    k_l0stats<<<gL, 256, 0, stream>>>(x, rowptr, csr, invd, wl0, bl0, wr0, mean6,
                                      sum0_8, sq0_8, N);
    k_bnfin8<<<1, 128, 0, stream>>>(sum0_8, sq0_8, g0, be0, sc0, sh0, invN);

    // layer 0b: recompute h (identical fp32 ops) + BN0+ReLU -> bf16 bufC
    k_l0apply<<<gL, 256, 0, stream>>>(x, mean6, wl0, bl0, wr0, sc0, sh0, bufC, N);

    // layer 1: agg(bufC) -> bufD (bf16) ; MFMA gemm(bufD, bufC) -> bufB (bf16) + BN1 stats
    k_agg_bf<<<gA, 256, 0, stream>>>(bufC, rowptr, csr, invd, bufD, N);
    k_gemm<<<gS, 256, 0, stream>>>(bufD, bufC, wcat, bl1, sum1_8, sq1_8, bufB, N);
    k_bnfin8<<<1, 128, 0, stream>>>(sum1_8, sq1_8, g1, be1, sc1, sh1, invN);

    // layer 2: per-node dots then scalar aggregation + sigmoid
    k_dots<<<gW, 256, 0, stream>>>(bufB, sc1, sh1, wl2, wr2, sarr, rarr, N);
    k_final2<<<gN, 256, 0, stream>>>(sarr, rarr, rowptr, csr, invd, bl2, outp, N);
}

// Round 17
// 193.084 us; speedup vs baseline: 1.1124x; 1.1124x over previous
//
#include <hip/hip_runtime.h>
#include <math.h>

#define HID 128
#define INDIM 6

typedef float4 f4;
typedef __attribute__((ext_vector_type(8))) short short8;
typedef __attribute__((ext_vector_type(4))) float f32x4;

static __device__ inline unsigned short f2bf(float f) {
    union { float f; unsigned int u; } v; v.f = f;
    unsigned int r = v.u + 0x7fffu + ((v.u >> 16) & 1u);   // RNE
    return (unsigned short)(r >> 16);
}
static __device__ inline float bf2f_lo(unsigned int u) {
    union { unsigned int u; float f; } v; v.u = u << 16; return v.f;
}
static __device__ inline float bf2f_hi(unsigned int u) {
    union { unsigned int u; float f; } v; v.u = u & 0xffff0000u; return v.f;
}

// ---------------- utility: zero degi[N] + bnbuf[4096] in one launch ----------------
__global__ void k_zero2(int* a, int na, int* b, int nb) {
    int i = blockIdx.x * blockDim.x + threadIdx.x;
    if (i < na) a[i] = 0;
    if (i < nb) b[i] = 0;
}

// ---------------- degree + per-edge rank ----------------
__global__ void k_deg(const int* dst, int* deg, int* rank, int E) {
    int e = blockIdx.x * blockDim.x + threadIdx.x;
    if (e < E) rank[e] = atomicAdd(&deg[dst[e]], 1);
}

// ---------------- hierarchical exclusive scan (deg -> rowptr) ----------------
__global__ void k_scan_partial(const int* __restrict__ deg, int* __restrict__ partial, int N) {
    __shared__ int lds[256];
    int t = threadIdx.x;
    int base = blockIdx.x * 1024 + t * 4;
    int s = 0;
    if (base + 4 <= N) {
        int4 v = *(const int4*)&deg[base];
        s = v.x + v.y + v.z + v.w;
    } else {
        for (int i = 0; i < 4; i++) if (base + i < N) s += deg[base + i];
    }
    lds[t] = s;
    __syncthreads();
    for (int off = 128; off > 0; off >>= 1) {
        if (t < off) lds[t] += lds[t + off];
        __syncthreads();
    }
    if (t == 0) partial[blockIdx.x] = lds[0];
}

__global__ void k_scan_tops(int* partial, int nb) {
    __shared__ int lds[1024];
    int t = threadIdx.x;
    lds[t] = (t < nb) ? partial[t] : 0;
    __syncthreads();
    for (int off = 1; off < 1024; off <<= 1) {
        int v = (t >= off) ? lds[t - off] : 0;
        __syncthreads();
        lds[t] += v;
        __syncthreads();
    }
    if (t < nb) partial[t] = (t == 0) ? 0 : lds[t - 1];
}

__global__ void k_scan_write(const int* __restrict__ deg, const int* __restrict__ partial,
                             int* __restrict__ rowptr, int N, int E) {
    __shared__ int lds[256];
    int t = threadIdx.x;
    int base = blockIdx.x * 1024 + t * 4;
    int v0 = 0, v1 = 0, v2 = 0, v3 = 0;
    if (base + 4 <= N) {
        int4 v = *(const int4*)&deg[base];
        v0 = v.x; v1 = v.y; v2 = v.z; v3 = v.w;
    } else {
        if (base + 0 < N) v0 = deg[base + 0];
        if (base + 1 < N) v1 = deg[base + 1];
        if (base + 2 < N) v2 = deg[base + 2];
        if (base + 3 < N) v3 = deg[base + 3];
    }
    lds[t] = v0 + v1 + v2 + v3;
    __syncthreads();
    for (int off = 1; off < 256; off <<= 1) {
        int v = (t >= off) ? lds[t - off] : 0;
        __syncthreads();
        lds[t] += v;
        __syncthreads();
    }
    int run = partial[blockIdx.x] + ((t == 0) ? 0 : lds[t - 1]);
    if (base + 0 < N) rowptr[base + 0] = run; run += v0;
    if (base + 1 < N) rowptr[base + 1] = run; run += v1;
    if (base + 2 < N) rowptr[base + 2] = run; run += v2;
    if (base + 3 < N) rowptr[base + 3] = run; run += v3;
    if (blockIdx.x == 0 && t == 0) rowptr[N] = E;
}

// ---------------- CSR fill, atomic-free (uses rank from k_deg) ----------------
__global__ void k_fill(const int* ei, const int* rank, const int* rowptr, int* csr, int E) {
    int e = blockIdx.x * blockDim.x + threadIdx.x;
    if (e < E) {
        int d = ei[E + e];
        csr[rowptr[d] + rank[e]] = ei[e];
    }
}

__global__ void k_invdeg(const int* deg, float* invd, int N) {
    int i = blockIdx.x * blockDim.x + threadIdx.x;
    if (i < N) invd[i] = 1.0f / (float)max(deg[i], 1);
}

// ---------------- weight prep: concat [Wl1 | Wr1] -> bf16 [128][256] ----------------
__global__ void k_prepw(const float* __restrict__ wl, const float* __restrict__ wr,
                        unsigned short* __restrict__ wcat) {
    int i = blockIdx.x * 256 + threadIdx.x;       // 32768 total
    int o = i >> 8, k = i & 255;
    float v = (k < 128) ? wl[o * 128 + k] : wr[o * 128 + k - 128];
    wcat[i] = f2bf(v);
}

// ---------------- layer 0a: gather mean6 + in-register h for BN0 stats ----------------
__global__ __launch_bounds__(256) void k_l0stats(
        const float* __restrict__ x, const int* __restrict__ rowptr,
        const int* __restrict__ csr, const float* __restrict__ invd,
        const float* __restrict__ wl, const float* __restrict__ bl,
        const float* __restrict__ wr, float* __restrict__ mean6,
        float* __restrict__ sum8, float* __restrict__ sq8, int N) {
    __shared__ float wlds[1600];   // [wl | wr], addr = base + o*6+i + (o>>4)*2  (bank-spread)
    __shared__ float blds[136];    // bias, addr = o + (o>>4)
    __shared__ float mx[32][8];
    __shared__ float xr[32][8];
    __shared__ float ps[4][128];
    __shared__ float pq[4][128];
    int t = threadIdx.x;
    for (int idx = t; idx < 1536; idx += 256) {
        int half = idx >= 768 ? 1 : 0;
        int lin = idx - half * 768;
        int o = lin / 6, i = lin - o * 6;
        float v = half ? wr[lin] : wl[lin];
        wlds[half * 800 + o * 6 + i + (o >> 4) * 2] = v;
    }
    if (t < 128) blds[t + (t >> 4)] = bl[t];
    int nl = t >> 3, f = t & 7;
    int n = blockIdx.x * 32 + nl;
    bool valid = n < N;
    if (f < 6) {
        float mean = 0.f, xv = 0.f;
        if (valid) {
            int s = rowptr[n], e = rowptr[n + 1];
            float acc = 0.f;
            int i = s;
            for (; i + 4 <= e; i += 4) {           // 4-deep MLP unroll
                int i0 = csr[i], i1 = csr[i + 1], i2 = csr[i + 2], i3 = csr[i + 3];
                float a0 = x[i0 * 6 + f], a1 = x[i1 * 6 + f];
                float a2 = x[i2 * 6 + f], a3 = x[i3 * 6 + f];
                acc += (a0 + a1) + (a2 + a3);
            }
            for (; i < e; i++) acc += x[csr[i] * 6 + f];
            mean = acc * invd[n];
            xv = x[n * 6 + f];
            mean6[n * 6 + f] = mean;
        }
        mx[nl][f] = mean;
        xr[nl][f] = xv;
    }
    __syncthreads();
    float m0 = mx[nl][0], m1 = mx[nl][1], m2 = mx[nl][2];
    float m3 = mx[nl][3], m4 = mx[nl][4], m5 = mx[nl][5];
    float r0 = xr[nl][0], r1 = xr[nl][1], r2 = xr[nl][2];
    float r3 = xr[nl][3], r4 = xr[nl][4], r5 = xr[nl][5];
    const float* wA = wlds;
    const float* wB = wlds + 800;
    int wv = t >> 6, lane = t & 63;
#pragma unroll
    for (int k = 0; k < 16; k++) {                 // inline reduce: no sk/qk arrays
        int o = f * 16 + k;
        int wb = 98 * f + 6 * k;                   // o*6 + (o>>4)*2
        float h = blds[o + f];                     // o + (o>>4), o>>4 == f
        h += m0 * wA[wb] + m1 * wA[wb + 1] + m2 * wA[wb + 2]
           + m3 * wA[wb + 3] + m4 * wA[wb + 4] + m5 * wA[wb + 5];
        h += r0 * wB[wb] + r1 * wB[wb + 1] + r2 * wB[wb + 2]
           + r3 * wB[wb + 3] + r4 * wB[wb + 4] + r5 * wB[wb + 5];
        float s = valid ? h : 0.f;
        float q = s * s;
        s += __shfl_xor(s, 8, 64);  q += __shfl_xor(q, 8, 64);
        s += __shfl_xor(s, 16, 64); q += __shfl_xor(q, 16, 64);
        s += __shfl_xor(s, 32, 64); q += __shfl_xor(q, 32, 64);
        if (lane < 8) { ps[wv][lane * 16 + k] = s; pq[wv][lane * 16 + k] = q; }
    }
    __syncthreads();
    if (t < 128) {
        float S = ps[0][t] + ps[1][t] + ps[2][t] + ps[3][t];
        float Q = pq[0][t] + pq[1][t] + pq[2][t] + pq[3][t];
        int slot = (blockIdx.x & 7) * 128 + t;
        atomicAdd(&sum8[slot], S);
        atomicAdd(&sq8[slot], Q);
    }
}

// ---------------- layer 0b: recompute h (identical code) + BN0+ReLU -> bf16 ----------
__global__ __launch_bounds__(256) void k_l0apply(
        const float* __restrict__ x, const float* __restrict__ mean6,
        const float* __restrict__ wl, const float* __restrict__ bl,
        const float* __restrict__ wr, const float* __restrict__ scale,
        const float* __restrict__ shift, unsigned short* __restrict__ out, int N) {
    __shared__ float wlds[1600];
    __shared__ float blds[136];
    __shared__ float sclds[136];
    __shared__ float shlds[136];
    __shared__ float mx[32][8];
    __shared__ float xr[32][8];
    int t = threadIdx.x;
    for (int idx = t; idx < 1536; idx += 256) {
        int half = idx >= 768 ? 1 : 0;
        int lin = idx - half * 768;
        int o = lin / 6, i = lin - o * 6;
        float v = half ? wr[lin] : wl[lin];
        wlds[half * 800 + o * 6 + i + (o >> 4) * 2] = v;
    }
    if (t < 128) {
        blds[t + (t >> 4)]  = bl[t];
        sclds[t + (t >> 4)] = scale[t];
        shlds[t + (t >> 4)] = shift[t];
    }
    int nl = t >> 3, f = t & 7;
    int n = blockIdx.x * 32 + nl;
    bool valid = n < N;
    if (f < 6) {
        mx[nl][f] = valid ? mean6[n * 6 + f] : 0.f;
        xr[nl][f] = valid ? x[n * 6 + f] : 0.f;
    }
    __syncthreads();
    if (!valid) return;
    float m0 = mx[nl][0], m1 = mx[nl][1], m2 = mx[nl][2];
    float m3 = mx[nl][3], m4 = mx[nl][4], m5 = mx[nl][5];
    float r0 = xr[nl][0], r1 = xr[nl][1], r2 = xr[nl][2];
    float r3 = xr[nl][3], r4 = xr[nl][4], r5 = xr[nl][5];
    const float* wA = wlds;
    const float* wB = wlds + 800;
    unsigned short pk[16];
#pragma unroll
    for (int k4 = 0; k4 < 4; k4++) {
#pragma unroll
        for (int j = 0; j < 4; j++) {
            int k = k4 * 4 + j;
            int o = f * 16 + k;
            int wb = 98 * f + 6 * k;
            float h = blds[o + f];              // identical expression tree to k_l0stats
            h += m0 * wA[wb] + m1 * wA[wb + 1] + m2 * wA[wb + 2]
               + m3 * wA[wb + 3] + m4 * wA[wb + 4] + m5 * wA[wb + 5];
            h += r0 * wB[wb] + r1 * wB[wb + 1] + r2 * wB[wb + 2]
               + r3 * wB[wb + 3] + r4 * wB[wb + 4] + r5 * wB[wb + 5];
            pk[k] = f2bf(fmaxf(0.f, fmaf(h, sclds[o + f], shlds[o + f])));
        }
    }
    unsigned short* dst = out + (size_t)n * HID + f * 16;
    *(uint4*)(dst)     = *(const uint4*)&pk[0];
    *(uint4*)(dst + 8) = *(const uint4*)&pk[8];
}

// ---------------- BN finalize from 8-copy accumulators ----------------
__global__ void k_bnfin8(const float* sum8, const float* sq8, const float* g, const float* b,
                         float* scale, float* shift, float invN) {
    int t = threadIdx.x;
    float s = 0.f, q = 0.f;
    for (int c = 0; c < 8; c++) { s += sum8[c * 128 + t]; q += sq8[c * 128 + t]; }
    float mu  = s * invN;
    float var = q * invN - mu * mu;
    float sc  = g[t] * rsqrtf(var + 1e-5f);
    scale[t] = sc;
    shift[t] = b[t] - mu * sc;
}

// ---------------- bf16 mean aggregation: half-wave per node, uint2 lanes, 4-deep MLP ----
__global__ void k_agg_bf(const unsigned short* __restrict__ hb, const int* __restrict__ rowptr,
                         const int* __restrict__ csr, const float* __restrict__ invd,
                         unsigned short* __restrict__ out, int N) {
    int t = threadIdx.x;
    int w = t >> 6, lid = t & 63;
    int half = lid >> 5, l32 = lid & 31;
    int n = blockIdx.x * 8 + w * 2 + half;
    if (n >= N) return;
    int s = rowptr[n], e = rowptr[n + 1];
    const uint2* hb64 = (const uint2*)hb;          // row stride = 32 uint2 (256 B)
    float ax0 = 0.f, ay0 = 0.f, ax1 = 0.f, ay1 = 0.f;
    int i = s;
    for (; i + 4 <= e; i += 4) {                   // 4 rows x 2 nodes/wave in flight
        int i0 = csr[i], i1 = csr[i + 1], i2 = csr[i + 2], i3 = csr[i + 3];
        uint2 u0 = hb64[(size_t)i0 * 32 + l32];
        uint2 u1 = hb64[(size_t)i1 * 32 + l32];
        uint2 u2 = hb64[(size_t)i2 * 32 + l32];
        uint2 u3 = hb64[(size_t)i3 * 32 + l32];
        ax0 += (bf2f_lo(u0.x) + bf2f_lo(u1.x)) + (bf2f_lo(u2.x) + bf2f_lo(u3.x));
        ay0 += (bf2f_hi(u0.x) + bf2f_hi(u1.x)) + (bf2f_hi(u2.x) + bf2f_hi(u3.x));
        ax1 += (bf2f_lo(u0.y) + bf2f_lo(u1.y)) + (bf2f_lo(u2.y) + bf2f_lo(u3.y));
        ay1 += (bf2f_hi(u0.y) + bf2f_hi(u1.y)) + (bf2f_hi(u2.y) + bf2f_hi(u3.y));
    }
    for (; i < e; i++) {
        uint2 u = hb64[(size_t)csr[i] * 32 + l32];
        ax0 += bf2f_lo(u.x); ay0 += bf2f_hi(u.x);
        ax1 += bf2f_lo(u.y); ay1 += bf2f_hi(u.y);
    }
    float id = invd[n];
    uint2 r;
    r.x = (unsigned int)f2bf(ax0 * id) | ((unsigned int)f2bf(ay0 * id) << 16);
    r.y = (unsigned int)f2bf(ax1 * id) | ((unsigned int)f2bf(ay1 * id) << 16);
    ((uint2*)out)[(size_t)n * 32 + l32] = r;
}

// ---------------- MFMA double GEMM + fused BN1 stats ----------------
// BK=64 (8 barriers), W staged in LDS, bf16 C via coalesced LDS-staged epilogue.
__global__ __launch_bounds__(256) void k_gemm(
        const unsigned short* __restrict__ Bm, const unsigned short* __restrict__ Ar,
        const unsigned short* __restrict__ wcat, const float* __restrict__ bias,
        float* __restrict__ sum8, float* __restrict__ sq8,
        unsigned short* __restrict__ C, int N) {
    __shared__ __align__(16) unsigned short As[128][72];   // 64 k + 8 pad
    __shared__ __align__(16) unsigned short Ws[128][72];
    __shared__ float lds_s[2][128];
    __shared__ float lds_q[2][128];
    int t = threadIdx.x;
    int wave = t >> 6, lane = t & 63;
    int wr = wave >> 1, wc = wave & 1;
    int row0 = blockIdx.x * 128;
    int r = t >> 1, half = t & 1;          // staging: row r, 32-col half
    int lrow = lane & 15, koff = (lane >> 4) * 8;

    f32x4 acc[4][4];
#pragma unroll
    for (int m = 0; m < 4; m++)
#pragma unroll
        for (int n = 0; n < 4; n++) acc[m][n] = (f32x4)(0.f);

    for (int chunk = 0; chunk < 4; chunk++) {
        int kb = chunk * 64;
        // ---- stage A + W (bf16, 64 B per thread each) ----
        int srow = row0 + r;
        int c0 = (kb & 127) + half * 32;
        const unsigned short* src = (kb < 128) ? Bm : Ar;
        uint4 a0, a1, a2, a3;
        if (srow < N) {
            const unsigned short* p = src + (size_t)srow * HID + c0;
            a0 = *(const uint4*)(p);      a1 = *(const uint4*)(p + 8);
            a2 = *(const uint4*)(p + 16); a3 = *(const uint4*)(p + 24);
        } else {
            a0 = a1 = a2 = a3 = make_uint4(0, 0, 0, 0);
        }
        *(uint4*)&As[r][half * 32]      = a0;
        *(uint4*)&As[r][half * 32 + 8]  = a1;
        *(uint4*)&As[r][half * 32 + 16] = a2;
        *(uint4*)&As[r][half * 32 + 24] = a3;
        const unsigned short* wp = wcat + r * 256 + kb + half * 32;
        *(uint4*)&Ws[r][half * 32]      = *(const uint4*)(wp);
        *(uint4*)&Ws[r][half * 32 + 8]  = *(const uint4*)(wp + 8);
        *(uint4*)&Ws[r][half * 32 + 16] = *(const uint4*)(wp + 16);
        *(uint4*)&Ws[r][half * 32 + 24] = *(const uint4*)(wp + 24);
        __syncthreads();

        // ---- MFMA: two k-steps of 32, all operands from LDS ----
#pragma unroll
        for (int ks = 0; ks < 64; ks += 32) {
            short8 af[4], bfr[4];
#pragma unroll
            for (int m = 0; m < 4; m++)
                af[m] = *(const short8*)&As[wr * 64 + m * 16 + lrow][ks + koff];
#pragma unroll
            for (int n = 0; n < 4; n++)
                bfr[n] = *(const short8*)&Ws[wc * 64 + n * 16 + lrow][ks + koff];
#pragma unroll
            for (int m = 0; m < 4; m++)
#pragma unroll
                for (int n = 0; n < 4; n++)
                    acc[m][n] = __builtin_amdgcn_mfma_f32_16x16x32_bf16(af[m], bfr[n], acc[m][n], 0, 0, 0);
        }
        __syncthreads();
    }

    // ---- epilogue: stats (fp32 from acc) + bf16 C via LDS re-stage, coalesced ----
    // Cst aliases the As/Ws region; stride 136 shorts (272 B) keeps uint4 rows 16B-aligned.
    unsigned short* Cst = &As[0][0];
    int cl = lane & 15, rq = (lane >> 4) * 4;
    float cs[4], cq[4];
#pragma unroll
    for (int n = 0; n < 4; n++) {
        int col = wc * 64 + n * 16 + cl;
        float bn = bias[col];
        float s = 0.f, q = 0.f;
#pragma unroll
        for (int m = 0; m < 4; m++) {
#pragma unroll
            for (int reg = 0; reg < 4; reg++) {
                int rl = wr * 64 + m * 16 + rq + reg;
                float v = acc[m][n][reg] + bn;
                Cst[rl * 136 + col] = f2bf(v);
                if (row0 + rl < N) { s += v; q += v * v; }
            }
        }
        cs[n] = s; cq[n] = q;
    }
#pragma unroll
    for (int n = 0; n < 4; n++) {
        float s = cs[n], q = cq[n];
        s += __shfl_xor(s, 16, 64); q += __shfl_xor(q, 16, 64);
        s += __shfl_xor(s, 32, 64); q += __shfl_xor(q, 32, 64);
        if (lane < 16) {
            int col = wc * 64 + n * 16 + cl;   // cl == lane
            lds_s[wr][col] = s;
            lds_q[wr][col] = q;
        }
    }
    __syncthreads();
    if (t < 128) {
        float S = lds_s[0][t] + lds_s[1][t];
        float Q = lds_q[0][t] + lds_q[1][t];
        int slot = (blockIdx.x & 7) * 128 + t;
        atomicAdd(&sum8[slot], S);
        atomicAdd(&sq8[slot], Q);
    }
    // coalesced bf16 C write: 2048 uint4 (128 rows x 16 segs), 8 per thread
#pragma unroll
    for (int j = 0; j < 8; j++) {
        int idx = t + j * 256;
        int rl = idx >> 4, seg = idx & 15;
        int row = row0 + rl;
        if (row < N)
            *(uint4*)(C + (size_t)row * HID + seg * 8) = *(const uint4*)&Cst[rl * 136 + seg * 8];
    }
}

// ---------------- layer 2 dots (bf16 h1): s = relu(bn1(h))·wl2, r = relu(bn1(h))·wr2 ----
__global__ void k_dots(const unsigned short* __restrict__ h, const float* __restrict__ scale,
                       const float* __restrict__ shift, const float* __restrict__ wl2,
                       const float* __restrict__ wr2, float* __restrict__ s_arr,
                       float* __restrict__ r_arr, int N) {
    int w = threadIdx.x >> 6, lid = threadIdx.x & 63;
    int n = blockIdx.x * 4 + w;
    if (n >= N) return;
    unsigned int u = ((const unsigned int*)h)[(size_t)n * 64 + lid];
    float hx = bf2f_lo(u), hy = bf2f_hi(u);
    float2 sc = *(const float2*)&scale[lid * 2];
    float2 sh = *(const float2*)&shift[lid * 2];
    float y0 = fmaxf(0.f, fmaf(hx, sc.x, sh.x));
    float y1 = fmaxf(0.f, fmaf(hy, sc.y, sh.y));
    float2 wl = *(const float2*)&wl2[lid * 2];
    float2 wrv = *(const float2*)&wr2[lid * 2];
    float ps = y0 * wl.x + y1 * wl.y;
    float pr = y0 * wrv.x + y1 * wrv.y;
#pragma unroll
    for (int off = 32; off > 0; off >>= 1) {
        ps += __shfl_down(ps, off, 64);
        pr += __shfl_down(pr, off, 64);
    }
    if (lid == 0) { s_arr[n] = ps; r_arr[n] = pr; }
}

// ---------------- final: scalar mean over edges + sigmoid (4-deep MLP) ----------------
__global__ void k_final2(const float* __restrict__ s_arr, const float* __restrict__ r_arr,
                         const int* __restrict__ rowptr, const int* __restrict__ csr,
                         const float* __restrict__ invd, const float* __restrict__ bl2,
                         float* __restrict__ out, int N) {
    int n = blockIdx.x * blockDim.x + threadIdx.x;
    if (n >= N) return;
    int s = rowptr[n], e = rowptr[n + 1];
    float a = 0.f;
    int i = s;
    for (; i + 4 <= e; i += 4) {
        float a0 = s_arr[csr[i]],     a1 = s_arr[csr[i + 1]];
        float a2 = s_arr[csr[i + 2]], a3 = s_arr[csr[i + 3]];
        a += (a0 + a1) + (a2 + a3);
    }
    for (; i < e; i++) a += s_arr[csr[i]];
    float p = a * invd[n] + r_arr[n] + bl2[0];
    out[n] = 1.f / (1.f + expf(-p));
}

// ---------------- host ----------------
extern "C" void kernel_launch(void* const* d_in, const int* in_sizes, int n_in,
                              void* d_out, int out_size, void* d_ws, size_t ws_size,
                              hipStream_t stream) {
    const float* x   = (const float*)d_in[0];
    const int*   ei  = (const int*)d_in[1];
    const float* wl0 = (const float*)d_in[2];
    const float* bl0 = (const float*)d_in[3];
    const float* wr0 = (const float*)d_in[4];
    const float* g0  = (const float*)d_in[5];
    const float* be0 = (const float*)d_in[6];
    const float* wl1 = (const float*)d_in[7];
    const float* bl1 = (const float*)d_in[8];
    const float* wr1 = (const float*)d_in[9];
    const float* g1  = (const float*)d_in[10];
    const float* be1 = (const float*)d_in[11];
    const float* wl2 = (const float*)d_in[12];
    const float* bl2 = (const float*)d_in[13];
    const float* wr2 = (const float*)d_in[14];
    float* outp = (float*)d_out;

    int N = in_sizes[0] / INDIM;     // 100000
    int E = in_sizes[1] / 2;         // 600000

    char* ws = (char*)d_ws;
    size_t off = 0;
    auto alloc = [&](size_t bytes) { size_t o = off; off = (off + bytes + 255) & ~(size_t)255; return o; };
    int*   degi   = (int*)(ws + alloc((size_t)N * 4));
    int*   rank   = (int*)(ws + alloc((size_t)E * 4));
    int*   rowptr = (int*)(ws + alloc((size_t)(N + 1) * 4));
    int*   csr    = (int*)(ws + alloc((size_t)E * 4));
    float* invd   = (float*)(ws + alloc((size_t)N * 4));
    int*   partial= (int*)(ws + alloc(1024 * 4));
    float* bnbuf  = (float*)(ws + alloc(5120 * 4));
    unsigned short* wcat = (unsigned short*)(ws + alloc(128 * 256 * 2));
    float* sarr   = (float*)(ws + alloc((size_t)N * 4));
    float* rarr   = (float*)(ws + alloc((size_t)N * 4));
    float* mean6  = (float*)(ws + alloc((size_t)N * 6 * 4));
    // bnbuf layout: sum0_8[1024] sq0_8[1024] sum1_8[1024] sq1_8[1024] sc0 sh0 sc1 sh1 [128 each]
    float* sum0_8 = bnbuf;
    float* sq0_8  = bnbuf + 1024;
    float* sum1_8 = bnbuf + 2048;
    float* sq1_8  = bnbuf + 3072;
    float* sc0 = bnbuf + 4096, *sh0 = bnbuf + 4224;
    float* sc1 = bnbuf + 4352, *sh1 = bnbuf + 4480;
    unsigned short* bufB = (unsigned short*)(ws + alloc((size_t)N * HID * 2)); // bf16 gemm out
    unsigned short* bufC = (unsigned short*)(ws + alloc((size_t)N * HID * 2)); // bf16 relu(bn0)
    unsigned short* bufD = (unsigned short*)(ws + alloc((size_t)N * HID * 2)); // bf16 agg mean

    float invN = 1.0f / (float)N;
    int gE = (E + 255) / 256;
    int gN = (N + 255) / 256;
    int gW = (N + 3) / 4;            // wave-per-node kernels
    int gA = (N + 7) / 8;            // agg blocks (8 nodes each, half-wave per node)
    int gL = (N + 31) / 32;          // layer0 blocks (32 nodes each)
    int gS = (N + 127) / 128;        // gemm blocks
    int nbScan = (N + 1023) / 1024;

    // zero degree + BN accumulators in one launch
    k_zero2<<<gN, 256, 0, stream>>>(degi, N, (int*)bnbuf, 4096);

    // weight prep (independent)
    k_prepw<<<128, 256, 0, stream>>>(wl1, wr1, wcat);

    // CSR build (rank-based, atomic-free fill)
    k_deg<<<gE, 256, 0, stream>>>(ei + E, degi, rank, E);
    k_scan_partial<<<nbScan, 256, 0, stream>>>(degi, partial, N);
    k_scan_tops<<<1, 1024, 0, stream>>>(partial, nbScan);
    k_scan_write<<<nbScan, 256, 0, stream>>>(degi, partial, rowptr, N, E);
    k_fill<<<gE, 256, 0, stream>>>(ei, rank, rowptr, csr, E);
    k_invdeg<<<gN, 256, 0, stream>>>(degi, invd, N);

    // layer 0a: gather mean6 + fused BN0 stats (h in-register, discarded)
    k_l0stats<<<gL, 256, 0, stream>>>(x, rowptr, csr, invd, wl0, bl0, wr0, mean6,
                                      sum0_8, sq0_8, N);
    k_bnfin8<<<1, 128, 0, stream>>>(sum0_8, sq0_8, g0, be0, sc0, sh0, invN);

    // layer 0b: recompute h (identical fp32 ops) + BN0+ReLU -> bf16 bufC
    k_l0apply<<<gL, 256, 0, stream>>>(x, mean6, wl0, bl0, wr0, sc0, sh0, bufC, N);

    // layer 1: agg(bufC) -> bufD (bf16) ; MFMA gemm(bufD, bufC) -> bufB (bf16) + BN1 stats
    k_agg_bf<<<gA, 256, 0, stream>>>(bufC, rowptr, csr, invd, bufD, N);
    k_gemm<<<gS, 256, 0, stream>>>(bufD, bufC, wcat, bl1, sum1_8, sq1_8, bufB, N);
    k_bnfin8<<<1, 128, 0, stream>>>(sum1_8, sq1_8, g1, be1, sc1, sh1, invN);

    // layer 2: per-node dots then scalar aggregation + sigmoid
    k_dots<<<gW, 256, 0, stream>>>(bufB, sc1, sh1, wl2, wr2, sarr, rarr, N);
    k_final2<<<gN, 256, 0, stream>>>(sarr, rarr, rowptr, csr, invd, bl2, outp, N);
}

// Round 18
// 187.423 us; speedup vs baseline: 1.1460x; 1.0302x over previous
//
#include <hip/hip_runtime.h>
#include <math.h>

#define HID 128
#define INDIM 6

typedef float4 f4;
typedef __attribute__((ext_vector_type(8))) short short8;
typedef __attribute__((ext_vector_type(4))) float f32x4;

static __device__ inline unsigned short f2bf(float f) {
    union { float f; unsigned int u; } v; v.f = f;
    unsigned int r = v.u + 0x7fffu + ((v.u >> 16) & 1u);   // RNE
    return (unsigned short)(r >> 16);
}
static __device__ inline float bf2f_lo(unsigned int u) {
    union { unsigned int u; float f; } v; v.u = u << 16; return v.f;
}
static __device__ inline float bf2f_hi(unsigned int u) {
    union { unsigned int u; float f; } v; v.u = u & 0xffff0000u; return v.f;
}

// ---------------- utility: zero degi[N] + bnbuf[4096] in one launch ----------------
__global__ void k_zero2(int* a, int na, int* b, int nb) {
    int i = blockIdx.x * blockDim.x + threadIdx.x;
    if (i < na) a[i] = 0;
    if (i < nb) b[i] = 0;
}

// ---------------- degree + per-edge rank ----------------
__global__ void k_deg(const int* dst, int* deg, int* rank, int E) {
    int e = blockIdx.x * blockDim.x + threadIdx.x;
    if (e < E) rank[e] = atomicAdd(&deg[dst[e]], 1);
}

// ---------------- hierarchical exclusive scan (deg -> rowptr) ----------------
__global__ void k_scan_partial(const int* __restrict__ deg, int* __restrict__ partial, int N) {
    __shared__ int lds[256];
    int t = threadIdx.x;
    int base = blockIdx.x * 1024 + t * 4;
    int s = 0;
    if (base + 4 <= N) {
        int4 v = *(const int4*)&deg[base];
        s = v.x + v.y + v.z + v.w;
    } else {
        for (int i = 0; i < 4; i++) if (base + i < N) s += deg[base + i];
    }
    lds[t] = s;
    __syncthreads();
    for (int off = 128; off > 0; off >>= 1) {
        if (t < off) lds[t] += lds[t + off];
        __syncthreads();
    }
    if (t == 0) partial[blockIdx.x] = lds[0];
}

__global__ void k_scan_tops(int* partial, int nb) {
    __shared__ int lds[1024];
    int t = threadIdx.x;
    lds[t] = (t < nb) ? partial[t] : 0;
    __syncthreads();
    for (int off = 1; off < 1024; off <<= 1) {
        int v = (t >= off) ? lds[t - off] : 0;
        __syncthreads();
        lds[t] += v;
        __syncthreads();
    }
    if (t < nb) partial[t] = (t == 0) ? 0 : lds[t - 1];
}

// scan_write + fused invdeg (deg values already in registers here)
__global__ void k_scan_write(const int* __restrict__ deg, const int* __restrict__ partial,
                             int* __restrict__ rowptr, float* __restrict__ invd,
                             int N, int E) {
    __shared__ int lds[256];
    int t = threadIdx.x;
    int base = blockIdx.x * 1024 + t * 4;
    int v0 = 0, v1 = 0, v2 = 0, v3 = 0;
    if (base + 4 <= N) {
        int4 v = *(const int4*)&deg[base];
        v0 = v.x; v1 = v.y; v2 = v.z; v3 = v.w;
    } else {
        if (base + 0 < N) v0 = deg[base + 0];
        if (base + 1 < N) v1 = deg[base + 1];
        if (base + 2 < N) v2 = deg[base + 2];
        if (base + 3 < N) v3 = deg[base + 3];
    }
    lds[t] = v0 + v1 + v2 + v3;
    __syncthreads();
    for (int off = 1; off < 256; off <<= 1) {
        int v = (t >= off) ? lds[t - off] : 0;
        __syncthreads();
        lds[t] += v;
        __syncthreads();
    }
    int run = partial[blockIdx.x] + ((t == 0) ? 0 : lds[t - 1]);
    if (base + 0 < N) { rowptr[base + 0] = run; invd[base + 0] = 1.0f / (float)max(v0, 1); } run += v0;
    if (base + 1 < N) { rowptr[base + 1] = run; invd[base + 1] = 1.0f / (float)max(v1, 1); } run += v1;
    if (base + 2 < N) { rowptr[base + 2] = run; invd[base + 2] = 1.0f / (float)max(v2, 1); } run += v2;
    if (base + 3 < N) { rowptr[base + 3] = run; invd[base + 3] = 1.0f / (float)max(v3, 1); } run += v3;
    if (blockIdx.x == 0 && t == 0) rowptr[N] = E;
}

// ---------------- CSR fill, atomic-free (uses rank from k_deg) ----------------
__global__ void k_fill(const int* ei, const int* rank, const int* rowptr, int* csr, int E) {
    int e = blockIdx.x * blockDim.x + threadIdx.x;
    if (e < E) {
        int d = ei[E + e];
        csr[rowptr[d] + rank[e]] = ei[e];
    }
}

// ---------------- weight prep: concat [Wl1 | Wr1] -> bf16 [128][256] ----------------
__global__ void k_prepw(const float* __restrict__ wl, const float* __restrict__ wr,
                        unsigned short* __restrict__ wcat) {
    int i = blockIdx.x * 256 + threadIdx.x;       // 32768 total
    int o = i >> 8, k = i & 255;
    float v = (k < 128) ? wl[o * 128 + k] : wr[o * 128 + k - 128];
    wcat[i] = f2bf(v);
}

// ---------------- layer 0a: gather mean6 + in-register h for BN0 stats ----------------
__global__ __launch_bounds__(256) void k_l0stats(
        const float* __restrict__ x, const int* __restrict__ rowptr,
        const int* __restrict__ csr, const float* __restrict__ invd,
        const float* __restrict__ wl, const float* __restrict__ bl,
        const float* __restrict__ wr, float* __restrict__ mean6,
        float* __restrict__ sum8, float* __restrict__ sq8, int N) {
    __shared__ float wlds[1600];   // [wl | wr], addr = base + o*6+i + (o>>4)*2  (bank-spread)
    __shared__ float blds[136];    // bias, addr = o + (o>>4)
    __shared__ float mx[32][8];
    __shared__ float xr[32][8];
    __shared__ float ps[4][128];
    __shared__ float pq[4][128];
    int t = threadIdx.x;
    for (int idx = t; idx < 1536; idx += 256) {
        int half = idx >= 768 ? 1 : 0;
        int lin = idx - half * 768;
        int o = lin / 6, i = lin - o * 6;
        float v = half ? wr[lin] : wl[lin];
        wlds[half * 800 + o * 6 + i + (o >> 4) * 2] = v;
    }
    if (t < 128) blds[t + (t >> 4)] = bl[t];
    int nl = t >> 3, f = t & 7;
    int n = blockIdx.x * 32 + nl;
    bool valid = n < N;
    if (f < 6) {
        float mean = 0.f, xv = 0.f;
        if (valid) {
            int s = rowptr[n], e = rowptr[n + 1];
            float acc = 0.f;
            int i = s;
            for (; i + 4 <= e; i += 4) {           // 4-deep MLP unroll
                int i0 = csr[i], i1 = csr[i + 1], i2 = csr[i + 2], i3 = csr[i + 3];
                float a0 = x[i0 * 6 + f], a1 = x[i1 * 6 + f];
                float a2 = x[i2 * 6 + f], a3 = x[i3 * 6 + f];
                acc += (a0 + a1) + (a2 + a3);
            }
            for (; i < e; i++) acc += x[csr[i] * 6 + f];
            mean = acc * invd[n];
            xv = x[n * 6 + f];
            mean6[n * 6 + f] = mean;
        }
        mx[nl][f] = mean;
        xr[nl][f] = xv;
    }
    __syncthreads();
    float m0 = mx[nl][0], m1 = mx[nl][1], m2 = mx[nl][2];
    float m3 = mx[nl][3], m4 = mx[nl][4], m5 = mx[nl][5];
    float r0 = xr[nl][0], r1 = xr[nl][1], r2 = xr[nl][2];
    float r3 = xr[nl][3], r4 = xr[nl][4], r5 = xr[nl][5];
    const float* wA = wlds;
    const float* wB = wlds + 800;
    int wv = t >> 6, lane = t & 63;
#pragma unroll
    for (int k = 0; k < 16; k++) {                 // inline reduce: no sk/qk arrays
        int o = f * 16 + k;
        int wb = 98 * f + 6 * k;                   // o*6 + (o>>4)*2
        float h = blds[o + f];                     // o + (o>>4), o>>4 == f
        h += m0 * wA[wb] + m1 * wA[wb + 1] + m2 * wA[wb + 2]
           + m3 * wA[wb + 3] + m4 * wA[wb + 4] + m5 * wA[wb + 5];
        h += r0 * wB[wb] + r1 * wB[wb + 1] + r2 * wB[wb + 2]
           + r3 * wB[wb + 3] + r4 * wB[wb + 4] + r5 * wB[wb + 5];
        float s = valid ? h : 0.f;
        float q = s * s;
        s += __shfl_xor(s, 8, 64);  q += __shfl_xor(q, 8, 64);
        s += __shfl_xor(s, 16, 64); q += __shfl_xor(q, 16, 64);
        s += __shfl_xor(s, 32, 64); q += __shfl_xor(q, 32, 64);
        if (lane < 8) { ps[wv][lane * 16 + k] = s; pq[wv][lane * 16 + k] = q; }
    }
    __syncthreads();
    if (t < 128) {
        float S = ps[0][t] + ps[1][t] + ps[2][t] + ps[3][t];
        float Q = pq[0][t] + pq[1][t] + pq[2][t] + pq[3][t];
        int slot = (blockIdx.x & 7) * 128 + t;
        atomicAdd(&sum8[slot], S);
        atomicAdd(&sq8[slot], Q);
    }
}

// ---------------- layer 0b: recompute h (identical code) + BN0+ReLU -> bf16 ----------
__global__ __launch_bounds__(256) void k_l0apply(
        const float* __restrict__ x, const float* __restrict__ mean6,
        const float* __restrict__ wl, const float* __restrict__ bl,
        const float* __restrict__ wr, const float* __restrict__ scale,
        const float* __restrict__ shift, unsigned short* __restrict__ out, int N) {
    __shared__ float wlds[1600];
    __shared__ float blds[136];
    __shared__ float sclds[136];
    __shared__ float shlds[136];
    __shared__ float mx[32][8];
    __shared__ float xr[32][8];
    int t = threadIdx.x;
    for (int idx = t; idx < 1536; idx += 256) {
        int half = idx >= 768 ? 1 : 0;
        int lin = idx - half * 768;
        int o = lin / 6, i = lin - o * 6;
        float v = half ? wr[lin] : wl[lin];
        wlds[half * 800 + o * 6 + i + (o >> 4) * 2] = v;
    }
    if (t < 128) {
        blds[t + (t >> 4)]  = bl[t];
        sclds[t + (t >> 4)] = scale[t];
        shlds[t + (t >> 4)] = shift[t];
    }
    int nl = t >> 3, f = t & 7;
    int n = blockIdx.x * 32 + nl;
    bool valid = n < N;
    if (f < 6) {
        mx[nl][f] = valid ? mean6[n * 6 + f] : 0.f;
        xr[nl][f] = valid ? x[n * 6 + f] : 0.f;
    }
    __syncthreads();
    if (!valid) return;
    float m0 = mx[nl][0], m1 = mx[nl][1], m2 = mx[nl][2];
    float m3 = mx[nl][3], m4 = mx[nl][4], m5 = mx[nl][5];
    float r0 = xr[nl][0], r1 = xr[nl][1], r2 = xr[nl][2];
    float r3 = xr[nl][3], r4 = xr[nl][4], r5 = xr[nl][5];
    const float* wA = wlds;
    const float* wB = wlds + 800;
    unsigned short pk[16];
#pragma unroll
    for (int k4 = 0; k4 < 4; k4++) {
#pragma unroll
        for (int j = 0; j < 4; j++) {
            int k = k4 * 4 + j;
            int o = f * 16 + k;
            int wb = 98 * f + 6 * k;
            float h = blds[o + f];              // identical expression tree to k_l0stats
            h += m0 * wA[wb] + m1 * wA[wb + 1] + m2 * wA[wb + 2]
               + m3 * wA[wb + 3] + m4 * wA[wb + 4] + m5 * wA[wb + 5];
            h += r0 * wB[wb] + r1 * wB[wb + 1] + r2 * wB[wb + 2]
               + r3 * wB[wb + 3] + r4 * wB[wb + 4] + r5 * wB[wb + 5];
            pk[k] = f2bf(fmaxf(0.f, fmaf(h, sclds[o + f], shlds[o + f])));
        }
    }
    unsigned short* dst = out + (size_t)n * HID + f * 16;
    *(uint4*)(dst)     = *(const uint4*)&pk[0];
    *(uint4*)(dst + 8) = *(const uint4*)&pk[8];
}

// ---------------- BN finalize from 8-copy accumulators ----------------
__global__ void k_bnfin8(const float* sum8, const float* sq8, const float* g, const float* b,
                         float* scale, float* shift, float invN) {
    int t = threadIdx.x;
    float s = 0.f, q = 0.f;
    for (int c = 0; c < 8; c++) { s += sum8[c * 128 + t]; q += sq8[c * 128 + t]; }
    float mu  = s * invN;
    float var = q * invN - mu * mu;
    float sc  = g[t] * rsqrtf(var + 1e-5f);
    scale[t] = sc;
    shift[t] = b[t] - mu * sc;
}

// ---------------- bf16 mean aggregation: quarter-wave per node, uint4 lanes, 4-deep ----
// 16 lanes x 16 B cover a 256 B row; 4 nodes/wave -> 16 rows in flight per wave.
// Per-feature edge-sum order identical to previous version -> bit-identical output.
__global__ void k_agg_bf(const unsigned short* __restrict__ hb, const int* __restrict__ rowptr,
                         const int* __restrict__ csr, const float* __restrict__ invd,
                         unsigned short* __restrict__ out, int N) {
    int t = threadIdx.x;
    int w = t >> 6, lid = t & 63;
    int q = lid >> 4, l16 = lid & 15;
    int n = blockIdx.x * 16 + w * 4 + q;
    if (n >= N) return;
    int s = rowptr[n], e = rowptr[n + 1];
    const uint4* hb128 = (const uint4*)hb;         // row stride = 16 uint4 (256 B)
    float ax0 = 0.f, ay0 = 0.f, ax1 = 0.f, ay1 = 0.f;
    float ax2 = 0.f, ay2 = 0.f, ax3 = 0.f, ay3 = 0.f;
    int i = s;
    for (; i + 4 <= e; i += 4) {                   // 4 rows x 4 nodes/wave in flight
        int i0 = csr[i], i1 = csr[i + 1], i2 = csr[i + 2], i3 = csr[i + 3];
        uint4 u0 = hb128[(size_t)i0 * 16 + l16];
        uint4 u1 = hb128[(size_t)i1 * 16 + l16];
        uint4 u2 = hb128[(size_t)i2 * 16 + l16];
        uint4 u3 = hb128[(size_t)i3 * 16 + l16];
        ax0 += (bf2f_lo(u0.x) + bf2f_lo(u1.x)) + (bf2f_lo(u2.x) + bf2f_lo(u3.x));
        ay0 += (bf2f_hi(u0.x) + bf2f_hi(u1.x)) + (bf2f_hi(u2.x) + bf2f_hi(u3.x));
        ax1 += (bf2f_lo(u0.y) + bf2f_lo(u1.y)) + (bf2f_lo(u2.y) + bf2f_lo(u3.y));
        ay1 += (bf2f_hi(u0.y) + bf2f_hi(u1.y)) + (bf2f_hi(u2.y) + bf2f_hi(u3.y));
        ax2 += (bf2f_lo(u0.z) + bf2f_lo(u1.z)) + (bf2f_lo(u2.z) + bf2f_lo(u3.z));
        ay2 += (bf2f_hi(u0.z) + bf2f_hi(u1.z)) + (bf2f_hi(u2.z) + bf2f_hi(u3.z));
        ax3 += (bf2f_lo(u0.w) + bf2f_lo(u1.w)) + (bf2f_lo(u2.w) + bf2f_lo(u3.w));
        ay3 += (bf2f_hi(u0.w) + bf2f_hi(u1.w)) + (bf2f_hi(u2.w) + bf2f_hi(u3.w));
    }
    for (; i < e; i++) {
        uint4 u = hb128[(size_t)csr[i] * 16 + l16];
        ax0 += bf2f_lo(u.x); ay0 += bf2f_hi(u.x);
        ax1 += bf2f_lo(u.y); ay1 += bf2f_hi(u.y);
        ax2 += bf2f_lo(u.z); ay2 += bf2f_hi(u.z);
        ax3 += bf2f_lo(u.w); ay3 += bf2f_hi(u.w);
    }
    float id = invd[n];
    uint4 r;
    r.x = (unsigned int)f2bf(ax0 * id) | ((unsigned int)f2bf(ay0 * id) << 16);
    r.y = (unsigned int)f2bf(ax1 * id) | ((unsigned int)f2bf(ay1 * id) << 16);
    r.z = (unsigned int)f2bf(ax2 * id) | ((unsigned int)f2bf(ay2 * id) << 16);
    r.w = (unsigned int)f2bf(ax3 * id) | ((unsigned int)f2bf(ay3 * id) << 16);
    ((uint4*)out)[(size_t)n * 16 + l16] = r;
}

// ---------------- MFMA double GEMM + fused BN1 stats ----------------
// BK=64 (8 barriers), W staged in LDS, bf16 C via coalesced LDS-staged epilogue.
__global__ __launch_bounds__(256) void k_gemm(
        const unsigned short* __restrict__ Bm, const unsigned short* __restrict__ Ar,
        const unsigned short* __restrict__ wcat, const float* __restrict__ bias,
        float* __restrict__ sum8, float* __restrict__ sq8,
        unsigned short* __restrict__ C, int N) {
    __shared__ __align__(16) unsigned short As[128][72];   // 64 k + 8 pad
    __shared__ __align__(16) unsigned short Ws[128][72];
    __shared__ float lds_s[2][128];
    __shared__ float lds_q[2][128];
    int t = threadIdx.x;
    int wave = t >> 6, lane = t & 63;
    int wr = wave >> 1, wc = wave & 1;
    int row0 = blockIdx.x * 128;
    int r = t >> 1, half = t & 1;          // staging: row r, 32-col half
    int lrow = lane & 15, koff = (lane >> 4) * 8;

    f32x4 acc[4][4];
#pragma unroll
    for (int m = 0; m < 4; m++)
#pragma unroll
        for (int n = 0; n < 4; n++) acc[m][n] = (f32x4)(0.f);

    for (int chunk = 0; chunk < 4; chunk++) {
        int kb = chunk * 64;
        // ---- stage A + W (bf16, 64 B per thread each) ----
        int srow = row0 + r;
        int c0 = (kb & 127) + half * 32;
        const unsigned short* src = (kb < 128) ? Bm : Ar;
        uint4 a0, a1, a2, a3;
        if (srow < N) {
            const unsigned short* p = src + (size_t)srow * HID + c0;
            a0 = *(const uint4*)(p);      a1 = *(const uint4*)(p + 8);
            a2 = *(const uint4*)(p + 16); a3 = *(const uint4*)(p + 24);
        } else {
            a0 = a1 = a2 = a3 = make_uint4(0, 0, 0, 0);
        }
        *(uint4*)&As[r][half * 32]      = a0;
        *(uint4*)&As[r][half * 32 + 8]  = a1;
        *(uint4*)&As[r][half * 32 + 16] = a2;
        *(uint4*)&As[r][half * 32 + 24] = a3;
        const unsigned short* wp = wcat + r * 256 + kb + half * 32;
        *(uint4*)&Ws[r][half * 32]      = *(const uint4*)(wp);
        *(uint4*)&Ws[r][half * 32 + 8]  = *(const uint4*)(wp + 8);
        *(uint4*)&Ws[r][half * 32 + 16] = *(const uint4*)(wp + 16);
        *(uint4*)&Ws[r][half * 32 + 24] = *(const uint4*)(wp + 24);
        __syncthreads();

        // ---- MFMA: two k-steps of 32, all operands from LDS ----
#pragma unroll
        for (int ks = 0; ks < 64; ks += 32) {
            short8 af[4], bfr[4];
#pragma unroll
            for (int m = 0; m < 4; m++)
                af[m] = *(const short8*)&As[wr * 64 + m * 16 + lrow][ks + koff];
#pragma unroll
            for (int n = 0; n < 4; n++)
                bfr[n] = *(const short8*)&Ws[wc * 64 + n * 16 + lrow][ks + koff];
#pragma unroll
            for (int m = 0; m < 4; m++)
#pragma unroll
                for (int n = 0; n < 4; n++)
                    acc[m][n] = __builtin_amdgcn_mfma_f32_16x16x32_bf16(af[m], bfr[n], acc[m][n], 0, 0, 0);
        }
        __syncthreads();
    }

    // ---- epilogue: stats (fp32 from acc) + bf16 C via LDS re-stage, coalesced ----
    unsigned short* Cst = &As[0][0];
    int cl = lane & 15, rq = (lane >> 4) * 4;
    float cs[4], cq[4];
#pragma unroll
    for (int n = 0; n < 4; n++) {
        int col = wc * 64 + n * 16 + cl;
        float bn = bias[col];
        float s = 0.f, q = 0.f;
#pragma unroll
        for (int m = 0; m < 4; m++) {
#pragma unroll
            for (int reg = 0; reg < 4; reg++) {
                int rl = wr * 64 + m * 16 + rq + reg;
                float v = acc[m][n][reg] + bn;
                Cst[rl * 136 + col] = f2bf(v);
                if (row0 + rl < N) { s += v; q += v * v; }
            }
        }
        cs[n] = s; cq[n] = q;
    }
#pragma unroll
    for (int n = 0; n < 4; n++) {
        float s = cs[n], q = cq[n];
        s += __shfl_xor(s, 16, 64); q += __shfl_xor(q, 16, 64);
        s += __shfl_xor(s, 32, 64); q += __shfl_xor(q, 32, 64);
        if (lane < 16) {
            int col = wc * 64 + n * 16 + cl;   // cl == lane
            lds_s[wr][col] = s;
            lds_q[wr][col] = q;
        }
    }
    __syncthreads();
    if (t < 128) {
        float S = lds_s[0][t] + lds_s[1][t];
        float Q = lds_q[0][t] + lds_q[1][t];
        int slot = (blockIdx.x & 7) * 128 + t;
        atomicAdd(&sum8[slot], S);
        atomicAdd(&sq8[slot], Q);
    }
    // coalesced bf16 C write: 2048 uint4 (128 rows x 16 segs), 8 per thread
#pragma unroll
    for (int j = 0; j < 8; j++) {
        int idx = t + j * 256;
        int rl = idx >> 4, seg = idx & 15;
        int row = row0 + rl;
        if (row < N)
            *(uint4*)(C + (size_t)row * HID + seg * 8) = *(const uint4*)&Cst[rl * 136 + seg * 8];
    }
}

// ---------------- layer 2 dots (bf16 h1): s = relu(bn1(h))·wl2, r = relu(bn1(h))·wr2 ----
__global__ void k_dots(const unsigned short* __restrict__ h, const float* __restrict__ scale,
                       const float* __restrict__ shift, const float* __restrict__ wl2,
                       const float* __restrict__ wr2, float* __restrict__ s_arr,
                       float* __restrict__ r_arr, int N) {
    int w = threadIdx.x >> 6, lid = threadIdx.x & 63;
    int n = blockIdx.x * 4 + w;
    if (n >= N) return;
    unsigned int u = ((const unsigned int*)h)[(size_t)n * 64 + lid];
    float hx = bf2f_lo(u), hy = bf2f_hi(u);
    float2 sc = *(const float2*)&scale[lid * 2];
    float2 sh = *(const float2*)&shift[lid * 2];
    float y0 = fmaxf(0.f, fmaf(hx, sc.x, sh.x));
    float y1 = fmaxf(0.f, fmaf(hy, sc.y, sh.y));
    float2 wl = *(const float2*)&wl2[lid * 2];
    float2 wrv = *(const float2*)&wr2[lid * 2];
    float ps = y0 * wl.x + y1 * wl.y;
    float pr = y0 * wrv.x + y1 * wrv.y;
#pragma unroll
    for (int off = 32; off > 0; off >>= 1) {
        ps += __shfl_down(ps, off, 64);
        pr += __shfl_down(pr, off, 64);
    }
    if (lid == 0) { s_arr[n] = ps; r_arr[n] = pr; }
}

// ---------------- final: scalar mean over edges + sigmoid (4-deep MLP) ----------------
__global__ void k_final2(const float* __restrict__ s_arr, const float* __restrict__ r_arr,
                         const int* __restrict__ rowptr, const int* __restrict__ csr,
                         const float* __restrict__ invd, const float* __restrict__ bl2,
                         float* __restrict__ out, int N) {
    int n = blockIdx.x * blockDim.x + threadIdx.x;
    if (n >= N) return;
    int s = rowptr[n], e = rowptr[n + 1];
    float a = 0.f;
    int i = s;
    for (; i + 4 <= e; i += 4) {
        float a0 = s_arr[csr[i]],     a1 = s_arr[csr[i + 1]];
        float a2 = s_arr[csr[i + 2]], a3 = s_arr[csr[i + 3]];
        a += (a0 + a1) + (a2 + a3);
    }
    for (; i < e; i++) a += s_arr[csr[i]];
    float p = a * invd[n] + r_arr[n] + bl2[0];
    out[n] = 1.f / (1.f + expf(-p));
}

// ---------------- host ----------------
extern "C" void kernel_launch(void* const* d_in, const int* in_sizes, int n_in,
                              void* d_out, int out_size, void* d_ws, size_t ws_size,
                              hipStream_t stream) {
    const float* x   = (const float*)d_in[0];
    const int*   ei  = (const int*)d_in[1];
    const float* wl0 = (const float*)d_in[2];
    const float* bl0 = (const float*)d_in[3];
    const float* wr0 = (const float*)d_in[4];
    const float* g0  = (const float*)d_in[5];
    const float* be0 = (const float*)d_in[6];
    const float* wl1 = (const float*)d_in[7];
    const float* bl1 = (const float*)d_in[8];
    const float* wr1 = (const float*)d_in[9];
    const float* g1  = (const float*)d_in[10];
    const float* be1 = (const float*)d_in[11];
    const float* wl2 = (const float*)d_in[12];
    const float* bl2 = (const float*)d_in[13];
    const float* wr2 = (const float*)d_in[14];
    float* outp = (float*)d_out;

    int N = in_sizes[0] / INDIM;     // 100000
    int E = in_sizes[1] / 2;         // 600000

    char* ws = (char*)d_ws;
    size_t off = 0;
    auto alloc = [&](size_t bytes) { size_t o = off; off = (off + bytes + 255) & ~(size_t)255; return o; };
    int*   degi   = (int*)(ws + alloc((size_t)N * 4));
    int*   rank   = (int*)(ws + alloc((size_t)E * 4));
    int*   rowptr = (int*)(ws + alloc((size_t)(N + 1) * 4));
    int*   csr    = (int*)(ws + alloc((size_t)E * 4));
    float* invd   = (float*)(ws + alloc((size_t)N * 4));
    int*   partial= (int*)(ws + alloc(1024 * 4));
    float* bnbuf  = (float*)(ws + alloc(5120 * 4));
    unsigned short* wcat = (unsigned short*)(ws + alloc(128 * 256 * 2));
    float* sarr   = (float*)(ws + alloc((size_t)N * 4));
    float* rarr   = (float*)(ws + alloc((size_t)N * 4));
    float* mean6  = (float*)(ws + alloc((size_t)N * 6 * 4));
    float* sum0_8 = bnbuf;
    float* sq0_8  = bnbuf + 1024;
    float* sum1_8 = bnbuf + 2048;
    float* sq1_8  = bnbuf + 3072;
    float* sc0 = bnbuf + 4096, *sh0 = bnbuf + 4224;
    float* sc1 = bnbuf + 4352, *sh1 = bnbuf + 4480;
    unsigned short* bufB = (unsigned short*)(ws + alloc((size_t)N * HID * 2)); // bf16 gemm out
    unsigned short* bufC = (unsigned short*)(ws + alloc((size_t)N * HID * 2)); // bf16 relu(bn0)
    unsigned short* bufD = (unsigned short*)(ws + alloc((size_t)N * HID * 2)); // bf16 agg mean

    float invN = 1.0f / (float)N;
    int gE = (E + 255) / 256;
    int gN = (N + 255) / 256;
    int gW = (N + 3) / 4;            // wave-per-node kernels
    int gA = (N + 15) / 16;          // agg blocks (16 nodes each, quarter-wave per node)
    int gL = (N + 31) / 32;          // layer0 blocks (32 nodes each)
    int gS = (N + 127) / 128;        // gemm blocks
    int nbScan = (N + 1023) / 1024;

    // zero degree + BN accumulators in one launch
    k_zero2<<<gN, 256, 0, stream>>>(degi, N, (int*)bnbuf, 4096);

    // weight prep (independent)
    k_prepw<<<128, 256, 0, stream>>>(wl1, wr1, wcat);

    // CSR build (rank-based, atomic-free fill; invdeg fused into scan_write)
    k_deg<<<gE, 256, 0, stream>>>(ei + E, degi, rank, E);
    k_scan_partial<<<nbScan, 256, 0, stream>>>(degi, partial, N);
    k_scan_tops<<<1, 1024, 0, stream>>>(partial, nbScan);
    k_scan_write<<<nbScan, 256, 0, stream>>>(degi, partial, rowptr, invd, N, E);
    k_fill<<<gE, 256, 0, stream>>>(ei, rank, rowptr, csr, E);

    // layer 0a: gather mean6 + fused BN0 stats (h in-register, discarded)
    k_l0stats<<<gL, 256, 0, stream>>>(x, rowptr, csr, invd, wl0, bl0, wr0, mean6,
                                      sum0_8, sq0_8, N);
    k_bnfin8<<<1, 128, 0, stream>>>(sum0_8, sq0_8, g0, be0, sc0, sh0, invN);

    // layer 0b: recompute h (identical fp32 ops) + BN0+ReLU -> bf16 bufC
    k_l0apply<<<gL, 256, 0, stream>>>(x, mean6, wl0, bl0, wr0, sc0, sh0, bufC, N);

    // layer 1: agg(bufC) -> bufD (bf16) ; MFMA gemm(bufD, bufC) -> bufB (bf16) + BN1 stats
    k_agg_bf<<<gA, 256, 0, stream>>>(bufC, rowptr, csr, invd, bufD, N);
    k_gemm<<<gS, 256, 0, stream>>>(bufD, bufC, wcat, bl1, sum1_8, sq1_8, bufB, N);
    k_bnfin8<<<1, 128, 0, stream>>>(sum1_8, sq1_8, g1, be1, sc1, sh1, invN);

    // layer 2: per-node dots then scalar aggregation + sigmoid
    k_dots<<<gW, 256, 0, stream>>>(bufB, sc1, sh1, wl2, wr2, sarr, rarr, N);
    k_final2<<<gN, 256, 0, stream>>>(sarr, rarr, rowptr, csr, invd, bl2, outp, N);
}

// Round 19
// 182.233 us; speedup vs baseline: 1.1786x; 1.0285x over previous
//
#include <hip/hip_runtime.h>
#include <math.h>

#define HID 128
#define INDIM 6

typedef float4 f4;
typedef __attribute__((ext_vector_type(8))) short short8;
typedef __attribute__((ext_vector_type(4))) float f32x4;

static __device__ inline unsigned short f2bf(float f) {
    union { float f; unsigned int u; } v; v.f = f;
    unsigned int r = v.u + 0x7fffu + ((v.u >> 16) & 1u);   // RNE
    return (unsigned short)(r >> 16);
}
static __device__ inline float bf2f_lo(unsigned int u) {
    union { unsigned int u; float f; } v; v.u = u << 16; return v.f;
}
static __device__ inline float bf2f_hi(unsigned int u) {
    union { unsigned int u; float f; } v; v.u = u & 0xffff0000u; return v.f;
}

// ---------------- init: zero degi + bnbuf, prep bf16 wcat (fused, one launch) ---------
__global__ void k_init(int* a, int na, int* b, int nb,
                       const float* __restrict__ wl, const float* __restrict__ wr,
                       unsigned short* __restrict__ wcat) {
    int i = blockIdx.x * blockDim.x + threadIdx.x;
    if (i < na) a[i] = 0;
    if (i < nb) b[i] = 0;
    if (i < 32768) {
        int o = i >> 8, k = i & 255;
        float v = (k < 128) ? wl[o * 128 + k] : wr[o * 128 + k - 128];
        wcat[i] = f2bf(v);
    }
}

// ---------------- degree + per-edge rank ----------------
__global__ void k_deg(const int* dst, int* deg, int* rank, int E) {
    int e = blockIdx.x * blockDim.x + threadIdx.x;
    if (e < E) rank[e] = atomicAdd(&deg[dst[e]], 1);
}

// ---------------- hierarchical exclusive scan (deg -> rowptr) ----------------
__global__ void k_scan_partial(const int* __restrict__ deg, int* __restrict__ partial, int N) {
    __shared__ int lds[256];
    int t = threadIdx.x;
    int base = blockIdx.x * 1024 + t * 4;
    int s = 0;
    if (base + 4 <= N) {
        int4 v = *(const int4*)&deg[base];
        s = v.x + v.y + v.z + v.w;
    } else {
        for (int i = 0; i < 4; i++) if (base + i < N) s += deg[base + i];
    }
    lds[t] = s;
    __syncthreads();
    for (int off = 128; off > 0; off >>= 1) {
        if (t < off) lds[t] += lds[t + off];
        __syncthreads();
    }
    if (t == 0) partial[blockIdx.x] = lds[0];
}

__global__ void k_scan_tops(int* partial, int nb) {
    __shared__ int lds[1024];
    int t = threadIdx.x;
    lds[t] = (t < nb) ? partial[t] : 0;
    __syncthreads();
    for (int off = 1; off < 1024; off <<= 1) {
        int v = (t >= off) ? lds[t - off] : 0;
        __syncthreads();
        lds[t] += v;
        __syncthreads();
    }
    if (t < nb) partial[t] = (t == 0) ? 0 : lds[t - 1];
}

// scan_write + fused invdeg (deg values already in registers here)
__global__ void k_scan_write(const int* __restrict__ deg, const int* __restrict__ partial,
                             int* __restrict__ rowptr, float* __restrict__ invd,
                             int N, int E) {
    __shared__ int lds[256];
    int t = threadIdx.x;
    int base = blockIdx.x * 1024 + t * 4;
    int v0 = 0, v1 = 0, v2 = 0, v3 = 0;
    if (base + 4 <= N) {
        int4 v = *(const int4*)&deg[base];
        v0 = v.x; v1 = v.y; v2 = v.z; v3 = v.w;
    } else {
        if (base + 0 < N) v0 = deg[base + 0];
        if (base + 1 < N) v1 = deg[base + 1];
        if (base + 2 < N) v2 = deg[base + 2];
        if (base + 3 < N) v3 = deg[base + 3];
    }
    lds[t] = v0 + v1 + v2 + v3;
    __syncthreads();
    for (int off = 1; off < 256; off <<= 1) {
        int v = (t >= off) ? lds[t - off] : 0;
        __syncthreads();
        lds[t] += v;
        __syncthreads();
    }
    int run = partial[blockIdx.x] + ((t == 0) ? 0 : lds[t - 1]);
    if (base + 0 < N) { rowptr[base + 0] = run; invd[base + 0] = 1.0f / (float)max(v0, 1); } run += v0;
    if (base + 1 < N) { rowptr[base + 1] = run; invd[base + 1] = 1.0f / (float)max(v1, 1); } run += v1;
    if (base + 2 < N) { rowptr[base + 2] = run; invd[base + 2] = 1.0f / (float)max(v2, 1); } run += v2;
    if (base + 3 < N) { rowptr[base + 3] = run; invd[base + 3] = 1.0f / (float)max(v3, 1); } run += v3;
    if (blockIdx.x == 0 && t == 0) rowptr[N] = E;
}

// ---------------- CSR fill, atomic-free (uses rank from k_deg) ----------------
__global__ void k_fill(const int* ei, const int* rank, const int* rowptr, int* csr, int E) {
    int e = blockIdx.x * blockDim.x + threadIdx.x;
    if (e < E) {
        int d = ei[E + e];
        csr[rowptr[d] + rank[e]] = ei[e];
    }
}

// ---------------- layer 0a: gather mean6 + in-register h for BN0 stats ----------------
__global__ __launch_bounds__(256) void k_l0stats(
        const float* __restrict__ x, const int* __restrict__ rowptr,
        const int* __restrict__ csr, const float* __restrict__ invd,
        const float* __restrict__ wl, const float* __restrict__ bl,
        const float* __restrict__ wr, float* __restrict__ mean6,
        float* __restrict__ sum8, float* __restrict__ sq8, int N) {
    __shared__ float wlds[1600];   // [wl | wr], addr = base + o*6+i + (o>>4)*2  (bank-spread)
    __shared__ float blds[136];    // bias, addr = o + (o>>4)
    __shared__ float mx[32][8];
    __shared__ float xr[32][8];
    __shared__ float ps[4][128];
    __shared__ float pq[4][128];
    int t = threadIdx.x;
    for (int idx = t; idx < 1536; idx += 256) {
        int half = idx >= 768 ? 1 : 0;
        int lin = idx - half * 768;
        int o = lin / 6, i = lin - o * 6;
        float v = half ? wr[lin] : wl[lin];
        wlds[half * 800 + o * 6 + i + (o >> 4) * 2] = v;
    }
    if (t < 128) blds[t + (t >> 4)] = bl[t];
    int nl = t >> 3, f = t & 7;
    int n = blockIdx.x * 32 + nl;
    bool valid = n < N;
    if (f < 6) {
        float mean = 0.f, xv = 0.f;
        if (valid) {
            int s = rowptr[n], e = rowptr[n + 1];
            float acc = 0.f;
            int i = s;
            for (; i + 4 <= e; i += 4) {           // 4-deep MLP unroll
                int i0 = csr[i], i1 = csr[i + 1], i2 = csr[i + 2], i3 = csr[i + 3];
                float a0 = x[i0 * 6 + f], a1 = x[i1 * 6 + f];
                float a2 = x[i2 * 6 + f], a3 = x[i3 * 6 + f];
                acc += (a0 + a1) + (a2 + a3);
            }
            for (; i < e; i++) acc += x[csr[i] * 6 + f];
            mean = acc * invd[n];
            xv = x[n * 6 + f];
            mean6[n * 6 + f] = mean;
        }
        mx[nl][f] = mean;
        xr[nl][f] = xv;
    }
    __syncthreads();
    float m0 = mx[nl][0], m1 = mx[nl][1], m2 = mx[nl][2];
    float m3 = mx[nl][3], m4 = mx[nl][4], m5 = mx[nl][5];
    float r0 = xr[nl][0], r1 = xr[nl][1], r2 = xr[nl][2];
    float r3 = xr[nl][3], r4 = xr[nl][4], r5 = xr[nl][5];
    const float* wA = wlds;
    const float* wB = wlds + 800;
    int wv = t >> 6, lane = t & 63;
#pragma unroll
    for (int k = 0; k < 16; k++) {                 // inline reduce: no sk/qk arrays
        int o = f * 16 + k;
        int wb = 98 * f + 6 * k;                   // o*6 + (o>>4)*2
        float h = blds[o + f];                     // o + (o>>4), o>>4 == f
        h += m0 * wA[wb] + m1 * wA[wb + 1] + m2 * wA[wb + 2]
           + m3 * wA[wb + 3] + m4 * wA[wb + 4] + m5 * wA[wb + 5];
        h += r0 * wB[wb] + r1 * wB[wb + 1] + r2 * wB[wb + 2]
           + r3 * wB[wb + 3] + r4 * wB[wb + 4] + r5 * wB[wb + 5];
        float s = valid ? h : 0.f;
        float q = s * s;
        s += __shfl_xor(s, 8, 64);  q += __shfl_xor(q, 8, 64);
        s += __shfl_xor(s, 16, 64); q += __shfl_xor(q, 16, 64);
        s += __shfl_xor(s, 32, 64); q += __shfl_xor(q, 32, 64);
        if (lane < 8) { ps[wv][lane * 16 + k] = s; pq[wv][lane * 16 + k] = q; }
    }
    __syncthreads();
    if (t < 128) {
        float S = ps[0][t] + ps[1][t] + ps[2][t] + ps[3][t];
        float Q = pq[0][t] + pq[1][t] + pq[2][t] + pq[3][t];
        int slot = (blockIdx.x & 7) * 128 + t;
        atomicAdd(&sum8[slot], S);
        atomicAdd(&sq8[slot], Q);
    }
}

// ---------------- layer 0b: recompute h (identical code) + BN0+ReLU -> bf16 ----------
__global__ __launch_bounds__(256) void k_l0apply(
        const float* __restrict__ x, const float* __restrict__ mean6,
        const float* __restrict__ wl, const float* __restrict__ bl,
        const float* __restrict__ wr, const float* __restrict__ scale,
        const float* __restrict__ shift, unsigned short* __restrict__ out, int N) {
    __shared__ float wlds[1600];
    __shared__ float blds[136];
    __shared__ float sclds[136];
    __shared__ float shlds[136];
    __shared__ float mx[32][8];
    __shared__ float xr[32][8];
    int t = threadIdx.x;
    for (int idx = t; idx < 1536; idx += 256) {
        int half = idx >= 768 ? 1 : 0;
        int lin = idx - half * 768;
        int o = lin / 6, i = lin - o * 6;
        float v = half ? wr[lin] : wl[lin];
        wlds[half * 800 + o * 6 + i + (o >> 4) * 2] = v;
    }
    if (t < 128) {
        blds[t + (t >> 4)]  = bl[t];
        sclds[t + (t >> 4)] = scale[t];
        shlds[t + (t >> 4)] = shift[t];
    }
    int nl = t >> 3, f = t & 7;
    int n = blockIdx.x * 32 + nl;
    bool valid = n < N;
    if (f < 6) {
        mx[nl][f] = valid ? mean6[n * 6 + f] : 0.f;
        xr[nl][f] = valid ? x[n * 6 + f] : 0.f;
    }
    __syncthreads();
    if (!valid) return;
    float m0 = mx[nl][0], m1 = mx[nl][1], m2 = mx[nl][2];
    float m3 = mx[nl][3], m4 = mx[nl][4], m5 = mx[nl][5];
    float r0 = xr[nl][0], r1 = xr[nl][1], r2 = xr[nl][2];
    float r3 = xr[nl][3], r4 = xr[nl][4], r5 = xr[nl][5];
    const float* wA = wlds;
    const float* wB = wlds + 800;
    unsigned short pk[16];
#pragma unroll
    for (int k4 = 0; k4 < 4; k4++) {
#pragma unroll
        for (int j = 0; j < 4; j++) {
            int k = k4 * 4 + j;
            int o = f * 16 + k;
            int wb = 98 * f + 6 * k;
            float h = blds[o + f];              // identical expression tree to k_l0stats
            h += m0 * wA[wb] + m1 * wA[wb + 1] + m2 * wA[wb + 2]
               + m3 * wA[wb + 3] + m4 * wA[wb + 4] + m5 * wA[wb + 5];
            h += r0 * wB[wb] + r1 * wB[wb + 1] + r2 * wB[wb + 2]
               + r3 * wB[wb + 3] + r4 * wB[wb + 4] + r5 * wB[wb + 5];
            pk[k] = f2bf(fmaxf(0.f, fmaf(h, sclds[o + f], shlds[o + f])));
        }
    }
    unsigned short* dst = out + (size_t)n * HID + f * 16;
    *(uint4*)(dst)     = *(const uint4*)&pk[0];
    *(uint4*)(dst + 8) = *(const uint4*)&pk[8];
}

// ---------------- BN finalize from 8-copy accumulators ----------------
__global__ void k_bnfin8(const float* sum8, const float* sq8, const float* g, const float* b,
                         float* scale, float* shift, float invN) {
    int t = threadIdx.x;
    float s = 0.f, q = 0.f;
    for (int c = 0; c < 8; c++) { s += sum8[c * 128 + t]; q += sq8[c * 128 + t]; }
    float mu  = s * invN;
    float var = q * invN - mu * mu;
    float sc  = g[t] * rsqrtf(var + 1e-5f);
    scale[t] = sc;
    shift[t] = b[t] - mu * sc;
}

// ---------------- bf16 mean aggregation: quarter-wave per node, uint4 lanes, 4-deep ----
__global__ void k_agg_bf(const unsigned short* __restrict__ hb, const int* __restrict__ rowptr,
                         const int* __restrict__ csr, const float* __restrict__ invd,
                         unsigned short* __restrict__ out, int N) {
    int t = threadIdx.x;
    int w = t >> 6, lid = t & 63;
    int q = lid >> 4, l16 = lid & 15;
    int n = blockIdx.x * 16 + w * 4 + q;
    if (n >= N) return;
    int s = rowptr[n], e = rowptr[n + 1];
    const uint4* hb128 = (const uint4*)hb;         // row stride = 16 uint4 (256 B)
    float ax0 = 0.f, ay0 = 0.f, ax1 = 0.f, ay1 = 0.f;
    float ax2 = 0.f, ay2 = 0.f, ax3 = 0.f, ay3 = 0.f;
    int i = s;
    for (; i + 4 <= e; i += 4) {                   // 4 rows x 4 nodes/wave in flight
        int i0 = csr[i], i1 = csr[i + 1], i2 = csr[i + 2], i3 = csr[i + 3];
        uint4 u0 = hb128[(size_t)i0 * 16 + l16];
        uint4 u1 = hb128[(size_t)i1 * 16 + l16];
        uint4 u2 = hb128[(size_t)i2 * 16 + l16];
        uint4 u3 = hb128[(size_t)i3 * 16 + l16];
        ax0 += (bf2f_lo(u0.x) + bf2f_lo(u1.x)) + (bf2f_lo(u2.x) + bf2f_lo(u3.x));
        ay0 += (bf2f_hi(u0.x) + bf2f_hi(u1.x)) + (bf2f_hi(u2.x) + bf2f_hi(u3.x));
        ax1 += (bf2f_lo(u0.y) + bf2f_lo(u1.y)) + (bf2f_lo(u2.y) + bf2f_lo(u3.y));
        ay1 += (bf2f_hi(u0.y) + bf2f_hi(u1.y)) + (bf2f_hi(u2.y) + bf2f_hi(u3.y));
        ax2 += (bf2f_lo(u0.z) + bf2f_lo(u1.z)) + (bf2f_lo(u2.z) + bf2f_lo(u3.z));
        ay2 += (bf2f_hi(u0.z) + bf2f_hi(u1.z)) + (bf2f_hi(u2.z) + bf2f_hi(u3.z));
        ax3 += (bf2f_lo(u0.w) + bf2f_lo(u1.w)) + (bf2f_lo(u2.w) + bf2f_lo(u3.w));
        ay3 += (bf2f_hi(u0.w) + bf2f_hi(u1.w)) + (bf2f_hi(u2.w) + bf2f_hi(u3.w));
    }
    for (; i < e; i++) {
        uint4 u = hb128[(size_t)csr[i] * 16 + l16];
        ax0 += bf2f_lo(u.x); ay0 += bf2f_hi(u.x);
        ax1 += bf2f_lo(u.y); ay1 += bf2f_hi(u.y);
        ax2 += bf2f_lo(u.z); ay2 += bf2f_hi(u.z);
        ax3 += bf2f_lo(u.w); ay3 += bf2f_hi(u.w);
    }
    float id = invd[n];
    uint4 r;
    r.x = (unsigned int)f2bf(ax0 * id) | ((unsigned int)f2bf(ay0 * id) << 16);
    r.y = (unsigned int)f2bf(ax1 * id) | ((unsigned int)f2bf(ay1 * id) << 16);
    r.z = (unsigned int)f2bf(ax2 * id) | ((unsigned int)f2bf(ay2 * id) << 16);
    r.w = (unsigned int)f2bf(ax3 * id) | ((unsigned int)f2bf(ay3 * id) << 16);
    ((uint4*)out)[(size_t)n * 16 + l16] = r;
}

// ---------------- MFMA double GEMM + fused BN1 stats (64-row tiles) ----------------
// Tile 64 rows x 128 cols; 4 waves, each 64r x 32c (acc[4][2]); K=256 in 4 chunks of 64.
// Grid 2x denser than 128-row version -> smaller tail, higher occupancy (LDS ~28.7 KB).
__global__ __launch_bounds__(256) void k_gemm(
        const unsigned short* __restrict__ Bm, const unsigned short* __restrict__ Ar,
        const unsigned short* __restrict__ wcat, const float* __restrict__ bias,
        float* __restrict__ sum8, float* __restrict__ sq8,
        unsigned short* __restrict__ C, int N) {
    __shared__ __align__(16) unsigned short As[64][72];    // 64 rows x (64 k + 8 pad)
    __shared__ __align__(16) unsigned short Ws[128][72];   // all 128 cols x 64 k
    __shared__ float lds_s[128];
    __shared__ float lds_q[128];
    int t = threadIdx.x;
    int wave = t >> 6, lane = t & 63;
    int row0 = blockIdx.x * 64;
    int lrow = lane & 15, koff = (lane >> 4) * 8;

    f32x4 acc[4][2];
#pragma unroll
    for (int m = 0; m < 4; m++)
#pragma unroll
        for (int n = 0; n < 2; n++) acc[m][n] = (f32x4)(0.f);

    for (int chunk = 0; chunk < 4; chunk++) {
        int kb = chunk * 64;
        // ---- stage A: 64x64 shorts, 16 shorts (32 B) per thread ----
        int rA = t >> 2, qA = t & 3;
        int srow = row0 + rA;
        int cA = (kb & 127) + qA * 16;
        const unsigned short* src = (kb < 128) ? Bm : Ar;
        uint4 a0, a1;
        if (srow < N) {
            const unsigned short* p = src + (size_t)srow * HID + cA;
            a0 = *(const uint4*)(p); a1 = *(const uint4*)(p + 8);
        } else {
            a0 = a1 = make_uint4(0, 0, 0, 0);
        }
        *(uint4*)&As[rA][qA * 16]     = a0;
        *(uint4*)&As[rA][qA * 16 + 8] = a1;
        // ---- stage W: 128x64 shorts, 32 shorts (64 B) per thread ----
        int rW = t >> 1, hW = t & 1;
        const unsigned short* wp = wcat + rW * 256 + kb + hW * 32;
        *(uint4*)&Ws[rW][hW * 32]      = *(const uint4*)(wp);
        *(uint4*)&Ws[rW][hW * 32 + 8]  = *(const uint4*)(wp + 8);
        *(uint4*)&Ws[rW][hW * 32 + 16] = *(const uint4*)(wp + 16);
        *(uint4*)&Ws[rW][hW * 32 + 24] = *(const uint4*)(wp + 24);
        __syncthreads();

        // ---- MFMA: two k-steps of 32; wave covers cols [wave*32, wave*32+32) ----
#pragma unroll
        for (int ks = 0; ks < 64; ks += 32) {
            short8 af[4], bfr[2];
#pragma unroll
            for (int m = 0; m < 4; m++)
                af[m] = *(const short8*)&As[m * 16 + lrow][ks + koff];
#pragma unroll
            for (int n = 0; n < 2; n++)
                bfr[n] = *(const short8*)&Ws[wave * 32 + n * 16 + lrow][ks + koff];
#pragma unroll
            for (int m = 0; m < 4; m++)
#pragma unroll
                for (int n = 0; n < 2; n++)
                    acc[m][n] = __builtin_amdgcn_mfma_f32_16x16x32_bf16(af[m], bfr[n], acc[m][n], 0, 0, 0);
        }
        __syncthreads();
    }

    // ---- epilogue: stats (fp32 from acc) + bf16 C via LDS re-stage (in Ws), coalesced --
    unsigned short* Cst = &Ws[0][0];   // 64 rows x 136 stride = 17408 B <= 18432 B
    int cl = lane & 15, rq = (lane >> 4) * 4;
#pragma unroll
    for (int n = 0; n < 2; n++) {
        int col = wave * 32 + n * 16 + cl;
        float bn = bias[col];
        float s = 0.f, q = 0.f;
#pragma unroll
        for (int m = 0; m < 4; m++) {
#pragma unroll
            for (int reg = 0; reg < 4; reg++) {
                int rl = m * 16 + rq + reg;
                float v = acc[m][n][reg] + bn;
                Cst[rl * 136 + col] = f2bf(v);
                if (row0 + rl < N) { s += v; q += v * v; }
            }
        }
        // reduce over row-groups (lane bits 4,5); wave's 32 cols are disjoint from others
        s += __shfl_xor(s, 16, 64); q += __shfl_xor(q, 16, 64);
        s += __shfl_xor(s, 32, 64); q += __shfl_xor(q, 32, 64);
        if (lane < 16) { lds_s[col] = s; lds_q[col] = q; }
    }
    __syncthreads();
    if (t < 128) {
        int slot = (blockIdx.x & 7) * 128 + t;
        atomicAdd(&sum8[slot], lds_s[t]);
        atomicAdd(&sq8[slot], lds_q[t]);
    }
    // coalesced bf16 C write: 1024 uint4 (64 rows x 16 segs), 4 per thread
#pragma unroll
    for (int j = 0; j < 4; j++) {
        int idx = t + j * 256;
        int rl = idx >> 4, seg = idx & 15;
        int row = row0 + rl;
        if (row < N)
            *(uint4*)(C + (size_t)row * HID + seg * 8) = *(const uint4*)&Cst[rl * 136 + seg * 8];
    }
}

// ---------------- layer 2 dots (bf16 h1): s = relu(bn1(h))·wl2, r = relu(bn1(h))·wr2 ----
__global__ void k_dots(const unsigned short* __restrict__ h, const float* __restrict__ scale,
                       const float* __restrict__ shift, const float* __restrict__ wl2,
                       const float* __restrict__ wr2, float* __restrict__ s_arr,
                       float* __restrict__ r_arr, int N) {
    int w = threadIdx.x >> 6, lid = threadIdx.x & 63;
    int n = blockIdx.x * 4 + w;
    if (n >= N) return;
    unsigned int u = ((const unsigned int*)h)[(size_t)n * 64 + lid];
    float hx = bf2f_lo(u), hy = bf2f_hi(u);
    float2 sc = *(const float2*)&scale[lid * 2];
    float2 sh = *(const float2*)&shift[lid * 2];
    float y0 = fmaxf(0.f, fmaf(hx, sc.x, sh.x));
    float y1 = fmaxf(0.f, fmaf(hy, sc.y, sh.y));
    float2 wl = *(const float2*)&wl2[lid * 2];
    float2 wrv = *(const float2*)&wr2[lid * 2];
    float ps = y0 * wl.x + y1 * wl.y;
    float pr = y0 * wrv.x + y1 * wrv.y;
#pragma unroll
    for (int off = 32; off > 0; off >>= 1) {
        ps += __shfl_down(ps, off, 64);
        pr += __shfl_down(pr, off, 64);
    }
    if (lid == 0) { s_arr[n] = ps; r_arr[n] = pr; }
}

// ---------------- final: scalar mean over edges + sigmoid (4-deep MLP) ----------------
__global__ void k_final2(const float* __restrict__ s_arr, const float* __restrict__ r_arr,
                         const int* __restrict__ rowptr, const int* __restrict__ csr,
                         const float* __restrict__ invd, const float* __restrict__ bl2,
                         float* __restrict__ out, int N) {
    int n = blockIdx.x * blockDim.x + threadIdx.x;
    if (n >= N) return;
    int s = rowptr[n], e = rowptr[n + 1];
    float a = 0.f;
    int i = s;
    for (; i + 4 <= e; i += 4) {
        float a0 = s_arr[csr[i]],     a1 = s_arr[csr[i + 1]];
        float a2 = s_arr[csr[i + 2]], a3 = s_arr[csr[i + 3]];
        a += (a0 + a1) + (a2 + a3);
    }
    for (; i < e; i++) a += s_arr[csr[i]];
    float p = a * invd[n] + r_arr[n] + bl2[0];
    out[n] = 1.f / (1.f + expf(-p));
}

// ---------------- host ----------------
extern "C" void kernel_launch(void* const* d_in, const int* in_sizes, int n_in,
                              void* d_out, int out_size, void* d_ws, size_t ws_size,
                              hipStream_t stream) {
    const float* x   = (const float*)d_in[0];
    const int*   ei  = (const int*)d_in[1];
    const float* wl0 = (const float*)d_in[2];
    const float* bl0 = (const float*)d_in[3];
    const float* wr0 = (const float*)d_in[4];
    const float* g0  = (const float*)d_in[5];
    const float* be0 = (const float*)d_in[6];
    const float* wl1 = (const float*)d_in[7];
    const float* bl1 = (const float*)d_in[8];
    const float* wr1 = (const float*)d_in[9];
    const float* g1  = (const float*)d_in[10];
    const float* be1 = (const float*)d_in[11];
    const float* wl2 = (const float*)d_in[12];
    const float* bl2 = (const float*)d_in[13];
    const float* wr2 = (const float*)d_in[14];
    float* outp = (float*)d_out;

    int N = in_sizes[0] / INDIM;     // 100000
    int E = in_sizes[1] / 2;         // 600000

    char* ws = (char*)d_ws;
    size_t off = 0;
    auto alloc = [&](size_t bytes) { size_t o = off; off = (off + bytes + 255) & ~(size_t)255; return o; };
    int*   degi   = (int*)(ws + alloc((size_t)N * 4));
    int*   rank   = (int*)(ws + alloc((size_t)E * 4));
    int*   rowptr = (int*)(ws + alloc((size_t)(N + 1) * 4));
    int*   csr    = (int*)(ws + alloc((size_t)E * 4));
    float* invd   = (float*)(ws + alloc((size_t)N * 4));
    int*   partial= (int*)(ws + alloc(1024 * 4));
    float* bnbuf  = (float*)(ws + alloc(5120 * 4));
    unsigned short* wcat = (unsigned short*)(ws + alloc(128 * 256 * 2));
    float* sarr   = (float*)(ws + alloc((size_t)N * 4));
    float* rarr   = (float*)(ws + alloc((size_t)N * 4));
    float* mean6  = (float*)(ws + alloc((size_t)N * 6 * 4));
    float* sum0_8 = bnbuf;
    float* sq0_8  = bnbuf + 1024;
    float* sum1_8 = bnbuf + 2048;
    float* sq1_8  = bnbuf + 3072;
    float* sc0 = bnbuf + 4096, *sh0 = bnbuf + 4224;
    float* sc1 = bnbuf + 4352, *sh1 = bnbuf + 4480;
    unsigned short* bufB = (unsigned short*)(ws + alloc((size_t)N * HID * 2)); // bf16 gemm out
    unsigned short* bufC = (unsigned short*)(ws + alloc((size_t)N * HID * 2)); // bf16 relu(bn0)
    unsigned short* bufD = (unsigned short*)(ws + alloc((size_t)N * HID * 2)); // bf16 agg mean

    float invN = 1.0f / (float)N;
    int gE = (E + 255) / 256;
    int gN = (N + 255) / 256;
    int gW = (N + 3) / 4;            // wave-per-node kernels
    int gA = (N + 15) / 16;          // agg blocks (16 nodes each, quarter-wave per node)
    int gL = (N + 31) / 32;          // layer0 blocks (32 nodes each)
    int gS = (N + 63) / 64;          // gemm blocks (64-row tiles)
    int nbScan = (N + 1023) / 1024;

    // init: zero degree + BN accumulators, prep bf16 wcat (one launch)
    k_init<<<gN, 256, 0, stream>>>(degi, N, (int*)bnbuf, 4096, wl1, wr1, wcat);

    // CSR build (rank-based, atomic-free fill; invdeg fused into scan_write)
    k_deg<<<gE, 256, 0, stream>>>(ei + E, degi, rank, E);
    k_scan_partial<<<nbScan, 256, 0, stream>>>(degi, partial, N);
    k_scan_tops<<<1, 1024, 0, stream>>>(partial, nbScan);
    k_scan_write<<<nbScan, 256, 0, stream>>>(degi, partial, rowptr, invd, N, E);
    k_fill<<<gE, 256, 0, stream>>>(ei, rank, rowptr, csr, E);

    // layer 0a: gather mean6 + fused BN0 stats (h in-register, discarded)
    k_l0stats<<<gL, 256, 0, stream>>>(x, rowptr, csr, invd, wl0, bl0, wr0, mean6,
                                      sum0_8, sq0_8, N);
    k_bnfin8<<<1, 128, 0, stream>>>(sum0_8, sq0_8, g0, be0, sc0, sh0, invN);

    // layer 0b: recompute h (identical fp32 ops) + BN0+ReLU -> bf16 bufC
    k_l0apply<<<gL, 256, 0, stream>>>(x, mean6, wl0, bl0, wr0, sc0, sh0, bufC, N);

    // layer 1: agg(bufC) -> bufD (bf16) ; MFMA gemm(bufD, bufC) -> bufB (bf16) + BN1 stats
    k_agg_bf<<<gA, 256, 0, stream>>>(bufC, rowptr, csr, invd, bufD, N);
    k_gemm<<<gS, 256, 0, stream>>>(bufD, bufC, wcat, bl1, sum1_8, sq1_8, bufB, N);
    k_bnfin8<<<1, 128, 0, stream>>>(sum1_8, sq1_8, g1, be1, sc1, sh1, invN);

    // layer 2: per-node dots then scalar aggregation + sigmoid
    k_dots<<<gW, 256, 0, stream>>>(bufB, sc1, sh1, wl2, wr2, sarr, rarr, N);
    k_final2<<<gN, 256, 0, stream>>>(sarr, rarr, rowptr, csr, invd, bl2, outp, N);
}

// Round 20
// 181.168 us; speedup vs baseline: 1.1856x; 1.0059x over previous
//
#include <hip/hip_runtime.h>
#include <math.h>

#define HID 128
#define INDIM 6

typedef float4 f4;
typedef __attribute__((ext_vector_type(8))) short short8;
typedef __attribute__((ext_vector_type(4))) float f32x4;

static __device__ inline unsigned short f2bf(float f) {
    union { float f; unsigned int u; } v; v.f = f;
    unsigned int r = v.u + 0x7fffu + ((v.u >> 16) & 1u);   // RNE
    return (unsigned short)(r >> 16);
}
static __device__ inline float bf2f_lo(unsigned int u) {
    union { unsigned int u; float f; } v; v.u = u << 16; return v.f;
}
static __device__ inline float bf2f_hi(unsigned int u) {
    union { unsigned int u; float f; } v; v.u = u & 0xffff0000u; return v.f;
}

// ---------------- init: zero degi + bnbuf, prep bf16 wcat (fused, one launch) ---------
__global__ void k_init(int* a, int na, int* b, int nb,
                       const float* __restrict__ wl, const float* __restrict__ wr,
                       unsigned short* __restrict__ wcat) {
    int i = blockIdx.x * blockDim.x + threadIdx.x;
    if (i < na) a[i] = 0;
    if (i < nb) b[i] = 0;
    if (i < 32768) {
        int o = i >> 8, k = i & 255;
        float v = (k < 128) ? wl[o * 128 + k] : wr[o * 128 + k - 128];
        wcat[i] = f2bf(v);
    }
}

// ---------------- degree + per-edge rank ----------------
__global__ void k_deg(const int* dst, int* deg, int* rank, int E) {
    int e = blockIdx.x * blockDim.x + threadIdx.x;
    if (e < E) rank[e] = atomicAdd(&deg[dst[e]], 1);
}

// ---------------- hierarchical exclusive scan (deg -> rowptr) ----------------
__global__ void k_scan_partial(const int* __restrict__ deg, int* __restrict__ partial, int N) {
    __shared__ int lds[256];
    int t = threadIdx.x;
    int base = blockIdx.x * 1024 + t * 4;
    int s = 0;
    if (base + 4 <= N) {
        int4 v = *(const int4*)&deg[base];
        s = v.x + v.y + v.z + v.w;
    } else {
        for (int i = 0; i < 4; i++) if (base + i < N) s += deg[base + i];
    }
    lds[t] = s;
    __syncthreads();
    for (int off = 128; off > 0; off >>= 1) {
        if (t < off) lds[t] += lds[t + off];
        __syncthreads();
    }
    if (t == 0) partial[blockIdx.x] = lds[0];
}

__global__ void k_scan_tops(int* partial, int nb) {
    __shared__ int lds[1024];
    int t = threadIdx.x;
    lds[t] = (t < nb) ? partial[t] : 0;
    __syncthreads();
    for (int off = 1; off < 1024; off <<= 1) {
        int v = (t >= off) ? lds[t - off] : 0;
        __syncthreads();
        lds[t] += v;
        __syncthreads();
    }
    if (t < nb) partial[t] = (t == 0) ? 0 : lds[t - 1];
}

// scan_write + fused invdeg (deg values already in registers here)
__global__ void k_scan_write(const int* __restrict__ deg, const int* __restrict__ partial,
                             int* __restrict__ rowptr, float* __restrict__ invd,
                             int N, int E) {
    __shared__ int lds[256];
    int t = threadIdx.x;
    int base = blockIdx.x * 1024 + t * 4;
    int v0 = 0, v1 = 0, v2 = 0, v3 = 0;
    if (base + 4 <= N) {
        int4 v = *(const int4*)&deg[base];
        v0 = v.x; v1 = v.y; v2 = v.z; v3 = v.w;
    } else {
        if (base + 0 < N) v0 = deg[base + 0];
        if (base + 1 < N) v1 = deg[base + 1];
        if (base + 2 < N) v2 = deg[base + 2];
        if (base + 3 < N) v3 = deg[base + 3];
    }
    lds[t] = v0 + v1 + v2 + v3;
    __syncthreads();
    for (int off = 1; off < 256; off <<= 1) {
        int v = (t >= off) ? lds[t - off] : 0;
        __syncthreads();
        lds[t] += v;
        __syncthreads();
    }
    int run = partial[blockIdx.x] + ((t == 0) ? 0 : lds[t - 1]);
    if (base + 0 < N) { rowptr[base + 0] = run; invd[base + 0] = 1.0f / (float)max(v0, 1); } run += v0;
    if (base + 1 < N) { rowptr[base + 1] = run; invd[base + 1] = 1.0f / (float)max(v1, 1); } run += v1;
    if (base + 2 < N) { rowptr[base + 2] = run; invd[base + 2] = 1.0f / (float)max(v2, 1); } run += v2;
    if (base + 3 < N) { rowptr[base + 3] = run; invd[base + 3] = 1.0f / (float)max(v3, 1); } run += v3;
    if (blockIdx.x == 0 && t == 0) rowptr[N] = E;
}

// ---------------- CSR fill, atomic-free (uses rank from k_deg) ----------------
__global__ void k_fill(const int* ei, const int* rank, const int* rowptr, int* csr, int E) {
    int e = blockIdx.x * blockDim.x + threadIdx.x;
    if (e < E) {
        int d = ei[E + e];
        csr[rowptr[d] + rank[e]] = ei[e];
    }
}

// ---------------- layer 0a: gather mean6 + in-register h for BN0 stats ----------------
__global__ __launch_bounds__(256) void k_l0stats(
        const float* __restrict__ x, const int* __restrict__ rowptr,
        const int* __restrict__ csr, const float* __restrict__ invd,
        const float* __restrict__ wl, const float* __restrict__ bl,
        const float* __restrict__ wr, float* __restrict__ mean6,
        float* __restrict__ sum8, float* __restrict__ sq8, int N) {
    __shared__ float wlds[1600];   // [wl | wr], addr = base + o*6+i + (o>>4)*2  (bank-spread)
    __shared__ float blds[136];    // bias, addr = o + (o>>4)
    __shared__ float mx[32][8];
    __shared__ float xr[32][8];
    __shared__ float ps[4][128];
    __shared__ float pq[4][128];
    int t = threadIdx.x;
    for (int idx = t; idx < 1536; idx += 256) {
        int half = idx >= 768 ? 1 : 0;
        int lin = idx - half * 768;
        int o = lin / 6, i = lin - o * 6;
        float v = half ? wr[lin] : wl[lin];
        wlds[half * 800 + o * 6 + i + (o >> 4) * 2] = v;
    }
    if (t < 128) blds[t + (t >> 4)] = bl[t];
    int nl = t >> 3, f = t & 7;
    int n = blockIdx.x * 32 + nl;
    bool valid = n < N;
    if (f < 6) {
        float mean = 0.f, xv = 0.f;
        if (valid) {
            int s = rowptr[n], e = rowptr[n + 1];
            float acc = 0.f;
            int i = s;
            for (; i + 4 <= e; i += 4) {           // 4-deep MLP unroll
                int i0 = csr[i], i1 = csr[i + 1], i2 = csr[i + 2], i3 = csr[i + 3];
                float a0 = x[i0 * 6 + f], a1 = x[i1 * 6 + f];
                float a2 = x[i2 * 6 + f], a3 = x[i3 * 6 + f];
                acc += (a0 + a1) + (a2 + a3);
            }
            int rem = e - i;                       // parallel tail: clamped loads,
            if (rem > 0) {                         // sequential accumulation (bit-identical)
                int eL = e - 1;
                int i0 = csr[i];
                int i1 = csr[min(i + 1, eL)];
                int i2 = csr[min(i + 2, eL)];
                float a0 = x[i0 * 6 + f];
                float a1 = x[i1 * 6 + f];
                float a2 = x[i2 * 6 + f];
                acc += a0;
                if (rem > 1) acc += a1;
                if (rem > 2) acc += a2;
            }
            mean = acc * invd[n];
            xv = x[n * 6 + f];
            mean6[n * 6 + f] = mean;
        }
        mx[nl][f] = mean;
        xr[nl][f] = xv;
    }
    __syncthreads();
    float m0 = mx[nl][0], m1 = mx[nl][1], m2 = mx[nl][2];
    float m3 = mx[nl][3], m4 = mx[nl][4], m5 = mx[nl][5];
    float r0 = xr[nl][0], r1 = xr[nl][1], r2 = xr[nl][2];
    float r3 = xr[nl][3], r4 = xr[nl][4], r5 = xr[nl][5];
    const float* wA = wlds;
    const float* wB = wlds + 800;
    int wv = t >> 6, lane = t & 63;
#pragma unroll
    for (int k = 0; k < 16; k++) {                 // inline reduce: no sk/qk arrays
        int o = f * 16 + k;
        int wb = 98 * f + 6 * k;                   // o*6 + (o>>4)*2
        float h = blds[o + f];                     // o + (o>>4), o>>4 == f
        h += m0 * wA[wb] + m1 * wA[wb + 1] + m2 * wA[wb + 2]
           + m3 * wA[wb + 3] + m4 * wA[wb + 4] + m5 * wA[wb + 5];
        h += r0 * wB[wb] + r1 * wB[wb + 1] + r2 * wB[wb + 2]
           + r3 * wB[wb + 3] + r4 * wB[wb + 4] + r5 * wB[wb + 5];
        float s = valid ? h : 0.f;
        float q = s * s;
        s += __shfl_xor(s, 8, 64);  q += __shfl_xor(q, 8, 64);
        s += __shfl_xor(s, 16, 64); q += __shfl_xor(q, 16, 64);
        s += __shfl_xor(s, 32, 64); q += __shfl_xor(q, 32, 64);
        if (lane < 8) { ps[wv][lane * 16 + k] = s; pq[wv][lane * 16 + k] = q; }
    }
    __syncthreads();
    if (t < 128) {
        float S = ps[0][t] + ps[1][t] + ps[2][t] + ps[3][t];
        float Q = pq[0][t] + pq[1][t] + pq[2][t] + pq[3][t];
        int slot = (blockIdx.x & 7) * 128 + t;
        atomicAdd(&sum8[slot], S);
        atomicAdd(&sq8[slot], Q);
    }
}

// ---------------- layer 0b: recompute h (identical code) + BN0+ReLU -> bf16 ----------
__global__ __launch_bounds__(256) void k_l0apply(
        const float* __restrict__ x, const float* __restrict__ mean6,
        const float* __restrict__ wl, const float* __restrict__ bl,
        const float* __restrict__ wr, const float* __restrict__ scale,
        const float* __restrict__ shift, unsigned short* __restrict__ out, int N) {
    __shared__ float wlds[1600];
    __shared__ float blds[136];
    __shared__ float sclds[136];
    __shared__ float shlds[136];
    __shared__ float mx[32][8];
    __shared__ float xr[32][8];
    int t = threadIdx.x;
    for (int idx = t; idx < 1536; idx += 256) {
        int half = idx >= 768 ? 1 : 0;
        int lin = idx - half * 768;
        int o = lin / 6, i = lin - o * 6;
        float v = half ? wr[lin] : wl[lin];
        wlds[half * 800 + o * 6 + i + (o >> 4) * 2] = v;
    }
    if (t < 128) {
        blds[t + (t >> 4)]  = bl[t];
        sclds[t + (t >> 4)] = scale[t];
        shlds[t + (t >> 4)] = shift[t];
    }
    int nl = t >> 3, f = t & 7;
    int n = blockIdx.x * 32 + nl;
    bool valid = n < N;
    if (f < 6) {
        mx[nl][f] = valid ? mean6[n * 6 + f] : 0.f;
        xr[nl][f] = valid ? x[n * 6 + f] : 0.f;
    }
    __syncthreads();
    if (!valid) return;
    float m0 = mx[nl][0], m1 = mx[nl][1], m2 = mx[nl][2];
    float m3 = mx[nl][3], m4 = mx[nl][4], m5 = mx[nl][5];
    float r0 = xr[nl][0], r1 = xr[nl][1], r2 = xr[nl][2];
    float r3 = xr[nl][3], r4 = xr[nl][4], r5 = xr[nl][5];
    const float* wA = wlds;
    const float* wB = wlds + 800;
    unsigned short pk[16];
#pragma unroll
    for (int k4 = 0; k4 < 4; k4++) {
#pragma unroll
        for (int j = 0; j < 4; j++) {
            int k = k4 * 4 + j;
            int o = f * 16 + k;
            int wb = 98 * f + 6 * k;
            float h = blds[o + f];              // identical expression tree to k_l0stats
            h += m0 * wA[wb] + m1 * wA[wb + 1] + m2 * wA[wb + 2]
               + m3 * wA[wb + 3] + m4 * wA[wb + 4] + m5 * wA[wb + 5];
            h += r0 * wB[wb] + r1 * wB[wb + 1] + r2 * wB[wb + 2]
               + r3 * wB[wb + 3] + r4 * wB[wb + 4] + r5 * wB[wb + 5];
            pk[k] = f2bf(fmaxf(0.f, fmaf(h, sclds[o + f], shlds[o + f])));
        }
    }
    unsigned short* dst = out + (size_t)n * HID + f * 16;
    *(uint4*)(dst)     = *(const uint4*)&pk[0];
    *(uint4*)(dst + 8) = *(const uint4*)&pk[8];
}

// ---------------- BN finalize from 8-copy accumulators ----------------
__global__ void k_bnfin8(const float* sum8, const float* sq8, const float* g, const float* b,
                         float* scale, float* shift, float invN) {
    int t = threadIdx.x;
    float s = 0.f, q = 0.f;
    for (int c = 0; c < 8; c++) { s += sum8[c * 128 + t]; q += sq8[c * 128 + t]; }
    float mu  = s * invN;
    float var = q * invN - mu * mu;
    float sc  = g[t] * rsqrtf(var + 1e-5f);
    scale[t] = sc;
    shift[t] = b[t] - mu * sc;
}

// ---------------- bf16 mean aggregation: quarter-wave per node, parallel tail ----------
__global__ void k_agg_bf(const unsigned short* __restrict__ hb, const int* __restrict__ rowptr,
                         const int* __restrict__ csr, const float* __restrict__ invd,
                         unsigned short* __restrict__ out, int N) {
    int t = threadIdx.x;
    int w = t >> 6, lid = t & 63;
    int q = lid >> 4, l16 = lid & 15;
    int n = blockIdx.x * 16 + w * 4 + q;
    if (n >= N) return;
    int s = rowptr[n], e = rowptr[n + 1];
    const uint4* hb128 = (const uint4*)hb;         // row stride = 16 uint4 (256 B)
    float ax0 = 0.f, ay0 = 0.f, ax1 = 0.f, ay1 = 0.f;
    float ax2 = 0.f, ay2 = 0.f, ax3 = 0.f, ay3 = 0.f;
    int i = s;
    for (; i + 4 <= e; i += 4) {                   // 4 rows x 4 nodes/wave in flight
        int i0 = csr[i], i1 = csr[i + 1], i2 = csr[i + 2], i3 = csr[i + 3];
        uint4 u0 = hb128[(size_t)i0 * 16 + l16];
        uint4 u1 = hb128[(size_t)i1 * 16 + l16];
        uint4 u2 = hb128[(size_t)i2 * 16 + l16];
        uint4 u3 = hb128[(size_t)i3 * 16 + l16];
        ax0 += (bf2f_lo(u0.x) + bf2f_lo(u1.x)) + (bf2f_lo(u2.x) + bf2f_lo(u3.x));
        ay0 += (bf2f_hi(u0.x) + bf2f_hi(u1.x)) + (bf2f_hi(u2.x) + bf2f_hi(u3.x));
        ax1 += (bf2f_lo(u0.y) + bf2f_lo(u1.y)) + (bf2f_lo(u2.y) + bf2f_lo(u3.y));
        ay1 += (bf2f_hi(u0.y) + bf2f_hi(u1.y)) + (bf2f_hi(u2.y) + bf2f_hi(u3.y));
        ax2 += (bf2f_lo(u0.z) + bf2f_lo(u1.z)) + (bf2f_lo(u2.z) + bf2f_lo(u3.z));
        ay2 += (bf2f_hi(u0.z) + bf2f_hi(u1.z)) + (bf2f_hi(u2.z) + bf2f_hi(u3.z));
        ax3 += (bf2f_lo(u0.w) + bf2f_lo(u1.w)) + (bf2f_lo(u2.w) + bf2f_lo(u3.w));
        ay3 += (bf2f_hi(u0.w) + bf2f_hi(u1.w)) + (bf2f_hi(u2.w) + bf2f_hi(u3.w));
    }
    int rem = e - i;                               // parallel tail (bit-identical sum order)
    if (rem > 0) {
        int eL = e - 1;
        int i0 = csr[i];
        int i1 = csr[min(i + 1, eL)];
        int i2 = csr[min(i + 2, eL)];
        uint4 u0 = hb128[(size_t)i0 * 16 + l16];
        uint4 u1 = hb128[(size_t)i1 * 16 + l16];
        uint4 u2 = hb128[(size_t)i2 * 16 + l16];
        ax0 += bf2f_lo(u0.x); ay0 += bf2f_hi(u0.x);
        ax1 += bf2f_lo(u0.y); ay1 += bf2f_hi(u0.y);
        ax2 += bf2f_lo(u0.z); ay2 += bf2f_hi(u0.z);
        ax3 += bf2f_lo(u0.w); ay3 += bf2f_hi(u0.w);
        if (rem > 1) {
            ax0 += bf2f_lo(u1.x); ay0 += bf2f_hi(u1.x);
            ax1 += bf2f_lo(u1.y); ay1 += bf2f_hi(u1.y);
            ax2 += bf2f_lo(u1.z); ay2 += bf2f_hi(u1.z);
            ax3 += bf2f_lo(u1.w); ay3 += bf2f_hi(u1.w);
        }
        if (rem > 2) {
            ax0 += bf2f_lo(u2.x); ay0 += bf2f_hi(u2.x);
            ax1 += bf2f_lo(u2.y); ay1 += bf2f_hi(u2.y);
            ax2 += bf2f_lo(u2.z); ay2 += bf2f_hi(u2.z);
            ax3 += bf2f_lo(u2.w); ay3 += bf2f_hi(u2.w);
        }
    }
    float id = invd[n];
    uint4 r;
    r.x = (unsigned int)f2bf(ax0 * id) | ((unsigned int)f2bf(ay0 * id) << 16);
    r.y = (unsigned int)f2bf(ax1 * id) | ((unsigned int)f2bf(ay1 * id) << 16);
    r.z = (unsigned int)f2bf(ax2 * id) | ((unsigned int)f2bf(ay2 * id) << 16);
    r.w = (unsigned int)f2bf(ax3 * id) | ((unsigned int)f2bf(ay3 * id) << 16);
    ((uint4*)out)[(size_t)n * 16 + l16] = r;
}

// ---------------- MFMA double GEMM + fused BN1 stats (64-row tiles) ----------------
__global__ __launch_bounds__(256) void k_gemm(
        const unsigned short* __restrict__ Bm, const unsigned short* __restrict__ Ar,
        const unsigned short* __restrict__ wcat, const float* __restrict__ bias,
        float* __restrict__ sum8, float* __restrict__ sq8,
        unsigned short* __restrict__ C, int N) {
    __shared__ __align__(16) unsigned short As[64][72];    // 64 rows x (64 k + 8 pad)
    __shared__ __align__(16) unsigned short Ws[128][72];   // all 128 cols x 64 k
    __shared__ float lds_s[128];
    __shared__ float lds_q[128];
    int t = threadIdx.x;
    int wave = t >> 6, lane = t & 63;
    int row0 = blockIdx.x * 64;
    int lrow = lane & 15, koff = (lane >> 4) * 8;

    f32x4 acc[4][2];
#pragma unroll
    for (int m = 0; m < 4; m++)
#pragma unroll
        for (int n = 0; n < 2; n++) acc[m][n] = (f32x4)(0.f);

    for (int chunk = 0; chunk < 4; chunk++) {
        int kb = chunk * 64;
        // ---- stage A: 64x64 shorts, 16 shorts (32 B) per thread ----
        int rA = t >> 2, qA = t & 3;
        int srow = row0 + rA;
        int cA = (kb & 127) + qA * 16;
        const unsigned short* src = (kb < 128) ? Bm : Ar;
        uint4 a0, a1;
        if (srow < N) {
            const unsigned short* p = src + (size_t)srow * HID + cA;
            a0 = *(const uint4*)(p); a1 = *(const uint4*)(p + 8);
        } else {
            a0 = a1 = make_uint4(0, 0, 0, 0);
        }
        *(uint4*)&As[rA][qA * 16]     = a0;
        *(uint4*)&As[rA][qA * 16 + 8] = a1;
        // ---- stage W: 128x64 shorts, 32 shorts (64 B) per thread ----
        int rW = t >> 1, hW = t & 1;
        const unsigned short* wp = wcat + rW * 256 + kb + hW * 32;
        *(uint4*)&Ws[rW][hW * 32]      = *(const uint4*)(wp);
        *(uint4*)&Ws[rW][hW * 32 + 8]  = *(const uint4*)(wp + 8);
        *(uint4*)&Ws[rW][hW * 32 + 16] = *(const uint4*)(wp + 16);
        *(uint4*)&Ws[rW][hW * 32 + 24] = *(const uint4*)(wp + 24);
        __syncthreads();

        // ---- MFMA: two k-steps of 32; wave covers cols [wave*32, wave*32+32) ----
#pragma unroll
        for (int ks = 0; ks < 64; ks += 32) {
            short8 af[4], bfr[2];
#pragma unroll
            for (int m = 0; m < 4; m++)
                af[m] = *(const short8*)&As[m * 16 + lrow][ks + koff];
#pragma unroll
            for (int n = 0; n < 2; n++)
                bfr[n] = *(const short8*)&Ws[wave * 32 + n * 16 + lrow][ks + koff];
#pragma unroll
            for (int m = 0; m < 4; m++)
#pragma unroll
                for (int n = 0; n < 2; n++)
                    acc[m][n] = __builtin_amdgcn_mfma_f32_16x16x32_bf16(af[m], bfr[n], acc[m][n], 0, 0, 0);
        }
        __syncthreads();
    }

    // ---- epilogue: stats (fp32 from acc) + bf16 C via LDS re-stage (in Ws), coalesced --
    unsigned short* Cst = &Ws[0][0];   // 64 rows x 136 stride = 17408 B <= 18432 B
    int cl = lane & 15, rq = (lane >> 4) * 4;
#pragma unroll
    for (int n = 0; n < 2; n++) {
        int col = wave * 32 + n * 16 + cl;
        float bn = bias[col];
        float s = 0.f, q = 0.f;
#pragma unroll
        for (int m = 0; m < 4; m++) {
#pragma unroll
            for (int reg = 0; reg < 4; reg++) {
                int rl = m * 16 + rq + reg;
                float v = acc[m][n][reg] + bn;
                Cst[rl * 136 + col] = f2bf(v);
                if (row0 + rl < N) { s += v; q += v * v; }
            }
        }
        s += __shfl_xor(s, 16, 64); q += __shfl_xor(q, 16, 64);
        s += __shfl_xor(s, 32, 64); q += __shfl_xor(q, 32, 64);
        if (lane < 16) { lds_s[col] = s; lds_q[col] = q; }
    }
    __syncthreads();
    if (t < 128) {
        int slot = (blockIdx.x & 7) * 128 + t;
        atomicAdd(&sum8[slot], lds_s[t]);
        atomicAdd(&sq8[slot], lds_q[t]);
    }
    // coalesced bf16 C write: 1024 uint4 (64 rows x 16 segs), 4 per thread
#pragma unroll
    for (int j = 0; j < 4; j++) {
        int idx = t + j * 256;
        int rl = idx >> 4, seg = idx & 15;
        int row = row0 + rl;
        if (row < N)
            *(uint4*)(C + (size_t)row * HID + seg * 8) = *(const uint4*)&Cst[rl * 136 + seg * 8];
    }
}

// ---------------- layer 2 dots (bf16 h1): s = relu(bn1(h))·wl2, r = relu(bn1(h))·wr2 ----
__global__ void k_dots(const unsigned short* __restrict__ h, const float* __restrict__ scale,
                       const float* __restrict__ shift, const float* __restrict__ wl2,
                       const float* __restrict__ wr2, float* __restrict__ s_arr,
                       float* __restrict__ r_arr, int N) {
    int w = threadIdx.x >> 6, lid = threadIdx.x & 63;
    int n = blockIdx.x * 4 + w;
    if (n >= N) return;
    unsigned int u = ((const unsigned int*)h)[(size_t)n * 64 + lid];
    float hx = bf2f_lo(u), hy = bf2f_hi(u);
    float2 sc = *(const float2*)&scale[lid * 2];
    float2 sh = *(const float2*)&shift[lid * 2];
    float y0 = fmaxf(0.f, fmaf(hx, sc.x, sh.x));
    float y1 = fmaxf(0.f, fmaf(hy, sc.y, sh.y));
    float2 wl = *(const float2*)&wl2[lid * 2];
    float2 wrv = *(const float2*)&wr2[lid * 2];
    float ps = y0 * wl.x + y1 * wl.y;
    float pr = y0 * wrv.x + y1 * wrv.y;
#pragma unroll
    for (int off = 32; off > 0; off >>= 1) {
        ps += __shfl_down(ps, off, 64);
        pr += __shfl_down(pr, off, 64);
    }
    if (lid == 0) { s_arr[n] = ps; r_arr[n] = pr; }
}

// ---------------- final: scalar mean over edges + sigmoid (parallel tail) --------------
__global__ void k_final2(const float* __restrict__ s_arr, const float* __restrict__ r_arr,
                         const int* __restrict__ rowptr, const int* __restrict__ csr,
                         const float* __restrict__ invd, const float* __restrict__ bl2,
                         float* __restrict__ out, int N) {
    int n = blockIdx.x * blockDim.x + threadIdx.x;
    if (n >= N) return;
    int s = rowptr[n], e = rowptr[n + 1];
    float a = 0.f;
    int i = s;
    for (; i + 4 <= e; i += 4) {
        float a0 = s_arr[csr[i]],     a1 = s_arr[csr[i + 1]];
        float a2 = s_arr[csr[i + 2]], a3 = s_arr[csr[i + 3]];
        a += (a0 + a1) + (a2 + a3);
    }
    int rem = e - i;
    if (rem > 0) {
        int eL = e - 1;
        float a0 = s_arr[csr[i]];
        float a1 = s_arr[csr[min(i + 1, eL)]];
        float a2 = s_arr[csr[min(i + 2, eL)]];
        a += a0;
        if (rem > 1) a += a1;
        if (rem > 2) a += a2;
    }
    float p = a * invd[n] + r_arr[n] + bl2[0];
    out[n] = 1.f / (1.f + expf(-p));
}

// ---------------- host ----------------
extern "C" void kernel_launch(void* const* d_in, const int* in_sizes, int n_in,
                              void* d_out, int out_size, void* d_ws, size_t ws_size,
                              hipStream_t stream) {
    const float* x   = (const float*)d_in[0];
    const int*   ei  = (const int*)d_in[1];
    const float* wl0 = (const float*)d_in[2];
    const float* bl0 = (const float*)d_in[3];
    const float* wr0 = (const float*)d_in[4];
    const float* g0  = (const float*)d_in[5];
    const float* be0 = (const float*)d_in[6];
    const float* wl1 = (const float*)d_in[7];
    const float* bl1 = (const float*)d_in[8];
    const float* wr1 = (const float*)d_in[9];
    const float* g1  = (const float*)d_in[10];
    const float* be1 = (const float*)d_in[11];
    const float* wl2 = (const float*)d_in[12];
    const float* bl2 = (const float*)d_in[13];
    const float* wr2 = (const float*)d_in[14];
    float* outp = (float*)d_out;

    int N = in_sizes[0] / INDIM;     // 100000
    int E = in_sizes[1] / 2;         // 600000

    char* ws = (char*)d_ws;
    size_t off = 0;
    auto alloc = [&](size_t bytes) { size_t o = off; off = (off + bytes + 255) & ~(size_t)255; return o; };
    int*   degi   = (int*)(ws + alloc((size_t)N * 4));
    int*   rank   = (int*)(ws + alloc((size_t)E * 4));
    int*   rowptr = (int*)(ws + alloc((size_t)(N + 1) * 4));
    int*   csr    = (int*)(ws + alloc((size_t)E * 4));
    float* invd   = (float*)(ws + alloc((size_t)N * 4));
    int*   partial= (int*)(ws + alloc(1024 * 4));
    float* bnbuf  = (float*)(ws + alloc(5120 * 4));
    unsigned short* wcat = (unsigned short*)(ws + alloc(128 * 256 * 2));
    float* sarr   = (float*)(ws + alloc((size_t)N * 4));
    float* rarr   = (float*)(ws + alloc((size_t)N * 4));
    float* mean6  = (float*)(ws + alloc((size_t)N * 6 * 4));
    float* sum0_8 = bnbuf;
    float* sq0_8  = bnbuf + 1024;
    float* sum1_8 = bnbuf + 2048;
    float* sq1_8  = bnbuf + 3072;
    float* sc0 = bnbuf + 4096, *sh0 = bnbuf + 4224;
    float* sc1 = bnbuf + 4352, *sh1 = bnbuf + 4480;
    unsigned short* bufB = (unsigned short*)(ws + alloc((size_t)N * HID * 2)); // bf16 gemm out
    unsigned short* bufC = (unsigned short*)(ws + alloc((size_t)N * HID * 2)); // bf16 relu(bn0)
    unsigned short* bufD = (unsigned short*)(ws + alloc((size_t)N * HID * 2)); // bf16 agg mean

    float invN = 1.0f / (float)N;
    int gE = (E + 255) / 256;
    int gN = (N + 255) / 256;
    int gW = (N + 3) / 4;            // wave-per-node kernels
    int gA = (N + 15) / 16;          // agg blocks (16 nodes each, quarter-wave per node)
    int gL = (N + 31) / 32;          // layer0 blocks (32 nodes each)
    int gS = (N + 63) / 64;          // gemm blocks (64-row tiles)
    int nbScan = (N + 1023) / 1024;

    // init: zero degree + BN accumulators, prep bf16 wcat (one launch)
    k_init<<<gN, 256, 0, stream>>>(degi, N, (int*)bnbuf, 4096, wl1, wr1, wcat);

    // CSR build (rank-based, atomic-free fill; invdeg fused into scan_write)
    k_deg<<<gE, 256, 0, stream>>>(ei + E, degi, rank, E);
    k_scan_partial<<<nbScan, 256, 0, stream>>>(degi, partial, N);
    k_scan_tops<<<1, 1024, 0, stream>>>(partial, nbScan);
    k_scan_write<<<nbScan, 256, 0, stream>>>(degi, partial, rowptr, invd, N, E);
    k_fill<<<gE, 256, 0, stream>>>(ei, rank, rowptr, csr, E);

    // layer 0a: gather mean6 + fused BN0 stats (h in-register, discarded)
    k_l0stats<<<gL, 256, 0, stream>>>(x, rowptr, csr, invd, wl0, bl0, wr0, mean6,
                                      sum0_8, sq0_8, N);
    k_bnfin8<<<1, 128, 0, stream>>>(sum0_8, sq0_8, g0, be0, sc0, sh0, invN);

    // layer 0b: recompute h (identical fp32 ops) + BN0+ReLU -> bf16 bufC
    k_l0apply<<<gL, 256, 0, stream>>>(x, mean6, wl0, bl0, wr0, sc0, sh0, bufC, N);

    // layer 1: agg(bufC) -> bufD (bf16) ; MFMA gemm(bufD, bufC) -> bufB (bf16) + BN1 stats
    k_agg_bf<<<gA, 256, 0, stream>>>(bufC, rowptr, csr, invd, bufD, N);
    k_gemm<<<gS, 256, 0, stream>>>(bufD, bufC, wcat, bl1, sum1_8, sq1_8, bufB, N);
    k_bnfin8<<<1, 128, 0, stream>>>(sum1_8, sq1_8, g1, be1, sc1, sh1, invN);

    // layer 2: per-node dots then scalar aggregation + sigmoid
    k_dots<<<gW, 256, 0, stream>>>(bufB, sc1, sh1, wl2, wr2, sarr, rarr, N);
    k_final2<<<gN, 256, 0, stream>>>(sarr, rarr, rowptr, csr, invd, bl2, outp, N);
}

// Round 21
// 179.619 us; speedup vs baseline: 1.1958x; 1.0086x over previous
//
#include <hip/hip_runtime.h>
#include <math.h>

#define HID 128
#define INDIM 6

typedef float4 f4;
typedef __attribute__((ext_vector_type(8))) short short8;
typedef __attribute__((ext_vector_type(4))) float f32x4;

static __device__ inline unsigned short f2bf(float f) {
    union { float f; unsigned int u; } v; v.f = f;
    unsigned int r = v.u + 0x7fffu + ((v.u >> 16) & 1u);   // RNE
    return (unsigned short)(r >> 16);
}
static __device__ inline float bf2f_lo(unsigned int u) {
    union { unsigned int u; float f; } v; v.u = u << 16; return v.f;
}
static __device__ inline float bf2f_hi(unsigned int u) {
    union { unsigned int u; float f; } v; v.u = u & 0xffff0000u; return v.f;
}

// ---------------- init: zero degi + bnbuf, prep bf16 wcat (fused, one launch) ---------
__global__ void k_init(int* a, int na, int* b, int nb,
                       const float* __restrict__ wl, const float* __restrict__ wr,
                       unsigned short* __restrict__ wcat) {
    int i = blockIdx.x * blockDim.x + threadIdx.x;
    if (i < na) a[i] = 0;
    if (i < nb) b[i] = 0;
    if (i < 32768) {
        int o = i >> 8, k = i & 255;
        float v = (k < 128) ? wl[o * 128 + k] : wr[o * 128 + k - 128];
        wcat[i] = f2bf(v);
    }
}

// ---------------- degree + per-edge rank ----------------
__global__ void k_deg(const int* dst, int* deg, int* rank, int E) {
    int e = blockIdx.x * blockDim.x + threadIdx.x;
    if (e < E) rank[e] = atomicAdd(&deg[dst[e]], 1);
}

// ---------------- scan pass 1: per-block (1024 elems) totals ----------------
__global__ void k_scan_partial(const int* __restrict__ deg, int* __restrict__ partial, int N) {
    __shared__ int lds[256];
    int t = threadIdx.x;
    int base = blockIdx.x * 1024 + t * 4;
    int s = 0;
    if (base + 4 <= N) {
        int4 v = *(const int4*)&deg[base];
        s = v.x + v.y + v.z + v.w;
    } else {
        for (int i = 0; i < 4; i++) if (base + i < N) s += deg[base + i];
    }
    lds[t] = s;
    __syncthreads();
    for (int off = 128; off > 0; off >>= 1) {
        if (t < off) lds[t] += lds[t + off];
        __syncthreads();
    }
    if (t == 0) partial[blockIdx.x] = lds[0];
}

// ---------------- scan pass 2: write rowptr + invd; each block scans partials itself ---
// (k_scan_tops eliminated: nb <= 256 partials, redundant per-block scan is ~free)
__global__ void k_scan_write(const int* __restrict__ deg, const int* __restrict__ partial,
                             int* __restrict__ rowptr, float* __restrict__ invd,
                             int N, int E, int nb) {
    __shared__ int lds[256];
    __shared__ int ptot[256];
    int t = threadIdx.x;
    // redundant scan of block partials (inclusive), then take own exclusive prefix
    ptot[t] = (t < nb) ? partial[t] : 0;
    __syncthreads();
    for (int off = 1; off < 256; off <<= 1) {
        int v = (t >= off) ? ptot[t - off] : 0;
        __syncthreads();
        ptot[t] += v;
        __syncthreads();
    }
    int blockbase = (blockIdx.x == 0) ? 0 : ptot[blockIdx.x - 1];

    int base = blockIdx.x * 1024 + t * 4;
    int v0 = 0, v1 = 0, v2 = 0, v3 = 0;
    if (base + 4 <= N) {
        int4 v = *(const int4*)&deg[base];
        v0 = v.x; v1 = v.y; v2 = v.z; v3 = v.w;
    } else {
        if (base + 0 < N) v0 = deg[base + 0];
        if (base + 1 < N) v1 = deg[base + 1];
        if (base + 2 < N) v2 = deg[base + 2];
        if (base + 3 < N) v3 = deg[base + 3];
    }
    lds[t] = v0 + v1 + v2 + v3;
    __syncthreads();
    for (int off = 1; off < 256; off <<= 1) {
        int v = (t >= off) ? lds[t - off] : 0;
        __syncthreads();
        lds[t] += v;
        __syncthreads();
    }
    int run = blockbase + ((t == 0) ? 0 : lds[t - 1]);
    if (base + 0 < N) { rowptr[base + 0] = run; invd[base + 0] = 1.0f / (float)max(v0, 1); } run += v0;
    if (base + 1 < N) { rowptr[base + 1] = run; invd[base + 1] = 1.0f / (float)max(v1, 1); } run += v1;
    if (base + 2 < N) { rowptr[base + 2] = run; invd[base + 2] = 1.0f / (float)max(v2, 1); } run += v2;
    if (base + 3 < N) { rowptr[base + 3] = run; invd[base + 3] = 1.0f / (float)max(v3, 1); } run += v3;
    if (blockIdx.x == 0 && t == 0) rowptr[N] = E;
}

// ---------------- CSR fill, atomic-free (uses rank from k_deg) ----------------
__global__ void k_fill(const int* ei, const int* rank, const int* rowptr, int* csr, int E) {
    int e = blockIdx.x * blockDim.x + threadIdx.x;
    if (e < E) {
        int d = ei[E + e];
        csr[rowptr[d] + rank[e]] = ei[e];
    }
}

// ---------------- layer 0a: gather mean6 + in-register h for BN0 stats ----------------
__global__ __launch_bounds__(256) void k_l0stats(
        const float* __restrict__ x, const int* __restrict__ rowptr,
        const int* __restrict__ csr, const float* __restrict__ invd,
        const float* __restrict__ wl, const float* __restrict__ bl,
        const float* __restrict__ wr, float* __restrict__ mean6,
        float* __restrict__ sum8, float* __restrict__ sq8, int N) {
    __shared__ float wlds[1600];   // [wl | wr], addr = base + o*6+i + (o>>4)*2  (bank-spread)
    __shared__ float blds[136];    // bias, addr = o + (o>>4)
    __shared__ float mx[32][8];
    __shared__ float xr[32][8];
    __shared__ float ps[4][128];
    __shared__ float pq[4][128];
    int t = threadIdx.x;
    for (int idx = t; idx < 1536; idx += 256) {
        int half = idx >= 768 ? 1 : 0;
        int lin = idx - half * 768;
        int o = lin / 6, i = lin - o * 6;
        float v = half ? wr[lin] : wl[lin];
        wlds[half * 800 + o * 6 + i + (o >> 4) * 2] = v;
    }
    if (t < 128) blds[t + (t >> 4)] = bl[t];
    int nl = t >> 3, f = t & 7;
    int n = blockIdx.x * 32 + nl;
    bool valid = n < N;
    if (f < 6) {
        float mean = 0.f, xv = 0.f;
        if (valid) {
            int s = rowptr[n], e = rowptr[n + 1];
            float acc = 0.f;
            int i = s;
            for (; i + 4 <= e; i += 4) {           // 4-deep MLP unroll
                int i0 = csr[i], i1 = csr[i + 1], i2 = csr[i + 2], i3 = csr[i + 3];
                float a0 = x[i0 * 6 + f], a1 = x[i1 * 6 + f];
                float a2 = x[i2 * 6 + f], a3 = x[i3 * 6 + f];
                acc += (a0 + a1) + (a2 + a3);
            }
            int rem = e - i;                       // parallel tail: clamped loads,
            if (rem > 0) {                         // sequential accumulation (bit-identical)
                int eL = e - 1;
                int i0 = csr[i];
                int i1 = csr[min(i + 1, eL)];
                int i2 = csr[min(i + 2, eL)];
                float a0 = x[i0 * 6 + f];
                float a1 = x[i1 * 6 + f];
                float a2 = x[i2 * 6 + f];
                acc += a0;
                if (rem > 1) acc += a1;
                if (rem > 2) acc += a2;
            }
            mean = acc * invd[n];
            xv = x[n * 6 + f];
            mean6[n * 6 + f] = mean;
        }
        mx[nl][f] = mean;
        xr[nl][f] = xv;
    }
    __syncthreads();
    float m0 = mx[nl][0], m1 = mx[nl][1], m2 = mx[nl][2];
    float m3 = mx[nl][3], m4 = mx[nl][4], m5 = mx[nl][5];
    float r0 = xr[nl][0], r1 = xr[nl][1], r2 = xr[nl][2];
    float r3 = xr[nl][3], r4 = xr[nl][4], r5 = xr[nl][5];
    const float* wA = wlds;
    const float* wB = wlds + 800;
    int wv = t >> 6, lane = t & 63;
#pragma unroll
    for (int k = 0; k < 16; k++) {                 // inline reduce: no sk/qk arrays
        int o = f * 16 + k;
        int wb = 98 * f + 6 * k;                   // o*6 + (o>>4)*2
        float h = blds[o + f];                     // o + (o>>4), o>>4 == f
        h += m0 * wA[wb] + m1 * wA[wb + 1] + m2 * wA[wb + 2]
           + m3 * wA[wb + 3] + m4 * wA[wb + 4] + m5 * wA[wb + 5];
        h += r0 * wB[wb] + r1 * wB[wb + 1] + r2 * wB[wb + 2]
           + r3 * wB[wb + 3] + r4 * wB[wb + 4] + r5 * wB[wb + 5];
        float s = valid ? h : 0.f;
        float q = s * s;
        s += __shfl_xor(s, 8, 64);  q += __shfl_xor(q, 8, 64);
        s += __shfl_xor(s, 16, 64); q += __shfl_xor(q, 16, 64);
        s += __shfl_xor(s, 32, 64); q += __shfl_xor(q, 32, 64);
        if (lane < 8) { ps[wv][lane * 16 + k] = s; pq[wv][lane * 16 + k] = q; }
    }
    __syncthreads();
    if (t < 128) {
        float S = ps[0][t] + ps[1][t] + ps[2][t] + ps[3][t];
        float Q = pq[0][t] + pq[1][t] + pq[2][t] + pq[3][t];
        int slot = (blockIdx.x & 7) * 128 + t;
        atomicAdd(&sum8[slot], S);
        atomicAdd(&sq8[slot], Q);
    }
}

// ---------------- layer 0b: inline bnfin + recompute h + BN0+ReLU -> bf16 -------------
// (k_bnfin8 launch eliminated: per-block recompute of scale/shift, identical math)
__global__ __launch_bounds__(256) void k_l0apply(
        const float* __restrict__ x, const float* __restrict__ mean6,
        const float* __restrict__ wl, const float* __restrict__ bl,
        const float* __restrict__ wr, const float* __restrict__ sum8,
        const float* __restrict__ sq8, const float* __restrict__ g,
        const float* __restrict__ be, float invN,
        unsigned short* __restrict__ out, int N) {
    __shared__ float wlds[1600];
    __shared__ float blds[136];
    __shared__ float sclds[136];
    __shared__ float shlds[136];
    __shared__ float mx[32][8];
    __shared__ float xr[32][8];
    int t = threadIdx.x;
    for (int idx = t; idx < 1536; idx += 256) {
        int half = idx >= 768 ? 1 : 0;
        int lin = idx - half * 768;
        int o = lin / 6, i = lin - o * 6;
        float v = half ? wr[lin] : wl[lin];
        wlds[half * 800 + o * 6 + i + (o >> 4) * 2] = v;
    }
    if (t < 128) {
        blds[t + (t >> 4)] = bl[t];
        float s = 0.f, q = 0.f;
        for (int c = 0; c < 8; c++) { s += sum8[c * 128 + t]; q += sq8[c * 128 + t]; }
        float mu  = s * invN;
        float var = q * invN - mu * mu;
        float sc  = g[t] * rsqrtf(var + 1e-5f);
        sclds[t + (t >> 4)] = sc;
        shlds[t + (t >> 4)] = be[t] - mu * sc;
    }
    int nl = t >> 3, f = t & 7;
    int n = blockIdx.x * 32 + nl;
    bool valid = n < N;
    if (f < 6) {
        mx[nl][f] = valid ? mean6[n * 6 + f] : 0.f;
        xr[nl][f] = valid ? x[n * 6 + f] : 0.f;
    }
    __syncthreads();
    if (!valid) return;
    float m0 = mx[nl][0], m1 = mx[nl][1], m2 = mx[nl][2];
    float m3 = mx[nl][3], m4 = mx[nl][4], m5 = mx[nl][5];
    float r0 = xr[nl][0], r1 = xr[nl][1], r2 = xr[nl][2];
    float r3 = xr[nl][3], r4 = xr[nl][4], r5 = xr[nl][5];
    const float* wA = wlds;
    const float* wB = wlds + 800;
    unsigned short pk[16];
#pragma unroll
    for (int k4 = 0; k4 < 4; k4++) {
#pragma unroll
        for (int j = 0; j < 4; j++) {
            int k = k4 * 4 + j;
            int o = f * 16 + k;
            int wb = 98 * f + 6 * k;
            float h = blds[o + f];              // identical expression tree to k_l0stats
            h += m0 * wA[wb] + m1 * wA[wb + 1] + m2 * wA[wb + 2]
               + m3 * wA[wb + 3] + m4 * wA[wb + 4] + m5 * wA[wb + 5];
            h += r0 * wB[wb] + r1 * wB[wb + 1] + r2 * wB[wb + 2]
               + r3 * wB[wb + 3] + r4 * wB[wb + 4] + r5 * wB[wb + 5];
            pk[k] = f2bf(fmaxf(0.f, fmaf(h, sclds[o + f], shlds[o + f])));
        }
    }
    unsigned short* dst = out + (size_t)n * HID + f * 16;
    *(uint4*)(dst)     = *(const uint4*)&pk[0];
    *(uint4*)(dst + 8) = *(const uint4*)&pk[8];
}

// ---------------- bf16 mean aggregation: quarter-wave per node, parallel tail ----------
__global__ void k_agg_bf(const unsigned short* __restrict__ hb, const int* __restrict__ rowptr,
                         const int* __restrict__ csr, const float* __restrict__ invd,
                         unsigned short* __restrict__ out, int N) {
    int t = threadIdx.x;
    int w = t >> 6, lid = t & 63;
    int q = lid >> 4, l16 = lid & 15;
    int n = blockIdx.x * 16 + w * 4 + q;
    if (n >= N) return;
    int s = rowptr[n], e = rowptr[n + 1];
    const uint4* hb128 = (const uint4*)hb;         // row stride = 16 uint4 (256 B)
    float ax0 = 0.f, ay0 = 0.f, ax1 = 0.f, ay1 = 0.f;
    float ax2 = 0.f, ay2 = 0.f, ax3 = 0.f, ay3 = 0.f;
    int i = s;
    for (; i + 4 <= e; i += 4) {                   // 4 rows x 4 nodes/wave in flight
        int i0 = csr[i], i1 = csr[i + 1], i2 = csr[i + 2], i3 = csr[i + 3];
        uint4 u0 = hb128[(size_t)i0 * 16 + l16];
        uint4 u1 = hb128[(size_t)i1 * 16 + l16];
        uint4 u2 = hb128[(size_t)i2 * 16 + l16];
        uint4 u3 = hb128[(size_t)i3 * 16 + l16];
        ax0 += (bf2f_lo(u0.x) + bf2f_lo(u1.x)) + (bf2f_lo(u2.x) + bf2f_lo(u3.x));
        ay0 += (bf2f_hi(u0.x) + bf2f_hi(u1.x)) + (bf2f_hi(u2.x) + bf2f_hi(u3.x));
        ax1 += (bf2f_lo(u0.y) + bf2f_lo(u1.y)) + (bf2f_lo(u2.y) + bf2f_lo(u3.y));
        ay1 += (bf2f_hi(u0.y) + bf2f_hi(u1.y)) + (bf2f_hi(u2.y) + bf2f_hi(u3.y));
        ax2 += (bf2f_lo(u0.z) + bf2f_lo(u1.z)) + (bf2f_lo(u2.z) + bf2f_lo(u3.z));
        ay2 += (bf2f_hi(u0.z) + bf2f_hi(u1.z)) + (bf2f_hi(u2.z) + bf2f_hi(u3.z));
        ax3 += (bf2f_lo(u0.w) + bf2f_lo(u1.w)) + (bf2f_lo(u2.w) + bf2f_lo(u3.w));
        ay3 += (bf2f_hi(u0.w) + bf2f_hi(u1.w)) + (bf2f_hi(u2.w) + bf2f_hi(u3.w));
    }
    int rem = e - i;                               // parallel tail (bit-identical sum order)
    if (rem > 0) {
        int eL = e - 1;
        int i0 = csr[i];
        int i1 = csr[min(i + 1, eL)];
        int i2 = csr[min(i + 2, eL)];
        uint4 u0 = hb128[(size_t)i0 * 16 + l16];
        uint4 u1 = hb128[(size_t)i1 * 16 + l16];
        uint4 u2 = hb128[(size_t)i2 * 16 + l16];
        ax0 += bf2f_lo(u0.x); ay0 += bf2f_hi(u0.x);
        ax1 += bf2f_lo(u0.y); ay1 += bf2f_hi(u0.y);
        ax2 += bf2f_lo(u0.z); ay2 += bf2f_hi(u0.z);
        ax3 += bf2f_lo(u0.w); ay3 += bf2f_hi(u0.w);
        if (rem > 1) {
            ax0 += bf2f_lo(u1.x); ay0 += bf2f_hi(u1.x);
            ax1 += bf2f_lo(u1.y); ay1 += bf2f_hi(u1.y);
            ax2 += bf2f_lo(u1.z); ay2 += bf2f_hi(u1.z);
            ax3 += bf2f_lo(u1.w); ay3 += bf2f_hi(u1.w);
        }
        if (rem > 2) {
            ax0 += bf2f_lo(u2.x); ay0 += bf2f_hi(u2.x);
            ax1 += bf2f_lo(u2.y); ay1 += bf2f_hi(u2.y);
            ax2 += bf2f_lo(u2.z); ay2 += bf2f_hi(u2.z);
            ax3 += bf2f_lo(u2.w); ay3 += bf2f_hi(u2.w);
        }
    }
    float id = invd[n];
    uint4 r;
    r.x = (unsigned int)f2bf(ax0 * id) | ((unsigned int)f2bf(ay0 * id) << 16);
    r.y = (unsigned int)f2bf(ax1 * id) | ((unsigned int)f2bf(ay1 * id) << 16);
    r.z = (unsigned int)f2bf(ax2 * id) | ((unsigned int)f2bf(ay2 * id) << 16);
    r.w = (unsigned int)f2bf(ax3 * id) | ((unsigned int)f2bf(ay3 * id) << 16);
    ((uint4*)out)[(size_t)n * 16 + l16] = r;
}

// ---------------- MFMA double GEMM + fused BN1 stats (64-row tiles) ----------------
__global__ __launch_bounds__(256) void k_gemm(
        const unsigned short* __restrict__ Bm, const unsigned short* __restrict__ Ar,
        const unsigned short* __restrict__ wcat, const float* __restrict__ bias,
        float* __restrict__ sum8, float* __restrict__ sq8,
        unsigned short* __restrict__ C, int N) {
    __shared__ __align__(16) unsigned short As[64][72];    // 64 rows x (64 k + 8 pad)
    __shared__ __align__(16) unsigned short Ws[128][72];   // all 128 cols x 64 k
    __shared__ float lds_s[128];
    __shared__ float lds_q[128];
    int t = threadIdx.x;
    int wave = t >> 6, lane = t & 63;
    int row0 = blockIdx.x * 64;
    int lrow = lane & 15, koff = (lane >> 4) * 8;

    f32x4 acc[4][2];
#pragma unroll
    for (int m = 0; m < 4; m++)
#pragma unroll
        for (int n = 0; n < 2; n++) acc[m][n] = (f32x4)(0.f);

    for (int chunk = 0; chunk < 4; chunk++) {
        int kb = chunk * 64;
        // ---- stage A: 64x64 shorts, 16 shorts (32 B) per thread ----
        int rA = t >> 2, qA = t & 3;
        int srow = row0 + rA;
        int cA = (kb & 127) + qA * 16;
        const unsigned short* src = (kb < 128) ? Bm : Ar;
        uint4 a0, a1;
        if (srow < N) {
            const unsigned short* p = src + (size_t)srow * HID + cA;
            a0 = *(const uint4*)(p); a1 = *(const uint4*)(p + 8);
        } else {
            a0 = a1 = make_uint4(0, 0, 0, 0);
        }
        *(uint4*)&As[rA][qA * 16]     = a0;
        *(uint4*)&As[rA][qA * 16 + 8] = a1;
        // ---- stage W: 128x64 shorts, 32 shorts (64 B) per thread ----
        int rW = t >> 1, hW = t & 1;
        const unsigned short* wp = wcat + rW * 256 + kb + hW * 32;
        *(uint4*)&Ws[rW][hW * 32]      = *(const uint4*)(wp);
        *(uint4*)&Ws[rW][hW * 32 + 8]  = *(const uint4*)(wp + 8);
        *(uint4*)&Ws[rW][hW * 32 + 16] = *(const uint4*)(wp + 16);
        *(uint4*)&Ws[rW][hW * 32 + 24] = *(const uint4*)(wp + 24);
        __syncthreads();

        // ---- MFMA: two k-steps of 32; wave covers cols [wave*32, wave*32+32) ----
#pragma unroll
        for (int ks = 0; ks < 64; ks += 32) {
            short8 af[4], bfr[2];
#pragma unroll
            for (int m = 0; m < 4; m++)
                af[m] = *(const short8*)&As[m * 16 + lrow][ks + koff];
#pragma unroll
            for (int n = 0; n < 2; n++)
                bfr[n] = *(const short8*)&Ws[wave * 32 + n * 16 + lrow][ks + koff];
#pragma unroll
            for (int m = 0; m < 4; m++)
#pragma unroll
                for (int n = 0; n < 2; n++)
                    acc[m][n] = __builtin_amdgcn_mfma_f32_16x16x32_bf16(af[m], bfr[n], acc[m][n], 0, 0, 0);
        }
        __syncthreads();
    }

    // ---- epilogue: stats (fp32 from acc) + bf16 C via LDS re-stage (in Ws), coalesced --
    unsigned short* Cst = &Ws[0][0];   // 64 rows x 136 stride = 17408 B <= 18432 B
    int cl = lane & 15, rq = (lane >> 4) * 4;
#pragma unroll
    for (int n = 0; n < 2; n++) {
        int col = wave * 32 + n * 16 + cl;
        float bn = bias[col];
        float s = 0.f, q = 0.f;
#pragma unroll
        for (int m = 0; m < 4; m++) {
#pragma unroll
            for (int reg = 0; reg < 4; reg++) {
                int rl = m * 16 + rq + reg;
                float v = acc[m][n][reg] + bn;
                Cst[rl * 136 + col] = f2bf(v);
                if (row0 + rl < N) { s += v; q += v * v; }
            }
        }
        s += __shfl_xor(s, 16, 64); q += __shfl_xor(q, 16, 64);
        s += __shfl_xor(s, 32, 64); q += __shfl_xor(q, 32, 64);
        if (lane < 16) { lds_s[col] = s; lds_q[col] = q; }
    }
    __syncthreads();
    if (t < 128) {
        int slot = (blockIdx.x & 7) * 128 + t;
        atomicAdd(&sum8[slot], lds_s[t]);
        atomicAdd(&sq8[slot], lds_q[t]);
    }
    // coalesced bf16 C write: 1024 uint4 (64 rows x 16 segs), 4 per thread
#pragma unroll
    for (int j = 0; j < 4; j++) {
        int idx = t + j * 256;
        int rl = idx >> 4, seg = idx & 15;
        int row = row0 + rl;
        if (row < N)
            *(uint4*)(C + (size_t)row * HID + seg * 8) = *(const uint4*)&Cst[rl * 136 + seg * 8];
    }
}

// ---------------- layer 2 dots: inline bnfin1 + relu(bn1(h))·wl2 / ·wr2 ---------------
__global__ void k_dots(const unsigned short* __restrict__ h, const float* __restrict__ sum8,
                       const float* __restrict__ sq8, const float* __restrict__ g,
                       const float* __restrict__ be, float invN,
                       const float* __restrict__ wl2, const float* __restrict__ wr2,
                       float* __restrict__ s_arr, float* __restrict__ r_arr, int N) {
    __shared__ float scl[128];
    __shared__ float shl[128];
    int t = threadIdx.x;
    if (t < 128) {
        float s = 0.f, q = 0.f;
        for (int c = 0; c < 8; c++) { s += sum8[c * 128 + t]; q += sq8[c * 128 + t]; }
        float mu  = s * invN;
        float var = q * invN - mu * mu;
        float sc  = g[t] * rsqrtf(var + 1e-5f);
        scl[t] = sc;
        shl[t] = be[t] - mu * sc;
    }
    __syncthreads();
    int w = t >> 6, lid = t & 63;
    int n = blockIdx.x * 4 + w;
    if (n >= N) return;
    unsigned int u = ((const unsigned int*)h)[(size_t)n * 64 + lid];
    float hx = bf2f_lo(u), hy = bf2f_hi(u);
    float2 sc = *(const float2*)&scl[lid * 2];
    float2 sh = *(const float2*)&shl[lid * 2];
    float y0 = fmaxf(0.f, fmaf(hx, sc.x, sh.x));
    float y1 = fmaxf(0.f, fmaf(hy, sc.y, sh.y));
    float2 wl = *(const float2*)&wl2[lid * 2];
    float2 wrv = *(const float2*)&wr2[lid * 2];
    float ps = y0 * wl.x + y1 * wl.y;
    float pr = y0 * wrv.x + y1 * wrv.y;
#pragma unroll
    for (int off = 32; off > 0; off >>= 1) {
        ps += __shfl_down(ps, off, 64);
        pr += __shfl_down(pr, off, 64);
    }
    if (lid == 0) { s_arr[n] = ps; r_arr[n] = pr; }
}

// ---------------- final: scalar mean over edges + sigmoid (parallel tail) --------------
__global__ void k_final2(const float* __restrict__ s_arr, const float* __restrict__ r_arr,
                         const int* __restrict__ rowptr, const int* __restrict__ csr,
                         const float* __restrict__ invd, const float* __restrict__ bl2,
                         float* __restrict__ out, int N) {
    int n = blockIdx.x * blockDim.x + threadIdx.x;
    if (n >= N) return;
    int s = rowptr[n], e = rowptr[n + 1];
    float a = 0.f;
    int i = s;
    for (; i + 4 <= e; i += 4) {
        float a0 = s_arr[csr[i]],     a1 = s_arr[csr[i + 1]];
        float a2 = s_arr[csr[i + 2]], a3 = s_arr[csr[i + 3]];
        a += (a0 + a1) + (a2 + a3);
    }
    int rem = e - i;
    if (rem > 0) {
        int eL = e - 1;
        float a0 = s_arr[csr[i]];
        float a1 = s_arr[csr[min(i + 1, eL)]];
        float a2 = s_arr[csr[min(i + 2, eL)]];
        a += a0;
        if (rem > 1) a += a1;
        if (rem > 2) a += a2;
    }
    float p = a * invd[n] + r_arr[n] + bl2[0];
    out[n] = 1.f / (1.f + expf(-p));
}

// ---------------- host ----------------
extern "C" void kernel_launch(void* const* d_in, const int* in_sizes, int n_in,
                              void* d_out, int out_size, void* d_ws, size_t ws_size,
                              hipStream_t stream) {
    const float* x   = (const float*)d_in[0];
    const int*   ei  = (const int*)d_in[1];
    const float* wl0 = (const float*)d_in[2];
    const float* bl0 = (const float*)d_in[3];
    const float* wr0 = (const float*)d_in[4];
    const float* g0  = (const float*)d_in[5];
    const float* be0 = (const float*)d_in[6];
    const float* wl1 = (const float*)d_in[7];
    const float* bl1 = (const float*)d_in[8];
    const float* wr1 = (const float*)d_in[9];
    const float* g1  = (const float*)d_in[10];
    const float* be1 = (const float*)d_in[11];
    const float* wl2 = (const float*)d_in[12];
    const float* bl2 = (const float*)d_in[13];
    const float* wr2 = (const float*)d_in[14];
    float* outp = (float*)d_out;

    int N = in_sizes[0] / INDIM;     // 100000
    int E = in_sizes[1] / 2;         // 600000

    char* ws = (char*)d_ws;
    size_t off = 0;
    auto alloc = [&](size_t bytes) { size_t o = off; off = (off + bytes + 255) & ~(size_t)255; return o; };
    int*   degi   = (int*)(ws + alloc((size_t)N * 4));
    int*   rank   = (int*)(ws + alloc((size_t)E * 4));
    int*   rowptr = (int*)(ws + alloc((size_t)(N + 1) * 4));
    int*   csr    = (int*)(ws + alloc((size_t)E * 4));
    float* invd   = (float*)(ws + alloc((size_t)N * 4));
    int*   partial= (int*)(ws + alloc(1024 * 4));
    float* bnbuf  = (float*)(ws + alloc(5120 * 4));
    unsigned short* wcat = (unsigned short*)(ws + alloc(128 * 256 * 2));
    float* sarr   = (float*)(ws + alloc((size_t)N * 4));
    float* rarr   = (float*)(ws + alloc((size_t)N * 4));
    float* mean6  = (float*)(ws + alloc((size_t)N * 6 * 4));
    float* sum0_8 = bnbuf;
    float* sq0_8  = bnbuf + 1024;
    float* sum1_8 = bnbuf + 2048;
    float* sq1_8  = bnbuf + 3072;
    unsigned short* bufB = (unsigned short*)(ws + alloc((size_t)N * HID * 2)); // bf16 gemm out
    unsigned short* bufC = (unsigned short*)(ws + alloc((size_t)N * HID * 2)); // bf16 relu(bn0)
    unsigned short* bufD = (unsigned short*)(ws + alloc((size_t)N * HID * 2)); // bf16 agg mean

    float invN = 1.0f / (float)N;
    int gE = (E + 255) / 256;
    int gN = (N + 255) / 256;
    int gW = (N + 3) / 4;            // wave-per-node kernels
    int gA = (N + 15) / 16;          // agg blocks (16 nodes each, quarter-wave per node)
    int gL = (N + 31) / 32;          // layer0 blocks (32 nodes each)
    int gS = (N + 63) / 64;          // gemm blocks (64-row tiles)
    int nbScan = (N + 1023) / 1024;  // <= 256 for N <= 262144

    // init: zero degree + BN accumulators, prep bf16 wcat (one launch)
    k_init<<<gN, 256, 0, stream>>>(degi, N, (int*)bnbuf, 4096, wl1, wr1, wcat);

    // CSR build (rank-based, atomic-free fill; invdeg fused; tops scan folded into write)
    k_deg<<<gE, 256, 0, stream>>>(ei + E, degi, rank, E);
    k_scan_partial<<<nbScan, 256, 0, stream>>>(degi, partial, N);
    k_scan_write<<<nbScan, 256, 0, stream>>>(degi, partial, rowptr, invd, N, E, nbScan);
    k_fill<<<gE, 256, 0, stream>>>(ei, rank, rowptr, csr, E);

    // layer 0a: gather mean6 + fused BN0 stats (h in-register, discarded)
    k_l0stats<<<gL, 256, 0, stream>>>(x, rowptr, csr, invd, wl0, bl0, wr0, mean6,
                                      sum0_8, sq0_8, N);

    // layer 0b: inline bnfin0 + recompute h + BN0+ReLU -> bf16 bufC
    k_l0apply<<<gL, 256, 0, stream>>>(x, mean6, wl0, bl0, wr0,
                                      sum0_8, sq0_8, g0, be0, invN, bufC, N);

    // layer 1: agg(bufC) -> bufD (bf16) ; MFMA gemm(bufD, bufC) -> bufB (bf16) + BN1 stats
    k_agg_bf<<<gA, 256, 0, stream>>>(bufC, rowptr, csr, invd, bufD, N);
    k_gemm<<<gS, 256, 0, stream>>>(bufD, bufC, wcat, bl1, sum1_8, sq1_8, bufB, N);

    // layer 2: inline bnfin1 + per-node dots, then scalar aggregation + sigmoid
    k_dots<<<gW, 256, 0, stream>>>(bufB, sum1_8, sq1_8, g1, be1, invN, wl2, wr2,
                                   sarr, rarr, N);
    k_final2<<<gN, 256, 0, stream>>>(sarr, rarr, rowptr, csr, invd, bl2, outp, N);
}

// Round 22
// 178.579 us; speedup vs baseline: 1.2028x; 1.0058x over previous
//
#include <hip/hip_runtime.h>
#include <math.h>

#define HID 128
#define INDIM 6

typedef float4 f4;
typedef __attribute__((ext_vector_type(8))) short short8;
typedef __attribute__((ext_vector_type(4))) float f32x4;

static __device__ inline unsigned short f2bf(float f) {
    union { float f; unsigned int u; } v; v.f = f;
    unsigned int r = v.u + 0x7fffu + ((v.u >> 16) & 1u);   // RNE
    return (unsigned short)(r >> 16);
}
static __device__ inline float bf2f_lo(unsigned int u) {
    union { unsigned int u; float f; } v; v.u = u << 16; return v.f;
}
static __device__ inline float bf2f_hi(unsigned int u) {
    union { unsigned int u; float f; } v; v.u = u & 0xffff0000u; return v.f;
}

// ---------------- init: zero degi + bnbuf, prep bf16 wcat (fused, one launch) ---------
__global__ void k_init(int* a, int na, int* b, int nb,
                       const float* __restrict__ wl, const float* __restrict__ wr,
                       unsigned short* __restrict__ wcat) {
    int i = blockIdx.x * blockDim.x + threadIdx.x;
    if (i < na) a[i] = 0;
    if (i < nb) b[i] = 0;
    if (i < 32768) {
        int o = i >> 8, k = i & 255;
        float v = (k < 128) ? wl[o * 128 + k] : wr[o * 128 + k - 128];
        wcat[i] = f2bf(v);
    }
}

// ---------------- degree + per-edge rank ----------------
__global__ void k_deg(const int* dst, int* deg, int* rank, int E) {
    int e = blockIdx.x * blockDim.x + threadIdx.x;
    if (e < E) rank[e] = atomicAdd(&deg[dst[e]], 1);
}

// ---------------- scan pass 1: per-block (1024 elems) totals ----------------
__global__ void k_scan_partial(const int* __restrict__ deg, int* __restrict__ partial, int N) {
    __shared__ int lds[256];
    int t = threadIdx.x;
    int base = blockIdx.x * 1024 + t * 4;
    int s = 0;
    if (base + 4 <= N) {
        int4 v = *(const int4*)&deg[base];
        s = v.x + v.y + v.z + v.w;
    } else {
        for (int i = 0; i < 4; i++) if (base + i < N) s += deg[base + i];
    }
    lds[t] = s;
    __syncthreads();
    for (int off = 128; off > 0; off >>= 1) {
        if (t < off) lds[t] += lds[t + off];
        __syncthreads();
    }
    if (t == 0) partial[blockIdx.x] = lds[0];
}

// ---------------- scan pass 2: write rowptr + invd; each block scans partials itself ---
__global__ void k_scan_write(const int* __restrict__ deg, const int* __restrict__ partial,
                             int* __restrict__ rowptr, float* __restrict__ invd,
                             int N, int E, int nb) {
    __shared__ int lds[256];
    __shared__ int ptot[256];
    int t = threadIdx.x;
    ptot[t] = (t < nb) ? partial[t] : 0;
    __syncthreads();
    for (int off = 1; off < 256; off <<= 1) {
        int v = (t >= off) ? ptot[t - off] : 0;
        __syncthreads();
        ptot[t] += v;
        __syncthreads();
    }
    int blockbase = (blockIdx.x == 0) ? 0 : ptot[blockIdx.x - 1];

    int base = blockIdx.x * 1024 + t * 4;
    int v0 = 0, v1 = 0, v2 = 0, v3 = 0;
    if (base + 4 <= N) {
        int4 v = *(const int4*)&deg[base];
        v0 = v.x; v1 = v.y; v2 = v.z; v3 = v.w;
    } else {
        if (base + 0 < N) v0 = deg[base + 0];
        if (base + 1 < N) v1 = deg[base + 1];
        if (base + 2 < N) v2 = deg[base + 2];
        if (base + 3 < N) v3 = deg[base + 3];
    }
    lds[t] = v0 + v1 + v2 + v3;
    __syncthreads();
    for (int off = 1; off < 256; off <<= 1) {
        int v = (t >= off) ? lds[t - off] : 0;
        __syncthreads();
        lds[t] += v;
        __syncthreads();
    }
    int run = blockbase + ((t == 0) ? 0 : lds[t - 1]);
    if (base + 0 < N) { rowptr[base + 0] = run; invd[base + 0] = 1.0f / (float)max(v0, 1); } run += v0;
    if (base + 1 < N) { rowptr[base + 1] = run; invd[base + 1] = 1.0f / (float)max(v1, 1); } run += v1;
    if (base + 2 < N) { rowptr[base + 2] = run; invd[base + 2] = 1.0f / (float)max(v2, 1); } run += v2;
    if (base + 3 < N) { rowptr[base + 3] = run; invd[base + 3] = 1.0f / (float)max(v3, 1); } run += v3;
    if (blockIdx.x == 0 && t == 0) rowptr[N] = E;
}

// ---------------- CSR fill, atomic-free (uses rank from k_deg) ----------------
__global__ void k_fill(const int* ei, const int* rank, const int* rowptr, int* csr, int E) {
    int e = blockIdx.x * blockDim.x + threadIdx.x;
    if (e < E) {
        int d = ei[E + e];
        csr[rowptr[d] + rank[e]] = ei[e];
    }
}

// ---------------- layer 0a: gather mean6 + in-register h for BN0 stats ----------------
__global__ __launch_bounds__(256) void k_l0stats(
        const float* __restrict__ x, const int* __restrict__ rowptr,
        const int* __restrict__ csr, const float* __restrict__ invd,
        const float* __restrict__ wl, const float* __restrict__ bl,
        const float* __restrict__ wr, float* __restrict__ mean6,
        float* __restrict__ sum8, float* __restrict__ sq8, int N) {
    __shared__ float wlds[1600];   // [wl | wr], addr = base + o*6+i + (o>>4)*2  (bank-spread)
    __shared__ float blds[136];    // bias, addr = o + (o>>4)
    __shared__ float mx[32][8];
    __shared__ float xr[32][8];
    __shared__ float ps[4][128];
    __shared__ float pq[4][128];
    int t = threadIdx.x;
    for (int idx = t; idx < 1536; idx += 256) {
        int half = idx >= 768 ? 1 : 0;
        int lin = idx - half * 768;
        int o = lin / 6, i = lin - o * 6;
        float v = half ? wr[lin] : wl[lin];
        wlds[half * 800 + o * 6 + i + (o >> 4) * 2] = v;
    }
    if (t < 128) blds[t + (t >> 4)] = bl[t];
    int nl = t >> 3, f = t & 7;
    int n = blockIdx.x * 32 + nl;
    bool valid = n < N;
    if (f < 6) {
        float mean = 0.f, xv = 0.f;
        if (valid) {
            int s = rowptr[n], e = rowptr[n + 1];
            float acc = 0.f;
            int i = s;
            for (; i + 4 <= e; i += 4) {           // 4-deep MLP unroll
                int i0 = csr[i], i1 = csr[i + 1], i2 = csr[i + 2], i3 = csr[i + 3];
                float a0 = x[i0 * 6 + f], a1 = x[i1 * 6 + f];
                float a2 = x[i2 * 6 + f], a3 = x[i3 * 6 + f];
                acc += (a0 + a1) + (a2 + a3);
            }
            int rem = e - i;                       // parallel tail: clamped loads,
            if (rem > 0) {                         // sequential accumulation (bit-identical)
                int eL = e - 1;
                int i0 = csr[i];
                int i1 = csr[min(i + 1, eL)];
                int i2 = csr[min(i + 2, eL)];
                float a0 = x[i0 * 6 + f];
                float a1 = x[i1 * 6 + f];
                float a2 = x[i2 * 6 + f];
                acc += a0;
                if (rem > 1) acc += a1;
                if (rem > 2) acc += a2;
            }
            mean = acc * invd[n];
            xv = x[n * 6 + f];
            mean6[n * 6 + f] = mean;
        }
        mx[nl][f] = mean;
        xr[nl][f] = xv;
    }
    __syncthreads();
    float m0 = mx[nl][0], m1 = mx[nl][1], m2 = mx[nl][2];
    float m3 = mx[nl][3], m4 = mx[nl][4], m5 = mx[nl][5];
    float r0 = xr[nl][0], r1 = xr[nl][1], r2 = xr[nl][2];
    float r3 = xr[nl][3], r4 = xr[nl][4], r5 = xr[nl][5];
    const float* wA = wlds;
    const float* wB = wlds + 800;
    int wv = t >> 6, lane = t & 63;
#pragma unroll
    for (int k = 0; k < 16; k++) {                 // inline reduce: no sk/qk arrays
        int o = f * 16 + k;
        int wb = 98 * f + 6 * k;                   // o*6 + (o>>4)*2
        float h = blds[o + f];                     // o + (o>>4), o>>4 == f
        h += m0 * wA[wb] + m1 * wA[wb + 1] + m2 * wA[wb + 2]
           + m3 * wA[wb + 3] + m4 * wA[wb + 4] + m5 * wA[wb + 5];
        h += r0 * wB[wb] + r1 * wB[wb + 1] + r2 * wB[wb + 2]
           + r3 * wB[wb + 3] + r4 * wB[wb + 4] + r5 * wB[wb + 5];
        float s = valid ? h : 0.f;
        float q = s * s;
        s += __shfl_xor(s, 8, 64);  q += __shfl_xor(q, 8, 64);
        s += __shfl_xor(s, 16, 64); q += __shfl_xor(q, 16, 64);
        s += __shfl_xor(s, 32, 64); q += __shfl_xor(q, 32, 64);
        if (lane < 8) { ps[wv][lane * 16 + k] = s; pq[wv][lane * 16 + k] = q; }
    }
    __syncthreads();
    if (t < 128) {
        float S = ps[0][t] + ps[1][t] + ps[2][t] + ps[3][t];
        float Q = pq[0][t] + pq[1][t] + pq[2][t] + pq[3][t];
        int slot = (blockIdx.x & 7) * 128 + t;
        atomicAdd(&sum8[slot], S);
        atomicAdd(&sq8[slot], Q);
    }
}

// ---------------- layer 0b: inline bnfin + recompute h + BN0+ReLU -> bf16 -------------
__global__ __launch_bounds__(256) void k_l0apply(
        const float* __restrict__ x, const float* __restrict__ mean6,
        const float* __restrict__ wl, const float* __restrict__ bl,
        const float* __restrict__ wr, const float* __restrict__ sum8,
        const float* __restrict__ sq8, const float* __restrict__ g,
        const float* __restrict__ be, float invN,
        unsigned short* __restrict__ out, int N) {
    __shared__ float wlds[1600];
    __shared__ float blds[136];
    __shared__ float sclds[136];
    __shared__ float shlds[136];
    __shared__ float mx[32][8];
    __shared__ float xr[32][8];
    int t = threadIdx.x;
    for (int idx = t; idx < 1536; idx += 256) {
        int half = idx >= 768 ? 1 : 0;
        int lin = idx - half * 768;
        int o = lin / 6, i = lin - o * 6;
        float v = half ? wr[lin] : wl[lin];
        wlds[half * 800 + o * 6 + i + (o >> 4) * 2] = v;
    }
    if (t < 128) {
        blds[t + (t >> 4)] = bl[t];
        float s = 0.f, q = 0.f;
        for (int c = 0; c < 8; c++) { s += sum8[c * 128 + t]; q += sq8[c * 128 + t]; }
        float mu  = s * invN;
        float var = q * invN - mu * mu;
        float sc  = g[t] * rsqrtf(var + 1e-5f);
        sclds[t + (t >> 4)] = sc;
        shlds[t + (t >> 4)] = be[t] - mu * sc;
    }
    int nl = t >> 3, f = t & 7;
    int n = blockIdx.x * 32 + nl;
    bool valid = n < N;
    if (f < 6) {
        mx[nl][f] = valid ? mean6[n * 6 + f] : 0.f;
        xr[nl][f] = valid ? x[n * 6 + f] : 0.f;
    }
    __syncthreads();
    if (!valid) return;
    float m0 = mx[nl][0], m1 = mx[nl][1], m2 = mx[nl][2];
    float m3 = mx[nl][3], m4 = mx[nl][4], m5 = mx[nl][5];
    float r0 = xr[nl][0], r1 = xr[nl][1], r2 = xr[nl][2];
    float r3 = xr[nl][3], r4 = xr[nl][4], r5 = xr[nl][5];
    const float* wA = wlds;
    const float* wB = wlds + 800;
    unsigned short pk[16];
#pragma unroll
    for (int k4 = 0; k4 < 4; k4++) {
#pragma unroll
        for (int j = 0; j < 4; j++) {
            int k = k4 * 4 + j;
            int o = f * 16 + k;
            int wb = 98 * f + 6 * k;
            float h = blds[o + f];              // identical expression tree to k_l0stats
            h += m0 * wA[wb] + m1 * wA[wb + 1] + m2 * wA[wb + 2]
               + m3 * wA[wb + 3] + m4 * wA[wb + 4] + m5 * wA[wb + 5];
            h += r0 * wB[wb] + r1 * wB[wb + 1] + r2 * wB[wb + 2]
               + r3 * wB[wb + 3] + r4 * wB[wb + 4] + r5 * wB[wb + 5];
            pk[k] = f2bf(fmaxf(0.f, fmaf(h, sclds[o + f], shlds[o + f])));
        }
    }
    unsigned short* dst = out + (size_t)n * HID + f * 16;
    *(uint4*)(dst)     = *(const uint4*)&pk[0];
    *(uint4*)(dst + 8) = *(const uint4*)&pk[8];
}

// ---------------- FUSED agg + MFMA GEMM + BN1 stats (64-row tiles) ----------------
// Phase 1: gather bf16 mean rows for the tile's 64 nodes directly into LDS (same code
// and rounding as the old k_agg_bf -> bit-identical A operand; bufD eliminated).
// Phase 2: K-loop; chunks 0-1 read A from means, chunks 2-3 re-stage own bufC rows.
__global__ __launch_bounds__(256) void k_agggemm(
        const unsigned short* __restrict__ hb, const int* __restrict__ rowptr,
        const int* __restrict__ csr, const float* __restrict__ invd,
        const unsigned short* __restrict__ wcat, const float* __restrict__ bias,
        float* __restrict__ sum8, float* __restrict__ sq8,
        unsigned short* __restrict__ C, int N) {
    __shared__ __align__(16) unsigned short Am[64][136];   // mean rows / chunk A / Cst
    __shared__ __align__(16) unsigned short Ws[128][72];   // per-chunk W
    __shared__ float lds_s[128];
    __shared__ float lds_q[128];
    int t = threadIdx.x;
    int wave = t >> 6, lane = t & 63;
    int row0 = blockIdx.x * 64;
    int lrow = lane & 15, koff = (lane >> 4) * 8;
    int qtr = lane >> 4, l16 = lane & 15;

    // ---- phase 1: gather means (quarter-wave per node, 4 nodes/wave/iter, 4 iters) ----
    const uint4* hb128 = (const uint4*)hb;
    for (int it = 0; it < 4; it++) {
        int nl = wave * 16 + it * 4 + qtr;
        int n = row0 + nl;
        if (n < N) {
            int s = rowptr[n], e = rowptr[n + 1];
            float ax0 = 0.f, ay0 = 0.f, ax1 = 0.f, ay1 = 0.f;
            float ax2 = 0.f, ay2 = 0.f, ax3 = 0.f, ay3 = 0.f;
            int i = s;
            for (; i + 4 <= e; i += 4) {
                int i0 = csr[i], i1 = csr[i + 1], i2 = csr[i + 2], i3 = csr[i + 3];
                uint4 u0 = hb128[(size_t)i0 * 16 + l16];
                uint4 u1 = hb128[(size_t)i1 * 16 + l16];
                uint4 u2 = hb128[(size_t)i2 * 16 + l16];
                uint4 u3 = hb128[(size_t)i3 * 16 + l16];
                ax0 += (bf2f_lo(u0.x) + bf2f_lo(u1.x)) + (bf2f_lo(u2.x) + bf2f_lo(u3.x));
                ay0 += (bf2f_hi(u0.x) + bf2f_hi(u1.x)) + (bf2f_hi(u2.x) + bf2f_hi(u3.x));
                ax1 += (bf2f_lo(u0.y) + bf2f_lo(u1.y)) + (bf2f_lo(u2.y) + bf2f_lo(u3.y));
                ay1 += (bf2f_hi(u0.y) + bf2f_hi(u1.y)) + (bf2f_hi(u2.y) + bf2f_hi(u3.y));
                ax2 += (bf2f_lo(u0.z) + bf2f_lo(u1.z)) + (bf2f_lo(u2.z) + bf2f_lo(u3.z));
                ay2 += (bf2f_hi(u0.z) + bf2f_hi(u1.z)) + (bf2f_hi(u2.z) + bf2f_hi(u3.z));
                ax3 += (bf2f_lo(u0.w) + bf2f_lo(u1.w)) + (bf2f_lo(u2.w) + bf2f_lo(u3.w));
                ay3 += (bf2f_hi(u0.w) + bf2f_hi(u1.w)) + (bf2f_hi(u2.w) + bf2f_hi(u3.w));
            }
            int rem = e - i;                       // parallel tail (bit-identical order)
            if (rem > 0) {
                int eL = e - 1;
                int i0 = csr[i];
                int i1 = csr[min(i + 1, eL)];
                int i2 = csr[min(i + 2, eL)];
                uint4 u0 = hb128[(size_t)i0 * 16 + l16];
                uint4 u1 = hb128[(size_t)i1 * 16 + l16];
                uint4 u2 = hb128[(size_t)i2 * 16 + l16];
                ax0 += bf2f_lo(u0.x); ay0 += bf2f_hi(u0.x);
                ax1 += bf2f_lo(u0.y); ay1 += bf2f_hi(u0.y);
                ax2 += bf2f_lo(u0.z); ay2 += bf2f_hi(u0.z);
                ax3 += bf2f_lo(u0.w); ay3 += bf2f_hi(u0.w);
                if (rem > 1) {
                    ax0 += bf2f_lo(u1.x); ay0 += bf2f_hi(u1.x);
                    ax1 += bf2f_lo(u1.y); ay1 += bf2f_hi(u1.y);
                    ax2 += bf2f_lo(u1.z); ay2 += bf2f_hi(u1.z);
                    ax3 += bf2f_lo(u1.w); ay3 += bf2f_hi(u1.w);
                }
                if (rem > 2) {
                    ax0 += bf2f_lo(u2.x); ay0 += bf2f_hi(u2.x);
                    ax1 += bf2f_lo(u2.y); ay1 += bf2f_hi(u2.y);
                    ax2 += bf2f_lo(u2.z); ay2 += bf2f_hi(u2.z);
                    ax3 += bf2f_lo(u2.w); ay3 += bf2f_hi(u2.w);
                }
            }
            float id = invd[n];
            uint4 r;
            r.x = (unsigned int)f2bf(ax0 * id) | ((unsigned int)f2bf(ay0 * id) << 16);
            r.y = (unsigned int)f2bf(ax1 * id) | ((unsigned int)f2bf(ay1 * id) << 16);
            r.z = (unsigned int)f2bf(ax2 * id) | ((unsigned int)f2bf(ay2 * id) << 16);
            r.w = (unsigned int)f2bf(ax3 * id) | ((unsigned int)f2bf(ay3 * id) << 16);
            *(uint4*)&Am[nl][l16 * 8] = r;
        } else {
            *(uint4*)&Am[nl][l16 * 8] = make_uint4(0, 0, 0, 0);
        }
    }

    f32x4 acc[4][2];
#pragma unroll
    for (int m = 0; m < 4; m++)
#pragma unroll
        for (int n = 0; n < 2; n++) acc[m][n] = (f32x4)(0.f);

    for (int chunk = 0; chunk < 4; chunk++) {
        int kb = chunk * 64;
        // ---- chunks 2-3: stage own bufC rows into Am cols 0..63 (post-MFMA barrier
        //      of the previous chunk guarantees mean reads are done) ----
        if (chunk >= 2) {
            int rA = t >> 2, qA = t & 3;
            int srow = row0 + rA;
            int cA = (kb & 127) + qA * 16;
            uint4 a0, a1;
            if (srow < N) {
                const unsigned short* p = hb + (size_t)srow * HID + cA;
                a0 = *(const uint4*)(p); a1 = *(const uint4*)(p + 8);
            } else {
                a0 = a1 = make_uint4(0, 0, 0, 0);
            }
            *(uint4*)&Am[rA][qA * 16]     = a0;
            *(uint4*)&Am[rA][qA * 16 + 8] = a1;
        }
        // ---- stage W: 128x64 shorts, 32 shorts (64 B) per thread ----
        int rW = t >> 1, hW = t & 1;
        const unsigned short* wp = wcat + rW * 256 + kb + hW * 32;
        *(uint4*)&Ws[rW][hW * 32]      = *(const uint4*)(wp);
        *(uint4*)&Ws[rW][hW * 32 + 8]  = *(const uint4*)(wp + 8);
        *(uint4*)&Ws[rW][hW * 32 + 16] = *(const uint4*)(wp + 16);
        *(uint4*)&Ws[rW][hW * 32 + 24] = *(const uint4*)(wp + 24);
        __syncthreads();

        int acol = (chunk < 2) ? kb : 0;   // chunks 0-1: means at cols kb..kb+63
        // ---- MFMA: two k-steps of 32; wave covers cols [wave*32, wave*32+32) ----
#pragma unroll
        for (int ks = 0; ks < 64; ks += 32) {
            short8 af[4], bfr[2];
#pragma unroll
            for (int m = 0; m < 4; m++)
                af[m] = *(const short8*)&Am[m * 16 + lrow][acol + ks + koff];
#pragma unroll
            for (int n = 0; n < 2; n++)
                bfr[n] = *(const short8*)&Ws[wave * 32 + n * 16 + lrow][ks + koff];
#pragma unroll
            for (int m = 0; m < 4; m++)
#pragma unroll
                for (int n = 0; n < 2; n++)
                    acc[m][n] = __builtin_amdgcn_mfma_f32_16x16x32_bf16(af[m], bfr[n], acc[m][n], 0, 0, 0);
        }
        __syncthreads();
    }

    // ---- epilogue: stats (fp32 from acc) + bf16 C via LDS re-stage (Am), coalesced ----
    unsigned short* Cst = &Am[0][0];   // 64 x 136 shorts, exact Am footprint
    int cl = lane & 15, rq = (lane >> 4) * 4;
#pragma unroll
    for (int n = 0; n < 2; n++) {
        int col = wave * 32 + n * 16 + cl;
        float bn = bias[col];
        float s = 0.f, q = 0.f;
#pragma unroll
        for (int m = 0; m < 4; m++) {
#pragma unroll
            for (int reg = 0; reg < 4; reg++) {
                int rl = m * 16 + rq + reg;
                float v = acc[m][n][reg] + bn;
                Cst[rl * 136 + col] = f2bf(v);
                if (row0 + rl < N) { s += v; q += v * v; }
            }
        }
        s += __shfl_xor(s, 16, 64); q += __shfl_xor(q, 16, 64);
        s += __shfl_xor(s, 32, 64); q += __shfl_xor(q, 32, 64);
        if (lane < 16) { lds_s[col] = s; lds_q[col] = q; }
    }
    __syncthreads();
    if (t < 128) {
        int slot = (blockIdx.x & 7) * 128 + t;
        atomicAdd(&sum8[slot], lds_s[t]);
        atomicAdd(&sq8[slot], lds_q[t]);
    }
    // coalesced bf16 C write: 1024 uint4 (64 rows x 16 segs), 4 per thread
#pragma unroll
    for (int j = 0; j < 4; j++) {
        int idx = t + j * 256;
        int rl = idx >> 4, seg = idx & 15;
        int row = row0 + rl;
        if (row < N)
            *(uint4*)(C + (size_t)row * HID + seg * 8) = *(const uint4*)&Cst[rl * 136 + seg * 8];
    }
}

// ---------------- layer 2 dots: inline bnfin1 + relu(bn1(h))·wl2 / ·wr2 ---------------
__global__ void k_dots(const unsigned short* __restrict__ h, const float* __restrict__ sum8,
                       const float* __restrict__ sq8, const float* __restrict__ g,
                       const float* __restrict__ be, float invN,
                       const float* __restrict__ wl2, const float* __restrict__ wr2,
                       float* __restrict__ s_arr, float* __restrict__ r_arr, int N) {
    __shared__ float scl[128];
    __shared__ float shl[128];
    int t = threadIdx.x;
    if (t < 128) {
        float s = 0.f, q = 0.f;
        for (int c = 0; c < 8; c++) { s += sum8[c * 128 + t]; q += sq8[c * 128 + t]; }
        float mu  = s * invN;
        float var = q * invN - mu * mu;
        float sc  = g[t] * rsqrtf(var + 1e-5f);
        scl[t] = sc;
        shl[t] = be[t] - mu * sc;
    }
    __syncthreads();
    int w = t >> 6, lid = t & 63;
    int n = blockIdx.x * 4 + w;
    if (n >= N) return;
    unsigned int u = ((const unsigned int*)h)[(size_t)n * 64 + lid];
    float hx = bf2f_lo(u), hy = bf2f_hi(u);
    float2 sc = *(const float2*)&scl[lid * 2];
    float2 sh = *(const float2*)&shl[lid * 2];
    float y0 = fmaxf(0.f, fmaf(hx, sc.x, sh.x));
    float y1 = fmaxf(0.f, fmaf(hy, sc.y, sh.y));
    float2 wl = *(const float2*)&wl2[lid * 2];
    float2 wrv = *(const float2*)&wr2[lid * 2];
    float ps = y0 * wl.x + y1 * wl.y;
    float pr = y0 * wrv.x + y1 * wrv.y;
#pragma unroll
    for (int off = 32; off > 0; off >>= 1) {
        ps += __shfl_down(ps, off, 64);
        pr += __shfl_down(pr, off, 64);
    }
    if (lid == 0) { s_arr[n] = ps; r_arr[n] = pr; }
}

// ---------------- final: scalar mean over edges + sigmoid (parallel tail) --------------
__global__ void k_final2(const float* __restrict__ s_arr, const float* __restrict__ r_arr,
                         const int* __restrict__ rowptr, const int* __restrict__ csr,
                         const float* __restrict__ invd, const float* __restrict__ bl2,
                         float* __restrict__ out, int N) {
    int n = blockIdx.x * blockDim.x + threadIdx.x;
    if (n >= N) return;
    int s = rowptr[n], e = rowptr[n + 1];
    float a = 0.f;
    int i = s;
    for (; i + 4 <= e; i += 4) {
        float a0 = s_arr[csr[i]],     a1 = s_arr[csr[i + 1]];
        float a2 = s_arr[csr[i + 2]], a3 = s_arr[csr[i + 3]];
        a += (a0 + a1) + (a2 + a3);
    }
    int rem = e - i;
    if (rem > 0) {
        int eL = e - 1;
        float a0 = s_arr[csr[i]];
        float a1 = s_arr[csr[min(i + 1, eL)]];
        float a2 = s_arr[csr[min(i + 2, eL)]];
        a += a0;
        if (rem > 1) a += a1;
        if (rem > 2) a += a2;
    }
    float p = a * invd[n] + r_arr[n] + bl2[0];
    out[n] = 1.f / (1.f + expf(-p));
}

// ---------------- host ----------------
extern "C" void kernel_launch(void* const* d_in, const int* in_sizes, int n_in,
                              void* d_out, int out_size, void* d_ws, size_t ws_size,
                              hipStream_t stream) {
    const float* x   = (const float*)d_in[0];
    const int*   ei  = (const int*)d_in[1];
    const float* wl0 = (const float*)d_in[2];
    const float* bl0 = (const float*)d_in[3];
    const float* wr0 = (const float*)d_in[4];
    const float* g0  = (const float*)d_in[5];
    const float* be0 = (const float*)d_in[6];
    const float* wl1 = (const float*)d_in[7];
    const float* bl1 = (const float*)d_in[8];
    const float* wr1 = (const float*)d_in[9];
    const float* g1  = (const float*)d_in[10];
    const float* be1 = (const float*)d_in[11];
    const float* wl2 = (const float*)d_in[12];
    const float* bl2 = (const float*)d_in[13];
    const float* wr2 = (const float*)d_in[14];
    float* outp = (float*)d_out;

    int N = in_sizes[0] / INDIM;     // 100000
    int E = in_sizes[1] / 2;         // 600000

    char* ws = (char*)d_ws;
    size_t off = 0;
    auto alloc = [&](size_t bytes) { size_t o = off; off = (off + bytes + 255) & ~(size_t)255; return o; };
    int*   degi   = (int*)(ws + alloc((size_t)N * 4));
    int*   rank   = (int*)(ws + alloc((size_t)E * 4));
    int*   rowptr = (int*)(ws + alloc((size_t)(N + 1) * 4));
    int*   csr    = (int*)(ws + alloc((size_t)E * 4));
    float* invd   = (float*)(ws + alloc((size_t)N * 4));
    int*   partial= (int*)(ws + alloc(1024 * 4));
    float* bnbuf  = (float*)(ws + alloc(5120 * 4));
    unsigned short* wcat = (unsigned short*)(ws + alloc(128 * 256 * 2));
    float* sarr   = (float*)(ws + alloc((size_t)N * 4));
    float* rarr   = (float*)(ws + alloc((size_t)N * 4));
    float* mean6  = (float*)(ws + alloc((size_t)N * 6 * 4));
    float* sum0_8 = bnbuf;
    float* sq0_8  = bnbuf + 1024;
    float* sum1_8 = bnbuf + 2048;
    float* sq1_8  = bnbuf + 3072;
    unsigned short* bufB = (unsigned short*)(ws + alloc((size_t)N * HID * 2)); // bf16 gemm out
    unsigned short* bufC = (unsigned short*)(ws + alloc((size_t)N * HID * 2)); // bf16 relu(bn0)

    float invN = 1.0f / (float)N;
    int gE = (E + 255) / 256;
    int gN = (N + 255) / 256;
    int gW = (N + 3) / 4;            // wave-per-node kernels
    int gL = (N + 31) / 32;          // layer0 blocks (32 nodes each)
    int gS = (N + 63) / 64;          // fused agg+gemm blocks (64-row tiles)
    int nbScan = (N + 1023) / 1024;  // <= 256 for N <= 262144

    // init: zero degree + BN accumulators, prep bf16 wcat (one launch)
    k_init<<<gN, 256, 0, stream>>>(degi, N, (int*)bnbuf, 4096, wl1, wr1, wcat);

    // CSR build (rank-based, atomic-free fill; invdeg fused; tops scan folded into write)
    k_deg<<<gE, 256, 0, stream>>>(ei + E, degi, rank, E);
    k_scan_partial<<<nbScan, 256, 0, stream>>>(degi, partial, N);
    k_scan_write<<<nbScan, 256, 0, stream>>>(degi, partial, rowptr, invd, N, E, nbScan);
    k_fill<<<gE, 256, 0, stream>>>(ei, rank, rowptr, csr, E);

    // layer 0a: gather mean6 + fused BN0 stats (h in-register, discarded)
    k_l0stats<<<gL, 256, 0, stream>>>(x, rowptr, csr, invd, wl0, bl0, wr0, mean6,
                                      sum0_8, sq0_8, N);

    // layer 0b: inline bnfin0 + recompute h + BN0+ReLU -> bf16 bufC
    k_l0apply<<<gL, 256, 0, stream>>>(x, mean6, wl0, bl0, wr0,
                                      sum0_8, sq0_8, g0, be0, invN, bufC, N);

    // layer 1 (fused): per-tile agg into LDS + MFMA gemm -> bufB (bf16) + BN1 stats
    k_agggemm<<<gS, 256, 0, stream>>>(bufC, rowptr, csr, invd, wcat, bl1,
                                      sum1_8, sq1_8, bufB, N);

    // layer 2: inline bnfin1 + per-node dots, then scalar aggregation + sigmoid
    k_dots<<<gW, 256, 0, stream>>>(bufB, sum1_8, sq1_8, g1, be1, invN, wl2, wr2,
                                   sarr, rarr, N);
    k_final2<<<gN, 256, 0, stream>>>(sarr, rarr, rowptr, csr, invd, bl2, outp, N);
}